// Round 1
// baseline (3499.932 us; speedup 1.0000x reference)
//
#include <hip/hip_runtime.h>
#include <hip/hip_bf16.h>
#include <math.h>

// Problem constants
// B=8, S=512, HID=512, HEADS=8, DH=64, FF=768, NL=3, SPAN=256, MAXP=512, VOCAB=100
#define EPS_LN 1e-7f
// SCALE = sqrt(64*3) = sqrt(192); we multiply by 1/SCALE
#define INV_SCALE 0.072168783648703221f
#define NEGMAX -3.402823466e38f

// ---------------------------------------------------------------------------
// Relative position log-bucket table (DeBERTa-v2), computed per launch.
// c2p[i*512+j] = clip(bucket(i-j)+256, 0, 511)
// p2c[i*512+j] = clip(-bucket(i-j)+256, 0, 511)
// ---------------------------------------------------------------------------
__global__ __launch_bounds__(256) void relbucket_kernel(int* __restrict__ c2p,
                                                        int* __restrict__ p2c) {
  int idx = blockIdx.x * 256 + threadIdx.x;  // 512*512 total
  int i = idx >> 9, j = idx & 511;
  int rel = i - j;
  int a = (rel < 128 && rel > -128) ? 127 : (rel < 0 ? -rel : rel);
  int bucket;
  if (a <= 128) {
    bucket = rel;
  } else {
    double lp = ceil(log((double)a / 128.0) / log(511.0 / 128.0) * 127.0) + 128.0;
    int l = (int)lp;
    bucket = (rel > 0) ? l : -l;
  }
  int c = bucket + 256;
  c = c < 0 ? 0 : (c > 511 ? 511 : c);
  int p = -bucket + 256;
  p = p < 0 ? 0 : (p > 511 ? 511 : p);
  c2p[idx] = c;
  p2c[idx] = p;
}

// ---------------------------------------------------------------------------
// LayerNorm over 512 cols. One wave per row, 4 rows per 256-thread block.
// RESID: out = LN(x + res); MASK: out *= mask[row] (post bias, like reference)
// ---------------------------------------------------------------------------
template <bool RESID, bool MASK>
__global__ __launch_bounds__(256) void ln_kernel(const float* __restrict__ x,
                                                 const float* __restrict__ res,
                                                 const float* __restrict__ gam,
                                                 const float* __restrict__ bet,
                                                 const float* __restrict__ mask,
                                                 float* __restrict__ out, int nrows) {
  int w = threadIdx.x >> 6, ln = threadIdx.x & 63;
  int row = blockIdx.x * 4 + w;
  if (row >= nrows) return;
  const float* xr = x + (size_t)row * 512;
  float v[8];
#pragma unroll
  for (int c = 0; c < 2; ++c) {
    float4 a = *(const float4*)(xr + (ln << 3) + (c << 2));
    v[c * 4 + 0] = a.x; v[c * 4 + 1] = a.y; v[c * 4 + 2] = a.z; v[c * 4 + 3] = a.w;
    if (RESID) {
      float4 r4 = *(const float4*)(res + (size_t)row * 512 + (ln << 3) + (c << 2));
      v[c * 4 + 0] += r4.x; v[c * 4 + 1] += r4.y; v[c * 4 + 2] += r4.z; v[c * 4 + 3] += r4.w;
    }
  }
  float sum = 0.f;
#pragma unroll
  for (int c = 0; c < 8; ++c) sum += v[c];
#pragma unroll
  for (int off = 32; off; off >>= 1) sum += __shfl_xor(sum, off);
  float mu = sum * (1.f / 512.f);
  float vs = 0.f;
#pragma unroll
  for (int c = 0; c < 8; ++c) {
    float d = v[c] - mu;
    vs += d * d;
  }
#pragma unroll
  for (int off = 32; off; off >>= 1) vs += __shfl_xor(vs, off);
  float var = vs * (1.f / 512.f);
  float rstd = 1.f / sqrtf(var + EPS_LN);
  float mk = MASK ? mask[row] : 1.f;
  float* orow = out + (size_t)row * 512;
#pragma unroll
  for (int c = 0; c < 2; ++c) {
    int col = (ln << 3) + (c << 2);
    float4 o;
    o.x = ((v[c * 4 + 0] - mu) * rstd * gam[col + 0] + bet[col + 0]) * mk;
    o.y = ((v[c * 4 + 1] - mu) * rstd * gam[col + 1] + bet[col + 1]) * mk;
    o.z = ((v[c * 4 + 2] - mu) * rstd * gam[col + 2] + bet[col + 2]) * mk;
    o.w = ((v[c * 4 + 3] - mu) * rstd * gam[col + 3] + bet[col + 3]) * mk;
    *(float4*)(orow + col) = o;
  }
}

// ---------------------------------------------------------------------------
// fp32 tiled GEMM: C[M,N] = A[M,K] @ W[K,N] + bias[N], ACT=1 -> exact GELU.
// 64x64 tile, BK=64, 256 threads, 4x4 micro-tile. M%64==0, K%64==0; N guarded.
// ---------------------------------------------------------------------------
__device__ __forceinline__ float gelu_exact(float v) {
  return 0.5f * v * (1.f + erff(v * 0.70710678118654752440f));
}

template <int ACT>
__global__ __launch_bounds__(256) void gemm_kernel(const float* __restrict__ A,
                                                   const float* __restrict__ W,
                                                   const float* __restrict__ bias,
                                                   float* __restrict__ C,
                                                   int M, int N, int K) {
  __shared__ float At[64][68];  // transposed A tile: At[k][m]
  __shared__ float Bs[64][68];  // Bs[k][n]
  int t = threadIdx.x;
  int m0 = blockIdx.y << 6, n0 = blockIdx.x << 6;
  int tx = t & 15, ty = t >> 4;
  float acc[4][4] = {};
  for (int k0 = 0; k0 < K; k0 += 64) {
#pragma unroll
    for (int L = 0; L < 4; ++L) {
      int f = t + (L << 8);  // float4 index 0..1023
      int r = f >> 4, c4 = (f & 15) << 2;
      float4 av = *(const float4*)(A + (size_t)(m0 + r) * K + k0 + c4);
      At[c4 + 0][r] = av.x; At[c4 + 1][r] = av.y;
      At[c4 + 2][r] = av.z; At[c4 + 3][r] = av.w;
      int nb = n0 + c4;
      float4 bv;
      if (nb + 3 < N) {
        bv = *(const float4*)(W + (size_t)(k0 + r) * N + nb);
      } else {
        bv.x = (nb + 0 < N) ? W[(size_t)(k0 + r) * N + nb + 0] : 0.f;
        bv.y = (nb + 1 < N) ? W[(size_t)(k0 + r) * N + nb + 1] : 0.f;
        bv.z = (nb + 2 < N) ? W[(size_t)(k0 + r) * N + nb + 2] : 0.f;
        bv.w = (nb + 3 < N) ? W[(size_t)(k0 + r) * N + nb + 3] : 0.f;
      }
      *(float4*)(&Bs[r][c4]) = bv;
    }
    __syncthreads();
#pragma unroll 8
    for (int kk = 0; kk < 64; ++kk) {
      float4 a4 = *(const float4*)(&At[kk][ty << 2]);
      float4 b4 = *(const float4*)(&Bs[kk][tx << 2]);
      float ar[4] = {a4.x, a4.y, a4.z, a4.w};
      float br[4] = {b4.x, b4.y, b4.z, b4.w};
#pragma unroll
      for (int r = 0; r < 4; ++r)
#pragma unroll
        for (int c = 0; c < 4; ++c) acc[r][c] += ar[r] * br[c];
    }
    __syncthreads();
  }
#pragma unroll
  for (int r = 0; r < 4; ++r) {
    int row = m0 + (ty << 2) + r;
#pragma unroll
    for (int c = 0; c < 4; ++c) {
      int col = n0 + (tx << 2) + c;
      if (col < N) {
        float v = acc[r][c] + bias[col];
        if (ACT == 1) v = gelu_exact(v);
        C[(size_t)row * N + col] = v;
      }
    }
  }
}

// ---------------------------------------------------------------------------
// Fused disentangled attention for one (b, head, 32-row q-tile).
// qc/kc/vc: [4608, 512]; rows 0..4095 = per-token q/k/v, rows 4096..4607 = pq/pk
// (pv unused). scores[i][j] = (q.k + q.pk[c2p(i,j)] + k.pq[p2c(j,i)]) / SCALE,
// masked softmax (XSoftmax), then ctx = probs @ v.
// ---------------------------------------------------------------------------
__global__ __launch_bounds__(256) void attn_kernel(const float* __restrict__ qc,
                                                   const float* __restrict__ kc,
                                                   const float* __restrict__ vc,
                                                   const float* __restrict__ mask,
                                                   const int* __restrict__ c2p_idx,
                                                   const int* __restrict__ p2c_idx,
                                                   float* __restrict__ ctx) {
  __shared__ float sc[32][512];  // 64 KB score tile
  __shared__ float qs[32][64];   // 8 KB q tile
  int t = threadIdx.x;
  int bid = blockIdx.x;
  int qt = bid & 15, head = (bid >> 4) & 7, b = bid >> 7;
  int i0 = qt << 5;

  const float* qbase = qc + ((size_t)(b * 512 + i0)) * 512 + head * 64;
  for (int idx = t; idx < 32 * 64; idx += 256) {
    int i = idx >> 6, d = idx & 63;
    qs[i][d] = qbase[(size_t)i * 512 + d];
  }
  __syncthreads();

  const float* pkbase = kc + (size_t)4096 * 512 + head * 64;
  const float* pqbase = qc + (size_t)4096 * 512 + head * 64;
#pragma unroll 1
  for (int jj = 0; jj < 2; ++jj) {
    int j = t + (jj << 8);
    const float* krow = kc + ((size_t)(b * 512 + j)) * 512 + head * 64;
    float kreg[64];
#pragma unroll
    for (int d = 0; d < 64; d += 4) {
      float4 f = *(const float4*)(krow + d);
      kreg[d] = f.x; kreg[d + 1] = f.y; kreg[d + 2] = f.z; kreg[d + 3] = f.w;
    }
    const int* c2prow = c2p_idx + (size_t)i0 * 512 + j;  // [(i0+i)*512 + j]
    const int* p2crow = p2c_idx + (size_t)j * 512 + i0;  // [j*512 + i0+i]
#pragma unroll 1
    for (int i = 0; i < 32; ++i) {
      int r1 = c2prow[i * 512];
      int r2 = p2crow[i];
      const float* pkrow = pkbase + (size_t)r1 * 512;
      const float* pqrow = pqbase + (size_t)r2 * 512;
      float acc = 0.f;
#pragma unroll
      for (int d = 0; d < 64; d += 4) {
        float4 q4 = *(const float4*)(&qs[i][d]);
        float4 p4 = *(const float4*)(pkrow + d);
        float4 u4 = *(const float4*)(pqrow + d);
        acc += q4.x * (kreg[d + 0] + p4.x) + kreg[d + 0] * u4.x;
        acc += q4.y * (kreg[d + 1] + p4.y) + kreg[d + 1] * u4.y;
        acc += q4.z * (kreg[d + 2] + p4.z) + kreg[d + 2] * u4.z;
        acc += q4.w * (kreg[d + 3] + p4.w) + kreg[d + 3] * u4.w;
      }
      sc[i][j] = acc;
    }
  }
  __syncthreads();

  // masked softmax per row (XSoftmax: -inf fill, softmax, re-zero)
  int w = t >> 6, ln = t & 63;
  for (int i = w; i < 32; i += 4) {
    float mi = mask[b * 512 + i0 + i];
    float vals[8];
    float mx = NEGMAX;
#pragma unroll
    for (int c = 0; c < 8; ++c) {
      int j = ln + (c << 6);
      float mj = mask[b * 512 + j];
      float s = (mi * mj > 0.f) ? sc[i][j] * INV_SCALE : NEGMAX;
      vals[c] = s;
      mx = fmaxf(mx, s);
    }
#pragma unroll
    for (int off = 32; off; off >>= 1) mx = fmaxf(mx, __shfl_xor(mx, off));
    float sum = 0.f;
#pragma unroll
    for (int c = 0; c < 8; ++c) {
      float e = expf(vals[c] - mx);
      vals[c] = e;
      sum += e;
    }
#pragma unroll
    for (int off = 32; off; off >>= 1) sum += __shfl_xor(sum, off);
    float rs = 1.f / sum;
#pragma unroll
    for (int c = 0; c < 8; ++c) {
      int j = ln + (c << 6);
      float mj = mask[b * 512 + j];
      sc[i][j] = (mi * mj > 0.f) ? vals[c] * rs : 0.f;
    }
  }
  __syncthreads();

  // ctx[i][d] = sum_j p[i][j] * v[j][d]; thread owns (d, 8 rows)
  {
    int d = t & 63, ig = t >> 6;
    const float* vbase = vc + ((size_t)(b * 512)) * 512 + head * 64 + d;
    float acc[8] = {};
    for (int j = 0; j < 512; ++j) {
      float vv = vbase[(size_t)j * 512];
#pragma unroll
      for (int c = 0; c < 8; ++c) acc[c] += sc[ig * 8 + c][j] * vv;
    }
    float* obase = ctx + ((size_t)(b * 512 + i0 + ig * 8)) * 512 + head * 64 + d;
#pragma unroll
    for (int c = 0; c < 8; ++c) obase[(size_t)c * 512] = acc[c];
  }
}

// ---------------------------------------------------------------------------
// Host launch
// ---------------------------------------------------------------------------
extern "C" void kernel_launch(void* const* d_in, const int* in_sizes, int n_in,
                              void* d_out, int out_size, void* d_ws, size_t ws_size,
                              hipStream_t stream) {
  const float* x       = (const float*)d_in[0];   // [8,512,512]
  const float* mask    = (const float*)d_in[1];   // [8,512]
  const float* emb_s   = (const float*)d_in[2];
  const float* emb_b   = (const float*)d_in[3];
  const float* rel_emb = (const float*)d_in[4];   // [512,512]
  const float* rel_s   = (const float*)d_in[5];
  const float* rel_b   = (const float*)d_in[6];
  const float* Wq = (const float*)d_in[7];
  const float* bq = (const float*)d_in[8];
  const float* Wk = (const float*)d_in[9];
  const float* bk = (const float*)d_in[10];
  const float* Wv = (const float*)d_in[11];
  const float* bv = (const float*)d_in[12];
  const float* Wo = (const float*)d_in[13];
  const float* bo = (const float*)d_in[14];
  const float* as_ = (const float*)d_in[15];
  const float* ab_ = (const float*)d_in[16];
  const float* Wi = (const float*)d_in[17];
  const float* bi = (const float*)d_in[18];
  const float* Wf = (const float*)d_in[19];
  const float* bf = (const float*)d_in[20];
  const float* fs_ = (const float*)d_in[21];
  const float* fb_ = (const float*)d_in[22];
  const float* Wc = (const float*)d_in[23];
  const float* bc = (const float*)d_in[24];
  float* out = (float*)d_out;

  float* ws = (float*)d_ws;
  const size_t R = (size_t)4608 * 512;  // h (4096) + rel_e (512) concatenated
  float* hcat = ws;            // [4608,512]: rows 0..4095 = h, 4096..4607 = LN(rel_emb)
  float* qcat = hcat + R;      // [4608,512]: q | pq
  float* kcat = qcat + R;      // [4608,512]: k | pk
  float* vcat = kcat + R;      // [4608,512]: v | (unused)
  float* ctx  = vcat + R;                       // [4096,512]
  float* tmpA = ctx + (size_t)4096 * 512;       // [4096,512]
  float* mid  = tmpA + (size_t)4096 * 512;      // [4096,768]
  int* c2p = (int*)(mid + (size_t)4096 * 768);  // [512,512]
  int* p2c = c2p + (size_t)512 * 512;           // [512,512]
  // total ws use: ~66 MB

  relbucket_kernel<<<1024, 256, 0, stream>>>(c2p, p2c);
  // h = LN(x) * mask ; rel_e = LN(rel_emb)
  ln_kernel<false, true><<<1024, 256, 0, stream>>>(x, nullptr, emb_s, emb_b, mask, hcat, 4096);
  ln_kernel<false, false><<<128, 256, 0, stream>>>(rel_emb, nullptr, rel_s, rel_b, nullptr,
                                                   hcat + (size_t)4096 * 512, 512);

  for (int l = 0; l < 3; ++l) {
    const float* wq = Wq + (size_t)l * 512 * 512;
    const float* wk = Wk + (size_t)l * 512 * 512;
    const float* wv = Wv + (size_t)l * 512 * 512;
    const float* wo = Wo + (size_t)l * 512 * 512;
    const float* wi = Wi + (size_t)l * 512 * 768;
    const float* wf = Wf + (size_t)l * 768 * 512;
    // q|pq, k|pk, v in one GEMM each (shared weights/bias, share_att_key=True)
    gemm_kernel<0><<<dim3(8, 72), 256, 0, stream>>>(hcat, wq, bq + l * 512, qcat, 4608, 512, 512);
    gemm_kernel<0><<<dim3(8, 72), 256, 0, stream>>>(hcat, wk, bk + l * 512, kcat, 4608, 512, 512);
    gemm_kernel<0><<<dim3(8, 72), 256, 0, stream>>>(hcat, wv, bv + l * 512, vcat, 4608, 512, 512);
    attn_kernel<<<1024, 256, 0, stream>>>(qcat, kcat, vcat, mask, c2p, p2c, ctx);
    gemm_kernel<0><<<dim3(8, 64), 256, 0, stream>>>(ctx, wo, bo + l * 512, tmpA, 4096, 512, 512);
    ln_kernel<true, false><<<1024, 256, 0, stream>>>(tmpA, hcat, as_ + l * 512, ab_ + l * 512,
                                                     nullptr, hcat, 4096);
    gemm_kernel<1><<<dim3(12, 64), 256, 0, stream>>>(hcat, wi, bi + l * 768, mid, 4096, 768, 512);
    gemm_kernel<0><<<dim3(8, 64), 256, 0, stream>>>(mid, wf, bf + l * 512, tmpA, 4096, 512, 768);
    ln_kernel<true, false><<<1024, 256, 0, stream>>>(tmpA, hcat, fs_ + l * 512, fb_ + l * 512,
                                                     nullptr, hcat, 4096);
  }
  gemm_kernel<0><<<dim3(2, 64), 256, 0, stream>>>(hcat, Wc, bc, out, 4096, 100, 512);
}

// Round 2
// 733.966 us; speedup vs baseline: 4.7685x; 4.7685x over previous
//
#include <hip/hip_runtime.h>
#include <hip/hip_bf16.h>
#include <math.h>

// B=8, S=512, HID=512, HEADS=8, DH=64, FF=768, NL=3, SPAN=256, MAXP=512, VOCAB=100
#define EPS_LN 1e-7f
#define INV_SCALE 0.072168783648703221f   // 1/sqrt(64*3)
#define NEGMAX -3.402823466e38f

typedef unsigned short u16;
typedef __attribute__((ext_vector_type(8))) short bf16x8;  // 8 bf16 = 4 VGPRs
typedef __attribute__((ext_vector_type(4))) float f32x4;

__device__ __forceinline__ u16 f2b(float f) {
  union { float f; unsigned int u; } v; v.f = f;
  unsigned int r = v.u + 0x7FFFu + ((v.u >> 16) & 1u);
  return (u16)(r >> 16);
}
__device__ __forceinline__ float b2f(u16 u) {
  union { unsigned int u; float f; } v; v.u = ((unsigned int)u) << 16;
  return v.f;
}
__device__ __forceinline__ float gelu_exact(float v) {
  return 0.5f * v * (1.f + erff(v * 0.70710678118654752440f));
}

// ---------------------------------------------------------------------------
// Single relative-position index table. Key identity: the log-bucket is an
// odd function of (i-j), so p2c_idx[j][i] == c2p_idx[i][j]; one table serves
// both gathers.
// ---------------------------------------------------------------------------
__global__ __launch_bounds__(256) void relbucket_kernel(int* __restrict__ c2p) {
  int idx = blockIdx.x * 256 + threadIdx.x;  // 512*512
  int i = idx >> 9, j = idx & 511;
  int rel = i - j;
  int a = (rel < 128 && rel > -128) ? 127 : (rel < 0 ? -rel : rel);
  int bucket;
  if (a <= 128) {
    bucket = rel;
  } else {
    double lp = ceil(log((double)a / 128.0) / log(511.0 / 128.0) * 127.0) + 128.0;
    int l = (int)lp;
    bucket = (rel > 0) ? l : -l;
  }
  int c = bucket + 256;
  c = c < 0 ? 0 : (c > 511 ? 511 : c);
  c2p[idx] = c;
}

// ---------------------------------------------------------------------------
// LayerNorm over 512 cols; writes fp32 master and optional bf16 mirror.
// ---------------------------------------------------------------------------
template <bool RESID, bool MASK>
__global__ __launch_bounds__(256) void ln_kernel(const float* __restrict__ x,
                                                 const float* __restrict__ res,
                                                 const float* __restrict__ gam,
                                                 const float* __restrict__ bet,
                                                 const float* __restrict__ mask,
                                                 float* __restrict__ out,
                                                 u16* __restrict__ outb, int nrows) {
  int w = threadIdx.x >> 6, ln = threadIdx.x & 63;
  int row = blockIdx.x * 4 + w;
  if (row >= nrows) return;
  const float* xr = x + (size_t)row * 512;
  float v[8];
#pragma unroll
  for (int c = 0; c < 2; ++c) {
    float4 a = *(const float4*)(xr + (ln << 3) + (c << 2));
    v[c * 4 + 0] = a.x; v[c * 4 + 1] = a.y; v[c * 4 + 2] = a.z; v[c * 4 + 3] = a.w;
    if (RESID) {
      float4 r4 = *(const float4*)(res + (size_t)row * 512 + (ln << 3) + (c << 2));
      v[c * 4 + 0] += r4.x; v[c * 4 + 1] += r4.y; v[c * 4 + 2] += r4.z; v[c * 4 + 3] += r4.w;
    }
  }
  float sum = 0.f;
#pragma unroll
  for (int c = 0; c < 8; ++c) sum += v[c];
#pragma unroll
  for (int off = 32; off; off >>= 1) sum += __shfl_xor(sum, off);
  float mu = sum * (1.f / 512.f);
  float vs = 0.f;
#pragma unroll
  for (int c = 0; c < 8; ++c) { float d = v[c] - mu; vs += d * d; }
#pragma unroll
  for (int off = 32; off; off >>= 1) vs += __shfl_xor(vs, off);
  float rstd = 1.f / sqrtf(vs * (1.f / 512.f) + EPS_LN);
  float mk = MASK ? mask[row] : 1.f;
  float* orow = out + (size_t)row * 512;
  u16* brow = outb ? outb + (size_t)row * 512 : nullptr;
#pragma unroll
  for (int c = 0; c < 2; ++c) {
    int col = (ln << 3) + (c << 2);
    float o[4];
#pragma unroll
    for (int q = 0; q < 4; ++q)
      o[q] = ((v[c * 4 + q] - mu) * rstd * gam[col + q] + bet[col + q]) * mk;
    *(float4*)(orow + col) = make_float4(o[0], o[1], o[2], o[3]);
    if (brow) {
      ushort4 ob = { f2b(o[0]), f2b(o[1]), f2b(o[2]), f2b(o[3]) };
      *(ushort4*)(brow + col) = ob;
    }
  }
}

// ---------------------------------------------------------------------------
// Weight transpose + bf16 cast: W f32 [K][N] row-major -> Wt bf16 [N][K].
// Batched over layers via blockIdx.z.
// ---------------------------------------------------------------------------
__global__ __launch_bounds__(256) void wtrans_kernel(const float* __restrict__ W,
                                                     u16* __restrict__ Wt,
                                                     int K, int N, long wstride, long tstride) {
  __shared__ float tl[32][33];
  int z = blockIdx.z;
  W += (size_t)z * wstride;
  Wt += (size_t)z * tstride;
  int n0 = blockIdx.x * 32, k0 = blockIdx.y * 32;
  int c = threadIdx.x & 31, r8 = threadIdx.x >> 5;
#pragma unroll
  for (int p = 0; p < 4; ++p) {
    int r = r8 + p * 8;
    int k = k0 + r, n = n0 + c;
    tl[r][c] = (k < K && n < N) ? W[(size_t)k * N + n] : 0.f;
  }
  __syncthreads();
#pragma unroll
  for (int p = 0; p < 4; ++p) {
    int r = r8 + p * 8;
    int n = n0 + r, k = k0 + c;
    if (n < N && k < K) Wt[(size_t)n * K + k] = f2b(tl[c][r]);
  }
}

// ---------------------------------------------------------------------------
// V transpose: vbf [4096][512] bf16 -> vT [64(bh)][64(d)][512(j)] bf16.
// ---------------------------------------------------------------------------
__global__ __launch_bounds__(256) void vtrans_kernel(const u16* __restrict__ vbf,
                                                     u16* __restrict__ vT) {
  __shared__ u16 tl[32][33];
  int z = blockIdx.z;  // b*8+h
  int b = z >> 3, h = z & 7;
  int j0 = blockIdx.x * 32, d0 = blockIdx.y * 32;
  int c = threadIdx.x & 31, r8 = threadIdx.x >> 5;
#pragma unroll
  for (int p = 0; p < 4; ++p) {
    int r = r8 + p * 8;
    tl[r][c] = vbf[(size_t)(b * 512 + j0 + r) * 512 + h * 64 + d0 + c];
  }
  __syncthreads();
#pragma unroll
  for (int p = 0; p < 4; ++p) {
    int r = r8 + p * 8;
    vT[(size_t)z * 32768 + (size_t)(d0 + r) * 512 + j0 + c] = tl[c][r];
  }
}

// ---------------------------------------------------------------------------
// bf16 MFMA GEMM: C[M,N] = A[M,K] @ B[N,K]^T (+bias, +gelu).
// Both operands K-contiguous. 64x64 tile, BK=64, 4 waves (2x2), each wave
// 32x32 via 2x2 fragments of mfma_f32_16x16x32_bf16.
// Batched via blockIdx.z = b*8+h with (b,h) strides.
// EPI: 0=none, 1=bias, 2=bias+gelu. CT: u16 (bf16 out) or float.
// ---------------------------------------------------------------------------
template <int EPI, typename CT>
__global__ __launch_bounds__(256) void gemm_bf16(const u16* __restrict__ A,
                                                 const u16* __restrict__ B,
                                                 const float* __restrict__ bias,
                                                 CT* __restrict__ C,
                                                 int M, int N, int K,
                                                 int lda, int ldb, int ldc,
                                                 long sAb, long sAh, long sBb, long sBh,
                                                 long sCb, long sCh) {
  __shared__ u16 As[64][72];  // +8 pad: 144B row stride, 16B aligned
  __shared__ u16 Bs[64][72];
  int t = threadIdx.x;
  int z = blockIdx.z, zb = z >> 3, zh = z & 7;
  A += (size_t)zb * sAb + (size_t)zh * sAh;
  B += (size_t)zb * sBb + (size_t)zh * sBh;
  C += (size_t)zb * sCb + (size_t)zh * sCh;
  int m0 = blockIdx.y * 64, n0 = blockIdx.x * 64;
  int w = t >> 6, l = t & 63;
  int wr = w >> 1, wc = w & 1, lr = l & 15, kg = l >> 4;
  f32x4 acc[2][2] = {};
  for (int k0 = 0; k0 < K; k0 += 64) {
#pragma unroll
    for (int p = 0; p < 2; ++p) {
      int c = t + (p << 8);           // 0..511
      int row = c >> 3, q = c & 7;    // row 0..63, 16B chunk 0..7
      uint4 av = *(const uint4*)(A + (size_t)(m0 + row) * lda + k0 + q * 8);
      *(uint4*)(&As[row][q * 8]) = av;
      uint4 bv = make_uint4(0u, 0u, 0u, 0u);
      if (n0 + row < N) bv = *(const uint4*)(B + (size_t)(n0 + row) * ldb + k0 + q * 8);
      *(uint4*)(&Bs[row][q * 8]) = bv;
    }
    __syncthreads();
#pragma unroll
    for (int s = 0; s < 2; ++s) {
      bf16x8 a0 = *(const bf16x8*)(&As[wr * 32 + lr][kg * 8 + s * 32]);
      bf16x8 a1 = *(const bf16x8*)(&As[wr * 32 + 16 + lr][kg * 8 + s * 32]);
      bf16x8 b0 = *(const bf16x8*)(&Bs[wc * 32 + lr][kg * 8 + s * 32]);
      bf16x8 b1 = *(const bf16x8*)(&Bs[wc * 32 + 16 + lr][kg * 8 + s * 32]);
      acc[0][0] = __builtin_amdgcn_mfma_f32_16x16x32_bf16(a0, b0, acc[0][0], 0, 0, 0);
      acc[0][1] = __builtin_amdgcn_mfma_f32_16x16x32_bf16(a0, b1, acc[0][1], 0, 0, 0);
      acc[1][0] = __builtin_amdgcn_mfma_f32_16x16x32_bf16(a1, b0, acc[1][0], 0, 0, 0);
      acc[1][1] = __builtin_amdgcn_mfma_f32_16x16x32_bf16(a1, b1, acc[1][1], 0, 0, 0);
    }
    __syncthreads();
  }
#pragma unroll
  for (int m = 0; m < 2; ++m)
#pragma unroll
    for (int n = 0; n < 2; ++n) {
      int col = n0 + wc * 32 + n * 16 + lr;
      if (col < N) {
        float bv = (EPI >= 1) ? bias[col] : 0.f;
#pragma unroll
        for (int r = 0; r < 4; ++r) {
          int row = m0 + wr * 32 + m * 16 + kg * 4 + r;
          float v = acc[m][n][r] + bv;
          if (EPI == 2) v = gelu_exact(v);
          if constexpr (sizeof(CT) == 2) {
            ((u16*)C)[(size_t)row * ldc + col] = f2b(v);
          } else {
            ((float*)C)[(size_t)row * ldc + col] = v;
          }
        }
      }
    }
}

// ---------------------------------------------------------------------------
// Gather + XSoftmax, in place on bf16 scores -> bf16 probs.
// logit = (scores[i][j] + Qpk[i][c2p(i,j)] + Kpq[j][c2p(i,j)]) / SCALE
// One wave per row; 4 rows per block.
// ---------------------------------------------------------------------------
__global__ __launch_bounds__(256) void softmax_kernel(u16* __restrict__ scores,
                                                      const u16* __restrict__ Qpk,
                                                      const u16* __restrict__ Kpq,
                                                      const float* __restrict__ mask,
                                                      const int* __restrict__ c2p) {
  int t = threadIdx.x;
  int wv = t >> 6, lane = t & 63;
  int rid = blockIdx.x * 4 + wv;          // 0..32767
  int z = rid >> 9, i = rid & 511;        // z = b*8+h
  int b = z >> 3;
  u16* srow = scores + (size_t)z * 262144 + (size_t)i * 512;
  const u16* qrow = Qpk + (size_t)z * 262144 + (size_t)i * 512;
  const u16* kbase = Kpq + (size_t)z * 262144;
  const int* crow = c2p + (size_t)i * 512;
  float mi = mask[b * 512 + i];
  float vals[8];
  float mx = NEGMAX;
  bool ok[8];
#pragma unroll
  for (int c = 0; c < 8; ++c) {
    int j = lane + (c << 6);
    int idx = crow[j];
    float s = b2f(srow[j]) + b2f(qrow[idx]) + b2f(kbase[(size_t)j * 512 + idx]);
    float mj = mask[b * 512 + j];
    ok[c] = (mi * mj) > 0.f;
    float lg = ok[c] ? s * INV_SCALE : NEGMAX;
    vals[c] = lg;
    mx = fmaxf(mx, lg);
  }
#pragma unroll
  for (int off = 32; off; off >>= 1) mx = fmaxf(mx, __shfl_xor(mx, off));
  float sum = 0.f;
#pragma unroll
  for (int c = 0; c < 8; ++c) {
    float e = __expf(vals[c] - mx);
    vals[c] = e;
    sum += e;
  }
#pragma unroll
  for (int off = 32; off; off >>= 1) sum += __shfl_xor(sum, off);
  float rs = 1.f / sum;
#pragma unroll
  for (int c = 0; c < 8; ++c) {
    int j = lane + (c << 6);
    srow[j] = ok[c] ? f2b(vals[c] * rs) : (u16)0;
  }
}

// ---------------------------------------------------------------------------
// Host launch
// ---------------------------------------------------------------------------
extern "C" void kernel_launch(void* const* d_in, const int* in_sizes, int n_in,
                              void* d_out, int out_size, void* d_ws, size_t ws_size,
                              hipStream_t stream) {
  const float* x       = (const float*)d_in[0];
  const float* mask    = (const float*)d_in[1];
  const float* emb_s   = (const float*)d_in[2];
  const float* emb_b   = (const float*)d_in[3];
  const float* rel_emb = (const float*)d_in[4];
  const float* rel_s   = (const float*)d_in[5];
  const float* rel_b   = (const float*)d_in[6];
  const float* Wq = (const float*)d_in[7];
  const float* bq = (const float*)d_in[8];
  const float* Wk = (const float*)d_in[9];
  const float* bk = (const float*)d_in[10];
  const float* Wv = (const float*)d_in[11];
  const float* bv = (const float*)d_in[12];
  const float* Wo = (const float*)d_in[13];
  const float* bo = (const float*)d_in[14];
  const float* as_ = (const float*)d_in[15];
  const float* ab_ = (const float*)d_in[16];
  const float* Wi = (const float*)d_in[17];
  const float* bi = (const float*)d_in[18];
  const float* Wf = (const float*)d_in[19];
  const float* bf_ = (const float*)d_in[20];
  const float* fs_ = (const float*)d_in[21];
  const float* fb_ = (const float*)d_in[22];
  const float* Wc = (const float*)d_in[23];
  const float* bc = (const float*)d_in[24];
  float* out = (float*)d_out;

  char* p = (char*)d_ws;
  auto alloc = [&](size_t bytes) {
    char* r = p;
    p += (bytes + 255) & ~(size_t)255;
    return r;
  };
  float* hcat = (float*)alloc((size_t)4608 * 512 * 4);  // h | LN(rel_emb), fp32 master
  float* tmpA = (float*)alloc((size_t)4096 * 512 * 4);  // pre-LN fp32
  u16* hbf  = (u16*)alloc((size_t)4608 * 512 * 2);      // bf16 mirror of hcat
  u16* qbf  = (u16*)alloc((size_t)4608 * 512 * 2);      // q | pq
  u16* kbf  = (u16*)alloc((size_t)4608 * 512 * 2);      // k | pk
  u16* vbf  = (u16*)alloc((size_t)4096 * 512 * 2);
  u16* vT   = (u16*)alloc((size_t)64 * 64 * 512 * 2);   // [bh][d][j]
  u16* ctxb = (u16*)alloc((size_t)4096 * 512 * 2);
  u16* mid  = (u16*)alloc((size_t)4096 * 768 * 2);
  u16* WtQ  = (u16*)alloc((size_t)3 * 512 * 512 * 2);
  u16* WtK  = (u16*)alloc((size_t)3 * 512 * 512 * 2);
  u16* WtV  = (u16*)alloc((size_t)3 * 512 * 512 * 2);
  u16* WtO  = (u16*)alloc((size_t)3 * 512 * 512 * 2);
  u16* WtI  = (u16*)alloc((size_t)3 * 768 * 512 * 2);   // [768][512] per layer
  u16* WtF  = (u16*)alloc((size_t)3 * 512 * 768 * 2);   // [512][768] per layer
  u16* WtC  = (u16*)alloc((size_t)100 * 512 * 2);
  u16* Qpk  = (u16*)alloc((size_t)64 * 512 * 512 * 2);  // [bh][i][r]
  u16* Kpq  = (u16*)alloc((size_t)64 * 512 * 512 * 2);  // [bh][j][r]
  u16* scr  = (u16*)alloc((size_t)64 * 512 * 512 * 2);  // scores -> probs in place
  int* c2p  = (int*)alloc((size_t)512 * 512 * 4);

  relbucket_kernel<<<1024, 256, 0, stream>>>(c2p);
  wtrans_kernel<<<dim3(16, 16, 3), 256, 0, stream>>>(Wq, WtQ, 512, 512, 262144, 262144);
  wtrans_kernel<<<dim3(16, 16, 3), 256, 0, stream>>>(Wk, WtK, 512, 512, 262144, 262144);
  wtrans_kernel<<<dim3(16, 16, 3), 256, 0, stream>>>(Wv, WtV, 512, 512, 262144, 262144);
  wtrans_kernel<<<dim3(16, 16, 3), 256, 0, stream>>>(Wo, WtO, 512, 512, 262144, 262144);
  wtrans_kernel<<<dim3(24, 16, 3), 256, 0, stream>>>(Wi, WtI, 512, 768, 393216, 393216);
  wtrans_kernel<<<dim3(16, 24, 3), 256, 0, stream>>>(Wf, WtF, 768, 512, 393216, 393216);
  wtrans_kernel<<<dim3(4, 16, 1), 256, 0, stream>>>(Wc, WtC, 512, 100, 0, 0);
  // h = LN(x)*mask ; rel_e = LN(rel_emb)
  ln_kernel<false, true><<<1024, 256, 0, stream>>>(x, nullptr, emb_s, emb_b, mask,
                                                   hcat, hbf, 4096);
  ln_kernel<false, false><<<128, 256, 0, stream>>>(rel_emb, nullptr, rel_s, rel_b, nullptr,
                                                   hcat + (size_t)4096 * 512,
                                                   hbf + (size_t)4096 * 512, 512);

  for (int l = 0; l < 3; ++l) {
    // q|pq, k|pk (shared weights incl. bias), v
    gemm_bf16<1, u16><<<dim3(8, 72, 1), 256, 0, stream>>>(
        hbf, WtQ + (size_t)l * 262144, bq + l * 512, qbf, 4608, 512, 512,
        512, 512, 512, 0, 0, 0, 0, 0, 0);
    gemm_bf16<1, u16><<<dim3(8, 72, 1), 256, 0, stream>>>(
        hbf, WtK + (size_t)l * 262144, bk + l * 512, kbf, 4608, 512, 512,
        512, 512, 512, 0, 0, 0, 0, 0, 0);
    gemm_bf16<1, u16><<<dim3(8, 64, 1), 256, 0, stream>>>(
        hbf, WtV + (size_t)l * 262144, bv + l * 512, vbf, 4096, 512, 512,
        512, 512, 512, 0, 0, 0, 0, 0, 0);
    vtrans_kernel<<<dim3(16, 2, 64), 256, 0, stream>>>(vbf, vT);
    // Qpk[b,h] = q @ pk^T ; Kpq[b,h] = k @ pq^T ; scores = q @ k^T
    gemm_bf16<0, u16><<<dim3(8, 8, 64), 256, 0, stream>>>(
        qbf, kbf + (size_t)4096 * 512, nullptr, Qpk, 512, 512, 64,
        512, 512, 512, 262144, 64, 0, 64, 2097152, 262144);
    gemm_bf16<0, u16><<<dim3(8, 8, 64), 256, 0, stream>>>(
        kbf, qbf + (size_t)4096 * 512, nullptr, Kpq, 512, 512, 64,
        512, 512, 512, 262144, 64, 0, 64, 2097152, 262144);
    gemm_bf16<0, u16><<<dim3(8, 8, 64), 256, 0, stream>>>(
        qbf, kbf, nullptr, scr, 512, 512, 64,
        512, 512, 512, 262144, 64, 262144, 64, 2097152, 262144);
    softmax_kernel<<<8192, 256, 0, stream>>>(scr, Qpk, Kpq, mask, c2p);
    // ctx = probs @ v  (B = vT[bh][d][j])
    gemm_bf16<0, u16><<<dim3(1, 8, 64), 256, 0, stream>>>(
        scr, vT, nullptr, ctxb, 512, 64, 512,
        512, 512, 512, 2097152, 262144, 262144, 32768, 262144, 64);
    // O proj -> fp32, LN(+h)
    gemm_bf16<1, float><<<dim3(8, 64, 1), 256, 0, stream>>>(
        ctxb, WtO + (size_t)l * 262144, bo + l * 512, tmpA, 4096, 512, 512,
        512, 512, 512, 0, 0, 0, 0, 0, 0);
    ln_kernel<true, false><<<1024, 256, 0, stream>>>(tmpA, hcat, as_ + l * 512, ab_ + l * 512,
                                                     nullptr, hcat, hbf, 4096);
    // FFN
    gemm_bf16<2, u16><<<dim3(12, 64, 1), 256, 0, stream>>>(
        hbf, WtI + (size_t)l * 393216, bi + l * 768, mid, 4096, 768, 512,
        512, 512, 768, 0, 0, 0, 0, 0, 0);
    gemm_bf16<1, float><<<dim3(8, 64, 1), 256, 0, stream>>>(
        mid, WtF + (size_t)l * 393216, bf_ + l * 512, tmpA, 4096, 512, 768,
        768, 768, 512, 0, 0, 0, 0, 0, 0);
    ln_kernel<true, false><<<1024, 256, 0, stream>>>(tmpA, hcat, fs_ + l * 512, fb_ + l * 512,
                                                     nullptr, hcat, hbf, 4096);
  }
  gemm_bf16<1, float><<<dim3(2, 64, 1), 256, 0, stream>>>(
      hbf, WtC, bc, out, 4096, 100, 512, 512, 512, 100, 0, 0, 0, 0, 0, 0);
}

// Round 4
// 635.589 us; speedup vs baseline: 5.5066x; 1.1548x over previous
//
#include <hip/hip_runtime.h>
#include <hip/hip_bf16.h>
#include <math.h>

// B=8, S=512, HID=512, HEADS=8, DH=64, FF=768, NL=3, SPAN=256, MAXP=512, VOCAB=100
#define EPS_LN 1e-7f
#define INV_SCALE 0.072168783648703221f   // 1/sqrt(64*3)
#define NEGMAX -3.402823466e38f

typedef unsigned short u16;
typedef __attribute__((ext_vector_type(8))) short bf16x8;  // 8 bf16 = 4 VGPRs
typedef __attribute__((ext_vector_type(4))) float f32x4;

__device__ __forceinline__ u16 f2b(float f) {
  union { float f; unsigned int u; } v; v.f = f;
  unsigned int r = v.u + 0x7FFFu + ((v.u >> 16) & 1u);
  return (u16)(r >> 16);
}
__device__ __forceinline__ float b2f(u16 u) {
  union { unsigned int u; float f; } v; v.u = ((unsigned int)u) << 16;
  return v.f;
}
__device__ __forceinline__ float gelu_exact(float v) {
  return 0.5f * v * (1.f + erff(v * 0.70710678118654752440f));
}

// ---------------------------------------------------------------------------
// Relative-position bucket, collapsed to 1-D: idx depends only on rel = i-j.
// crel[rel+511] = clip(bucket(rel)+256, 0, 511), rel in [-511,511].
// (p2c gather uses the same table: p2c_idx[j][i] == c2p_idx[i][j].)
// ---------------------------------------------------------------------------
__global__ __launch_bounds__(256) void relbucket_kernel(int* __restrict__ crel) {
  int idx = blockIdx.x * 256 + threadIdx.x;
  if (idx >= 1023) return;
  int rel = idx - 511;
  int a = (rel < 128 && rel > -128) ? 127 : (rel < 0 ? -rel : rel);
  int bucket;
  if (a <= 128) {
    bucket = rel;
  } else {
    double lp = ceil(log((double)a / 128.0) / log(511.0 / 128.0) * 127.0) + 128.0;
    int l = (int)lp;
    bucket = (rel > 0) ? l : -l;
  }
  int c = bucket + 256;
  c = c < 0 ? 0 : (c > 511 ? 511 : c);
  crel[idx] = c;
}

// ---------------------------------------------------------------------------
// LayerNorm over 512 cols; writes fp32 master and optional bf16 mirror.
// ---------------------------------------------------------------------------
template <bool RESID, bool MASK>
__global__ __launch_bounds__(256) void ln_kernel(const float* __restrict__ x,
                                                 const float* __restrict__ res,
                                                 const float* __restrict__ gam,
                                                 const float* __restrict__ bet,
                                                 const float* __restrict__ mask,
                                                 float* __restrict__ out,
                                                 u16* __restrict__ outb, int nrows) {
  int w = threadIdx.x >> 6, ln = threadIdx.x & 63;
  int row = blockIdx.x * 4 + w;
  if (row >= nrows) return;
  const float* xr = x + (size_t)row * 512;
  float v[8];
#pragma unroll
  for (int c = 0; c < 2; ++c) {
    float4 a = *(const float4*)(xr + (ln << 3) + (c << 2));
    v[c * 4 + 0] = a.x; v[c * 4 + 1] = a.y; v[c * 4 + 2] = a.z; v[c * 4 + 3] = a.w;
    if (RESID) {
      float4 r4 = *(const float4*)(res + (size_t)row * 512 + (ln << 3) + (c << 2));
      v[c * 4 + 0] += r4.x; v[c * 4 + 1] += r4.y; v[c * 4 + 2] += r4.z; v[c * 4 + 3] += r4.w;
    }
  }
  float sum = 0.f;
#pragma unroll
  for (int c = 0; c < 8; ++c) sum += v[c];
#pragma unroll
  for (int off = 32; off; off >>= 1) sum += __shfl_xor(sum, off);
  float mu = sum * (1.f / 512.f);
  float vs = 0.f;
#pragma unroll
  for (int c = 0; c < 8; ++c) { float d = v[c] - mu; vs += d * d; }
#pragma unroll
  for (int off = 32; off; off >>= 1) vs += __shfl_xor(vs, off);
  float rstd = 1.f / sqrtf(vs * (1.f / 512.f) + EPS_LN);
  float mk = MASK ? mask[row] : 1.f;
  float* orow = out + (size_t)row * 512;
  u16* brow = outb ? outb + (size_t)row * 512 : nullptr;
#pragma unroll
  for (int c = 0; c < 2; ++c) {
    int col = (ln << 3) + (c << 2);
    float o[4];
#pragma unroll
    for (int q = 0; q < 4; ++q)
      o[q] = ((v[c * 4 + q] - mu) * rstd * gam[col + q] + bet[col + q]) * mk;
    *(float4*)(orow + col) = make_float4(o[0], o[1], o[2], o[3]);
    if (brow) {
      ushort4 ob = { f2b(o[0]), f2b(o[1]), f2b(o[2]), f2b(o[3]) };
      *(ushort4*)(brow + col) = ob;
    }
  }
}

// ---------------------------------------------------------------------------
// Weight transpose + bf16 cast: W f32 [K][N] row-major -> Wt bf16 [N][K].
// ---------------------------------------------------------------------------
__global__ __launch_bounds__(256) void wtrans_kernel(const float* __restrict__ W,
                                                     u16* __restrict__ Wt,
                                                     int K, int N, long wstride, long tstride) {
  __shared__ float tl[32][33];
  int z = blockIdx.z;
  W += (size_t)z * wstride;
  Wt += (size_t)z * tstride;
  int n0 = blockIdx.x * 32, k0 = blockIdx.y * 32;
  int c = threadIdx.x & 31, r8 = threadIdx.x >> 5;
#pragma unroll
  for (int p = 0; p < 4; ++p) {
    int r = r8 + p * 8;
    int k = k0 + r, n = n0 + c;
    tl[r][c] = (k < K && n < N) ? W[(size_t)k * N + n] : 0.f;
  }
  __syncthreads();
#pragma unroll
  for (int p = 0; p < 4; ++p) {
    int r = r8 + p * 8;
    int n = n0 + r, k = k0 + c;
    if (n < N && k < K) Wt[(size_t)n * K + k] = f2b(tl[c][r]);
  }
}

// ---------------------------------------------------------------------------
// V transpose: vbf [4096][512] bf16 -> vT [64(bh)][64(d)][512(j)] bf16.
// ---------------------------------------------------------------------------
__global__ __launch_bounds__(256) void vtrans_kernel(const u16* __restrict__ vbf,
                                                     u16* __restrict__ vT) {
  __shared__ u16 tl[32][33];
  int z = blockIdx.z;  // b*8+h
  int b = z >> 3, h = z & 7;
  int j0 = blockIdx.x * 32, d0 = blockIdx.y * 32;
  int c = threadIdx.x & 31, r8 = threadIdx.x >> 5;
#pragma unroll
  for (int p = 0; p < 4; ++p) {
    int r = r8 + p * 8;
    tl[r][c] = vbf[(size_t)(b * 512 + j0 + r) * 512 + h * 64 + d0 + c];
  }
  __syncthreads();
#pragma unroll
  for (int p = 0; p < 4; ++p) {
    int r = r8 + p * 8;
    vT[(size_t)z * 32768 + (size_t)(d0 + r) * 512 + j0 + c] = tl[c][r];
  }
}

// ---------------------------------------------------------------------------
// bf16 MFMA GEMM: C[M,N] = A[M,K] @ B[N,K]^T (+bias, +gelu).
// 64x64 tile, BK=64, 4 waves (2x2), mfma_f32_16x16x32_bf16.
// ---------------------------------------------------------------------------
template <int EPI, typename CT>
__global__ __launch_bounds__(256) void gemm_bf16(const u16* __restrict__ A,
                                                 const u16* __restrict__ B,
                                                 const float* __restrict__ bias,
                                                 CT* __restrict__ C,
                                                 int M, int N, int K,
                                                 int lda, int ldb, int ldc,
                                                 long sAb, long sAh, long sBb, long sBh,
                                                 long sCb, long sCh) {
  __shared__ u16 As[64][72];
  __shared__ u16 Bs[64][72];
  int t = threadIdx.x;
  int z = blockIdx.z, zb = z >> 3, zh = z & 7;
  A += (size_t)zb * sAb + (size_t)zh * sAh;
  B += (size_t)zb * sBb + (size_t)zh * sBh;
  C += (size_t)zb * sCb + (size_t)zh * sCh;
  int m0 = blockIdx.y * 64, n0 = blockIdx.x * 64;
  int w = t >> 6, l = t & 63;
  int wr = w >> 1, wc = w & 1, lr = l & 15, kg = l >> 4;
  f32x4 acc[2][2] = {};
  for (int k0 = 0; k0 < K; k0 += 64) {
#pragma unroll
    for (int p = 0; p < 2; ++p) {
      int c = t + (p << 8);
      int row = c >> 3, q = c & 7;
      uint4 av = *(const uint4*)(A + (size_t)(m0 + row) * lda + k0 + q * 8);
      *(uint4*)(&As[row][q * 8]) = av;
      uint4 bv = make_uint4(0u, 0u, 0u, 0u);
      if (n0 + row < N) bv = *(const uint4*)(B + (size_t)(n0 + row) * ldb + k0 + q * 8);
      *(uint4*)(&Bs[row][q * 8]) = bv;
    }
    __syncthreads();
#pragma unroll
    for (int s = 0; s < 2; ++s) {
      bf16x8 a0 = *(const bf16x8*)(&As[wr * 32 + lr][kg * 8 + s * 32]);
      bf16x8 a1 = *(const bf16x8*)(&As[wr * 32 + 16 + lr][kg * 8 + s * 32]);
      bf16x8 b0 = *(const bf16x8*)(&Bs[wc * 32 + lr][kg * 8 + s * 32]);
      bf16x8 b1 = *(const bf16x8*)(&Bs[wc * 32 + 16 + lr][kg * 8 + s * 32]);
      acc[0][0] = __builtin_amdgcn_mfma_f32_16x16x32_bf16(a0, b0, acc[0][0], 0, 0, 0);
      acc[0][1] = __builtin_amdgcn_mfma_f32_16x16x32_bf16(a0, b1, acc[0][1], 0, 0, 0);
      acc[1][0] = __builtin_amdgcn_mfma_f32_16x16x32_bf16(a1, b0, acc[1][0], 0, 0, 0);
      acc[1][1] = __builtin_amdgcn_mfma_f32_16x16x32_bf16(a1, b1, acc[1][1], 0, 0, 0);
    }
    __syncthreads();
  }
#pragma unroll
  for (int m = 0; m < 2; ++m)
#pragma unroll
    for (int n = 0; n < 2; ++n) {
      int col = n0 + wc * 32 + n * 16 + lr;
      if (col < N) {
        float bv = (EPI >= 1) ? bias[col] : 0.f;
#pragma unroll
        for (int r = 0; r < 4; ++r) {
          int row = m0 + wr * 32 + m * 16 + kg * 4 + r;
          float v = acc[m][n][r] + bv;
          if (EPI == 2) v = gelu_exact(v);
          if constexpr (sizeof(CT) == 2) {
            ((u16*)C)[(size_t)row * ldc + col] = f2b(v);
          } else {
            ((float*)C)[(size_t)row * ldc + col] = v;
          }
        }
      }
    }
}

// ---------------------------------------------------------------------------
// Fused disentangled attention (flash-style, full-S online softmax).
// Block = (i-tile of 64, z=b*8+h). 4 waves; wave w owns q-rows w*16..w*16+15.
// logit(i,j) = (q.k + Qpk[i][f(i-j)] + KpqT[f(i-j)][j]) / SCALE, XSoftmax, @V.
// ---------------------------------------------------------------------------
__global__ __launch_bounds__(256) void attn_fused(const u16* __restrict__ qbf,
                                                  const u16* __restrict__ kbf,
                                                  const u16* __restrict__ vT,
                                                  const u16* __restrict__ Qpk,
                                                  const u16* __restrict__ KpqT,
                                                  const float* __restrict__ mask,
                                                  const int* __restrict__ crel,
                                                  u16* __restrict__ ctx) {
  __shared__ u16 qs[64][72];
  __shared__ u16 ks[64][72];
  __shared__ u16 vs[64][72];
  __shared__ u16 ps[4][16][72];
  __shared__ int crl[1024];
  int t = threadIdx.x;
  int it = blockIdx.x;       // 0..7
  int z = blockIdx.y;        // b*8+h
  int b = z >> 3, h = z & 7;
  int i0 = it * 64;
  int w = t >> 6, l = t & 63;
  int lr = l & 15, kg = l >> 4;

  for (int c = t; c < 1023; c += 256) crl[c] = crel[c];
  for (int c = t; c < 512; c += 256) {  // 512 chunks of 16B
    int row = c >> 3, off = (c & 7) * 8;
    *(uint4*)(&qs[row][off]) =
        *(const uint4*)(qbf + (size_t)(b * 512 + i0 + row) * 512 + h * 64 + off);
  }
  __syncthreads();
  bf16x8 qa0 = *(const bf16x8*)(&qs[w * 16 + lr][kg * 8]);
  bf16x8 qa1 = *(const bf16x8*)(&qs[w * 16 + lr][kg * 8 + 32]);

  float m_run[4], s_run[4];
  f32x4 o[4] = {};
  float mi[4];
#pragma unroll
  for (int r = 0; r < 4; ++r) {
    m_run[r] = NEGMAX;
    s_run[r] = 0.f;
    mi[r] = mask[b * 512 + i0 + w * 16 + kg * 4 + r];
  }
  const u16* qpk_base = Qpk + (size_t)z * 262144;   // [i][bucket]
  const u16* kpq_base = KpqT + (size_t)z * 262144;  // [bucket][j]

  for (int jt = 0; jt < 8; ++jt) {
    int j0 = jt * 64;
    __syncthreads();
    for (int c = t; c < 512; c += 256) {
      int row = c >> 3, off = (c & 7) * 8;
      *(uint4*)(&ks[row][off]) =
          *(const uint4*)(kbf + (size_t)(b * 512 + j0 + row) * 512 + h * 64 + off);
      *(uint4*)(&vs[row][off]) =
          *(const uint4*)(vT + (size_t)z * 32768 + (size_t)row * 512 + j0 + off);
    }
    __syncthreads();
    // scores: 4 n-frags of 16 cols
    f32x4 sc[4];
#pragma unroll
    for (int nf = 0; nf < 4; ++nf) {
      bf16x8 kb0 = *(const bf16x8*)(&ks[nf * 16 + lr][kg * 8]);
      bf16x8 kb1 = *(const bf16x8*)(&ks[nf * 16 + lr][kg * 8 + 32]);
      f32x4 a = {};
      a = __builtin_amdgcn_mfma_f32_16x16x32_bf16(qa0, kb0, a, 0, 0, 0);
      a = __builtin_amdgcn_mfma_f32_16x16x32_bf16(qa1, kb1, a, 0, 0, 0);
      sc[nf] = a;
    }
    // bias gather + mask + online softmax
    float mj[4];
#pragma unroll
    for (int nf = 0; nf < 4; ++nf) mj[nf] = mask[b * 512 + j0 + nf * 16 + lr];
    float lgv[4][4];
    bool ok[4][4];
    float tmax[4] = {NEGMAX, NEGMAX, NEGMAX, NEGMAX};
#pragma unroll
    for (int nf = 0; nf < 4; ++nf) {
      int j = j0 + nf * 16 + lr;
#pragma unroll
      for (int r = 0; r < 4; ++r) {
        int i = i0 + w * 16 + kg * 4 + r;
        int idx = crl[i - j + 511];
        float bias = b2f(qpk_base[(size_t)i * 512 + idx]) +
                     b2f(kpq_base[(size_t)idx * 512 + j]);
        bool o_ = (mi[r] * mj[nf]) > 0.f;
        float v = o_ ? (sc[nf][r] + bias) * INV_SCALE : NEGMAX;
        ok[nf][r] = o_;
        lgv[nf][r] = v;
        tmax[r] = fmaxf(tmax[r], v);
      }
    }
#pragma unroll
    for (int r = 0; r < 4; ++r) {
#pragma unroll
      for (int off = 8; off; off >>= 1) tmax[r] = fmaxf(tmax[r], __shfl_xor(tmax[r], off));
    }
    float tsum[4];
#pragma unroll
    for (int r = 0; r < 4; ++r) {
      float mn = fmaxf(m_run[r], tmax[r]);
      float scale = (mn <= -1e37f) ? 1.f : __expf(m_run[r] - mn);
      m_run[r] = mn;
      s_run[r] *= scale;
      o[0][r] *= scale; o[1][r] *= scale; o[2][r] *= scale; o[3][r] *= scale;
      float ls = 0.f;
#pragma unroll
      for (int nf = 0; nf < 4; ++nf) {
        float p = ok[nf][r] ? __expf(lgv[nf][r] - mn) : 0.f;
        lgv[nf][r] = p;
        ls += p;
      }
      tsum[r] = ls;
    }
#pragma unroll
    for (int r = 0; r < 4; ++r) {
#pragma unroll
      for (int off = 8; off; off >>= 1) tsum[r] += __shfl_xor(tsum[r], off);
      s_run[r] += tsum[r];
    }
    // P (C/D layout) -> LDS -> A-frag layout
#pragma unroll
    for (int nf = 0; nf < 4; ++nf)
#pragma unroll
      for (int r = 0; r < 4; ++r) ps[w][kg * 4 + r][nf * 16 + lr] = f2b(lgv[nf][r]);
    bf16x8 pa0 = *(const bf16x8*)(&ps[w][lr][kg * 8]);
    bf16x8 pa1 = *(const bf16x8*)(&ps[w][lr][kg * 8 + 32]);
    // PV accumulate
#pragma unroll
    for (int nf = 0; nf < 4; ++nf) {
      bf16x8 vb0 = *(const bf16x8*)(&vs[nf * 16 + lr][kg * 8]);
      bf16x8 vb1 = *(const bf16x8*)(&vs[nf * 16 + lr][kg * 8 + 32]);
      o[nf] = __builtin_amdgcn_mfma_f32_16x16x32_bf16(pa0, vb0, o[nf], 0, 0, 0);
      o[nf] = __builtin_amdgcn_mfma_f32_16x16x32_bf16(pa1, vb1, o[nf], 0, 0, 0);
    }
  }
#pragma unroll
  for (int r = 0; r < 4; ++r) {
    float inv = (s_run[r] > 0.f) ? 1.f / s_run[r] : 0.f;
    int i = i0 + w * 16 + kg * 4 + r;
#pragma unroll
    for (int nf = 0; nf < 4; ++nf)
      ctx[(size_t)(b * 512 + i) * 512 + h * 64 + nf * 16 + lr] = f2b(o[nf][r] * inv);
  }
}

// ---------------------------------------------------------------------------
// Host launch
// ---------------------------------------------------------------------------
extern "C" void kernel_launch(void* const* d_in, const int* in_sizes, int n_in,
                              void* d_out, int out_size, void* d_ws, size_t ws_size,
                              hipStream_t stream) {
  const float* x       = (const float*)d_in[0];
  const float* mask    = (const float*)d_in[1];
  const float* emb_s   = (const float*)d_in[2];
  const float* emb_b   = (const float*)d_in[3];
  const float* rel_emb = (const float*)d_in[4];
  const float* rel_s   = (const float*)d_in[5];
  const float* rel_b   = (const float*)d_in[6];
  const float* Wq = (const float*)d_in[7];
  const float* bq = (const float*)d_in[8];
  const float* Wk = (const float*)d_in[9];
  const float* bk = (const float*)d_in[10];
  const float* Wv = (const float*)d_in[11];
  const float* bv = (const float*)d_in[12];
  const float* Wo = (const float*)d_in[13];
  const float* bo = (const float*)d_in[14];
  const float* as_ = (const float*)d_in[15];
  const float* ab_ = (const float*)d_in[16];
  const float* Wi = (const float*)d_in[17];
  const float* bi = (const float*)d_in[18];
  const float* Wf = (const float*)d_in[19];
  const float* bf_ = (const float*)d_in[20];
  const float* fs_ = (const float*)d_in[21];
  const float* fb_ = (const float*)d_in[22];
  const float* Wc = (const float*)d_in[23];
  const float* bc = (const float*)d_in[24];
  float* out = (float*)d_out;

  char* p = (char*)d_ws;
  auto alloc = [&](size_t bytes) {
    char* r = p;
    p += (bytes + 255) & ~(size_t)255;
    return r;
  };
  float* hcat = (float*)alloc((size_t)4608 * 512 * 4);
  float* tmpA = (float*)alloc((size_t)4096 * 512 * 4);
  u16* hbf  = (u16*)alloc((size_t)4608 * 512 * 2);
  u16* qbf  = (u16*)alloc((size_t)4608 * 512 * 2);      // q | pq
  u16* kbf  = (u16*)alloc((size_t)4608 * 512 * 2);      // k | pk
  u16* vbf  = (u16*)alloc((size_t)4096 * 512 * 2);
  u16* vT   = (u16*)alloc((size_t)64 * 64 * 512 * 2);   // [bh][d][j]
  u16* ctxb = (u16*)alloc((size_t)4096 * 512 * 2);
  u16* mid  = (u16*)alloc((size_t)4096 * 768 * 2);
  u16* WtQ  = (u16*)alloc((size_t)3 * 512 * 512 * 2);
  u16* WtK  = (u16*)alloc((size_t)3 * 512 * 512 * 2);
  u16* WtV  = (u16*)alloc((size_t)3 * 512 * 512 * 2);
  u16* WtO  = (u16*)alloc((size_t)3 * 512 * 512 * 2);
  u16* WtI  = (u16*)alloc((size_t)3 * 768 * 512 * 2);
  u16* WtF  = (u16*)alloc((size_t)3 * 512 * 768 * 2);
  u16* WtC  = (u16*)alloc((size_t)100 * 512 * 2);
  u16* Qpk  = (u16*)alloc((size_t)64 * 512 * 512 * 2);  // [bh][i][bucket]
  u16* KpqT = (u16*)alloc((size_t)64 * 512 * 512 * 2);  // [bh][bucket][j]
  int* crel = (int*)alloc((size_t)1024 * 4);

  relbucket_kernel<<<4, 256, 0, stream>>>(crel);
  wtrans_kernel<<<dim3(16, 16, 3), 256, 0, stream>>>(Wq, WtQ, 512, 512, 262144, 262144);
  wtrans_kernel<<<dim3(16, 16, 3), 256, 0, stream>>>(Wk, WtK, 512, 512, 262144, 262144);
  wtrans_kernel<<<dim3(16, 16, 3), 256, 0, stream>>>(Wv, WtV, 512, 512, 262144, 262144);
  wtrans_kernel<<<dim3(16, 16, 3), 256, 0, stream>>>(Wo, WtO, 512, 512, 262144, 262144);
  wtrans_kernel<<<dim3(24, 16, 3), 256, 0, stream>>>(Wi, WtI, 512, 768, 393216, 393216);
  wtrans_kernel<<<dim3(16, 24, 3), 256, 0, stream>>>(Wf, WtF, 768, 512, 393216, 393216);
  wtrans_kernel<<<dim3(4, 16, 1), 256, 0, stream>>>(Wc, WtC, 512, 100, 0, 0);
  ln_kernel<false, true><<<1024, 256, 0, stream>>>(x, nullptr, emb_s, emb_b, mask,
                                                   hcat, hbf, 4096);
  ln_kernel<false, false><<<128, 256, 0, stream>>>(rel_emb, nullptr, rel_s, rel_b, nullptr,
                                                   hcat + (size_t)4096 * 512,
                                                   hbf + (size_t)4096 * 512, 512);

  for (int l = 0; l < 3; ++l) {
    // q|pq, k|pk (shared weights incl. bias), v
    gemm_bf16<1, u16><<<dim3(8, 72, 1), 256, 0, stream>>>(
        hbf, WtQ + (size_t)l * 262144, bq + l * 512, qbf, 4608, 512, 512,
        512, 512, 512, 0, 0, 0, 0, 0, 0);
    gemm_bf16<1, u16><<<dim3(8, 72, 1), 256, 0, stream>>>(
        hbf, WtK + (size_t)l * 262144, bk + l * 512, kbf, 4608, 512, 512,
        512, 512, 512, 0, 0, 0, 0, 0, 0);
    gemm_bf16<1, u16><<<dim3(8, 64, 1), 256, 0, stream>>>(
        hbf, WtV + (size_t)l * 262144, bv + l * 512, vbf, 4096, 512, 512,
        512, 512, 512, 0, 0, 0, 0, 0, 0);
    vtrans_kernel<<<dim3(16, 2, 64), 256, 0, stream>>>(vbf, vT);
    // Qpk[b,h][i][r] = q @ pk^T ; KpqT[b,h][r][j] = pq @ k^T (swapped operands)
    gemm_bf16<0, u16><<<dim3(8, 8, 64), 256, 0, stream>>>(
        qbf, kbf + (size_t)4096 * 512, nullptr, Qpk, 512, 512, 64,
        512, 512, 512, 262144, 64, 0, 64, 2097152, 262144);
    gemm_bf16<0, u16><<<dim3(8, 8, 64), 256, 0, stream>>>(
        qbf + (size_t)4096 * 512, kbf, nullptr, KpqT, 512, 512, 64,
        512, 512, 512, 0, 64, 262144, 64, 2097152, 262144);
    // fused QK^T + bias + XSoftmax + PV
    attn_fused<<<dim3(8, 64), 256, 0, stream>>>(qbf, kbf, vT, Qpk, KpqT, mask, crel, ctxb);
    // O proj -> fp32, LN(+h)
    gemm_bf16<1, float><<<dim3(8, 64, 1), 256, 0, stream>>>(
        ctxb, WtO + (size_t)l * 262144, bo + l * 512, tmpA, 4096, 512, 512,
        512, 512, 512, 0, 0, 0, 0, 0, 0);
    ln_kernel<true, false><<<1024, 256, 0, stream>>>(tmpA, hcat, as_ + l * 512, ab_ + l * 512,
                                                     nullptr, hcat, hbf, 4096);
    // FFN
    gemm_bf16<2, u16><<<dim3(12, 64, 1), 256, 0, stream>>>(
        hbf, WtI + (size_t)l * 393216, bi + l * 768, mid, 4096, 768, 512,
        512, 512, 768, 0, 0, 0, 0, 0, 0);
    gemm_bf16<1, float><<<dim3(8, 64, 1), 256, 0, stream>>>(
        mid, WtF + (size_t)l * 393216, bf_ + l * 512, tmpA, 4096, 512, 768,
        768, 768, 512, 0, 0, 0, 0, 0, 0);
    ln_kernel<true, false><<<1024, 256, 0, stream>>>(tmpA, hcat, fs_ + l * 512, fb_ + l * 512,
                                                     nullptr, hcat, hbf, 4096);
  }
  gemm_bf16<1, float><<<dim3(2, 64, 1), 256, 0, stream>>>(
      hbf, WtC, bc, out, 4096, 100, 512, 512, 512, 100, 0, 0, 0, 0, 0, 0);
}

// Round 6
// 616.321 us; speedup vs baseline: 5.6787x; 1.0313x over previous
//
#include <hip/hip_runtime.h>
#include <hip/hip_bf16.h>
#include <math.h>

// B=8, S=512, HID=512, HEADS=8, DH=64, FF=768, NL=3, SPAN=256, MAXP=512, VOCAB=100
#define EPS_LN 1e-7f
#define INV_SCALE 0.072168783648703221f   // 1/sqrt(64*3)
#define NEGMAX -3.402823466e38f

typedef unsigned short u16;
typedef __attribute__((ext_vector_type(8))) short bf16x8;  // 8 bf16 = 4 VGPRs
typedef __attribute__((ext_vector_type(4))) float f32x4;

__device__ __forceinline__ u16 f2b(float f) {
  union { float f; unsigned int u; } v; v.f = f;
  unsigned int r = v.u + 0x7FFFu + ((v.u >> 16) & 1u);
  return (u16)(r >> 16);
}
__device__ __forceinline__ float b2f(u16 u) {
  union { unsigned int u; float f; } v; v.u = ((unsigned int)u) << 16;
  return v.f;
}
__device__ __forceinline__ float gelu_exact(float v) {
  return 0.5f * v * (1.f + erff(v * 0.70710678118654752440f));
}

// ---------------------------------------------------------------------------
// Relative-position bucket, collapsed to 1-D: idx depends only on rel = i-j.
// crel[rel+511] = clip(bucket(rel)+256, 0, 511), rel in [-511,511].
// Monotone nondecreasing in rel, |step| <= 1 -> any 127-wide rel window maps
// to a <=127-wide contiguous idx window (used for LDS staging in attn).
// ---------------------------------------------------------------------------
__global__ __launch_bounds__(256) void relbucket_kernel(int* __restrict__ crel) {
  int idx = blockIdx.x * 256 + threadIdx.x;
  if (idx >= 1023) return;
  int rel = idx - 511;
  int a = (rel < 128 && rel > -128) ? 127 : (rel < 0 ? -rel : rel);
  int bucket;
  if (a <= 128) {
    bucket = rel;
  } else {
    double lp = ceil(log((double)a / 128.0) / log(511.0 / 128.0) * 127.0) + 128.0;
    int l = (int)lp;
    bucket = (rel > 0) ? l : -l;
  }
  int c = bucket + 256;
  c = c < 0 ? 0 : (c > 511 ? 511 : c);
  crel[idx] = c;
}

// ---------------------------------------------------------------------------
// LayerNorm over 512 cols; writes fp32 master and optional bf16 mirror.
// ---------------------------------------------------------------------------
template <bool RESID, bool MASK>
__global__ __launch_bounds__(256) void ln_kernel(const float* __restrict__ x,
                                                 const float* __restrict__ res,
                                                 const float* __restrict__ gam,
                                                 const float* __restrict__ bet,
                                                 const float* __restrict__ mask,
                                                 float* __restrict__ out,
                                                 u16* __restrict__ outb, int nrows) {
  int w = threadIdx.x >> 6, ln = threadIdx.x & 63;
  int row = blockIdx.x * 4 + w;
  if (row >= nrows) return;
  const float* xr = x + (size_t)row * 512;
  float v[8];
#pragma unroll
  for (int c = 0; c < 2; ++c) {
    float4 a = *(const float4*)(xr + (ln << 3) + (c << 2));
    v[c * 4 + 0] = a.x; v[c * 4 + 1] = a.y; v[c * 4 + 2] = a.z; v[c * 4 + 3] = a.w;
    if (RESID) {
      float4 r4 = *(const float4*)(res + (size_t)row * 512 + (ln << 3) + (c << 2));
      v[c * 4 + 0] += r4.x; v[c * 4 + 1] += r4.y; v[c * 4 + 2] += r4.z; v[c * 4 + 3] += r4.w;
    }
  }
  float sum = 0.f;
#pragma unroll
  for (int c = 0; c < 8; ++c) sum += v[c];
#pragma unroll
  for (int off = 32; off; off >>= 1) sum += __shfl_xor(sum, off);
  float mu = sum * (1.f / 512.f);
  float vs = 0.f;
#pragma unroll
  for (int c = 0; c < 8; ++c) { float d = v[c] - mu; vs += d * d; }
#pragma unroll
  for (int off = 32; off; off >>= 1) vs += __shfl_xor(vs, off);
  float rstd = 1.f / sqrtf(vs * (1.f / 512.f) + EPS_LN);
  float mk = MASK ? mask[row] : 1.f;
  float* orow = out + (size_t)row * 512;
  u16* brow = outb ? outb + (size_t)row * 512 : nullptr;
#pragma unroll
  for (int c = 0; c < 2; ++c) {
    int col = (ln << 3) + (c << 2);
    float o[4];
#pragma unroll
    for (int q = 0; q < 4; ++q)
      o[q] = ((v[c * 4 + q] - mu) * rstd * gam[col + q] + bet[col + q]) * mk;
    *(float4*)(orow + col) = make_float4(o[0], o[1], o[2], o[3]);
    if (brow) {
      ushort4 ob = { f2b(o[0]), f2b(o[1]), f2b(o[2]), f2b(o[3]) };
      *(ushort4*)(brow + col) = ob;
    }
  }
}

// ---------------------------------------------------------------------------
// Weight transpose + bf16 cast: W f32 [K][N] row-major -> Wt bf16 [N][K].
// ---------------------------------------------------------------------------
__global__ __launch_bounds__(256) void wtrans_kernel(const float* __restrict__ W,
                                                     u16* __restrict__ Wt,
                                                     int K, int N, long wstride, long tstride) {
  __shared__ float tl[32][33];
  int z = blockIdx.z;
  W += (size_t)z * wstride;
  Wt += (size_t)z * tstride;
  int n0 = blockIdx.x * 32, k0 = blockIdx.y * 32;
  int c = threadIdx.x & 31, r8 = threadIdx.x >> 5;
#pragma unroll
  for (int p = 0; p < 4; ++p) {
    int r = r8 + p * 8;
    int k = k0 + r, n = n0 + c;
    tl[r][c] = (k < K && n < N) ? W[(size_t)k * N + n] : 0.f;
  }
  __syncthreads();
#pragma unroll
  for (int p = 0; p < 4; ++p) {
    int r = r8 + p * 8;
    int n = n0 + r, k = k0 + c;
    if (n < N && k < K) Wt[(size_t)n * K + k] = f2b(tl[c][r]);
  }
}

// ---------------------------------------------------------------------------
// V transpose: vbf [4096][512] bf16 -> vT [64(bh)][64(d)][512(j)] bf16.
// ---------------------------------------------------------------------------
__global__ __launch_bounds__(256) void vtrans_kernel(const u16* __restrict__ vbf,
                                                     u16* __restrict__ vT) {
  __shared__ u16 tl[32][33];
  int z = blockIdx.z;  // b*8+h
  int b = z >> 3, h = z & 7;
  int j0 = blockIdx.x * 32, d0 = blockIdx.y * 32;
  int c = threadIdx.x & 31, r8 = threadIdx.x >> 5;
#pragma unroll
  for (int p = 0; p < 4; ++p) {
    int r = r8 + p * 8;
    tl[r][c] = vbf[(size_t)(b * 512 + j0 + r) * 512 + h * 64 + d0 + c];
  }
  __syncthreads();
#pragma unroll
  for (int p = 0; p < 4; ++p) {
    int r = r8 + p * 8;
    vT[(size_t)z * 32768 + (size_t)(d0 + r) * 512 + j0 + c] = tl[c][r];
  }
}

// ---------------------------------------------------------------------------
// bf16 MFMA GEMM: C[M,N] = A[M,K] @ B[N,K]^T (+bias, +gelu).
// 64x64 tile, BK=64, 4 waves (2x2), mfma_f32_16x16x32_bf16.
// ---------------------------------------------------------------------------
template <int EPI, typename CT>
__global__ __launch_bounds__(256) void gemm_bf16(const u16* __restrict__ A,
                                                 const u16* __restrict__ B,
                                                 const float* __restrict__ bias,
                                                 CT* __restrict__ C,
                                                 int M, int N, int K,
                                                 int lda, int ldb, int ldc,
                                                 long sAb, long sAh, long sBb, long sBh,
                                                 long sCb, long sCh) {
  __shared__ u16 As[64][72];
  __shared__ u16 Bs[64][72];
  int t = threadIdx.x;
  int z = blockIdx.z, zb = z >> 3, zh = z & 7;
  A += (size_t)zb * sAb + (size_t)zh * sAh;
  B += (size_t)zb * sBb + (size_t)zh * sBh;
  C += (size_t)zb * sCb + (size_t)zh * sCh;
  int m0 = blockIdx.y * 64, n0 = blockIdx.x * 64;
  int w = t >> 6, l = t & 63;
  int wr = w >> 1, wc = w & 1, lr = l & 15, kg = l >> 4;
  f32x4 acc[2][2] = {};
  for (int k0 = 0; k0 < K; k0 += 64) {
#pragma unroll
    for (int p = 0; p < 2; ++p) {
      int c = t + (p << 8);
      int row = c >> 3, q = c & 7;
      uint4 av = *(const uint4*)(A + (size_t)(m0 + row) * lda + k0 + q * 8);
      *(uint4*)(&As[row][q * 8]) = av;
      uint4 bv = make_uint4(0u, 0u, 0u, 0u);
      if (n0 + row < N) bv = *(const uint4*)(B + (size_t)(n0 + row) * ldb + k0 + q * 8);
      *(uint4*)(&Bs[row][q * 8]) = bv;
    }
    __syncthreads();
#pragma unroll
    for (int s = 0; s < 2; ++s) {
      bf16x8 a0 = *(const bf16x8*)(&As[wr * 32 + lr][kg * 8 + s * 32]);
      bf16x8 a1 = *(const bf16x8*)(&As[wr * 32 + 16 + lr][kg * 8 + s * 32]);
      bf16x8 b0 = *(const bf16x8*)(&Bs[wc * 32 + lr][kg * 8 + s * 32]);
      bf16x8 b1 = *(const bf16x8*)(&Bs[wc * 32 + 16 + lr][kg * 8 + s * 32]);
      acc[0][0] = __builtin_amdgcn_mfma_f32_16x16x32_bf16(a0, b0, acc[0][0], 0, 0, 0);
      acc[0][1] = __builtin_amdgcn_mfma_f32_16x16x32_bf16(a0, b1, acc[0][1], 0, 0, 0);
      acc[1][0] = __builtin_amdgcn_mfma_f32_16x16x32_bf16(a1, b0, acc[1][0], 0, 0, 0);
      acc[1][1] = __builtin_amdgcn_mfma_f32_16x16x32_bf16(a1, b1, acc[1][1], 0, 0, 0);
    }
    __syncthreads();
  }
#pragma unroll
  for (int m = 0; m < 2; ++m)
#pragma unroll
    for (int n = 0; n < 2; ++n) {
      int col = n0 + wc * 32 + n * 16 + lr;
      if (col < N) {
        float bv = (EPI >= 1) ? bias[col] : 0.f;
#pragma unroll
        for (int r = 0; r < 4; ++r) {
          int row = m0 + wr * 32 + m * 16 + kg * 4 + r;
          float v = acc[m][n][r] + bv;
          if (EPI == 2) v = gelu_exact(v);
          if constexpr (sizeof(CT) == 2) {
            ((u16*)C)[(size_t)row * ldc + col] = f2b(v);
          } else {
            ((float*)C)[(size_t)row * ldc + col] = v;
          }
        }
      }
    }
}

// ---------------------------------------------------------------------------
// Fused disentangled attention (flash-style, full-S online softmax).
// Block = (i-tile of 64, z=b*8+h). 4 waves; wave w owns q-rows w*16..w*16+15.
// logit(i,j) = (q.k + Qpk[i][f(i-j)] + KpqT[f(i-j)][j]) / SCALE, XSoftmax, @V.
// Bias slices are DENSE blocks (crel monotone, |step|<=1): staged to LDS with
// coalesced loads; per-element gather is then 2x 2B LDS reads.
// KpqT has 128 guard rows per (b,h): stride 640*512.
// ---------------------------------------------------------------------------
__global__ __launch_bounds__(256) void attn_fused(const u16* __restrict__ qbf,
                                                  const u16* __restrict__ kbf,
                                                  const u16* __restrict__ vT,
                                                  const u16* __restrict__ Qpk,
                                                  const u16* __restrict__ KpqT,
                                                  const float* __restrict__ mask,
                                                  const int* __restrict__ crel,
                                                  u16* __restrict__ ctx) {
  __shared__ u16 ks[64][72];        //  9216 B
  __shared__ u16 vs[64][72];        //  9216 B
  __shared__ u16 ps[4][16][72];     //  9216 B
  __shared__ u16 qpk_s[64][136];    // 17408 B  (col base aligned down to x8)
  __shared__ u16 kpq_s[128][72];    // 18432 B
  __shared__ u16 crl16[1024];       //  2048 B   -> total 65536 B
  int t = threadIdx.x;
  int it = blockIdx.x;       // 0..7
  int z = blockIdx.y;        // b*8+h
  int b = z >> 3, h = z & 7;
  int i0 = it * 64;
  int w = t >> 6, l = t & 63;
  int lr = l & 15, kg = l >> 4;

  for (int c = t; c < 1023; c += 256) crl16[c] = (u16)crel[c];

  // q fragments straight from global (one-time, 2x16B per lane)
  const u16* qrow = qbf + (size_t)(b * 512 + i0 + w * 16 + lr) * 512 + h * 64;
  bf16x8 qa0 = *(const bf16x8*)(qrow + kg * 8);
  bf16x8 qa1 = *(const bf16x8*)(qrow + kg * 8 + 32);

  float m_run[4], s_run[4];
  f32x4 o[4] = {};
  float mi[4];
#pragma unroll
  for (int r = 0; r < 4; ++r) {
    m_run[r] = NEGMAX;
    s_run[r] = 0.f;
    mi[r] = mask[b * 512 + i0 + w * 16 + kg * 4 + r];
  }
  const u16* qpk_base = Qpk + (size_t)z * 262144;   // [i][bucket], 512x512
  const u16* kpq_base = KpqT + (size_t)z * 327680;  // [bucket][j], 640x512 (guarded)
  __syncthreads();  // crl16 ready

  for (int jt = 0; jt < 8; ++jt) {
    int j0 = jt * 64;
    int idx_base = crl16[i0 - j0 - 63 + 511];  // min idx over tile (monotone)
    int ib8 = idx_base & ~7;                   // 16B-aligned qpk col base
    __syncthreads();  // previous tile's consumers done
    for (int c = t; c < 512; c += 256) {
      int row = c >> 3, off = (c & 7) * 8;
      *(uint4*)(&ks[row][off]) =
          *(const uint4*)(kbf + (size_t)(b * 512 + j0 + row) * 512 + h * 64 + off);
      *(uint4*)(&vs[row][off]) =
          *(const uint4*)(vT + (size_t)z * 32768 + (size_t)row * 512 + j0 + off);
    }
    // qpk_s[64][136] <- Qpk[i0+row][ib8 .. ib8+135]  (17 chunks/row)
    for (int c = t; c < 1088; c += 256) {
      int row = c / 17, off = (c % 17) * 8;
      *(uint4*)(&qpk_s[row][off]) =
          *(const uint4*)(qpk_base + (size_t)(i0 + row) * 512 + ib8 + off);
    }
    // kpq_s[128][64] <- KpqT[idx_base+row][j0 .. j0+63]  (8 chunks/row)
    for (int c = t; c < 1024; c += 256) {
      int row = c >> 3, off = (c & 7) * 8;
      *(uint4*)(&kpq_s[row][off]) =
          *(const uint4*)(kpq_base + (size_t)(idx_base + row) * 512 + j0 + off);
    }
    __syncthreads();
    // scores: 4 n-frags of 16 cols
    f32x4 sc[4];
#pragma unroll
    for (int nf = 0; nf < 4; ++nf) {
      bf16x8 kb0 = *(const bf16x8*)(&ks[nf * 16 + lr][kg * 8]);
      bf16x8 kb1 = *(const bf16x8*)(&ks[nf * 16 + lr][kg * 8 + 32]);
      f32x4 a = {};
      a = __builtin_amdgcn_mfma_f32_16x16x32_bf16(qa0, kb0, a, 0, 0, 0);
      a = __builtin_amdgcn_mfma_f32_16x16x32_bf16(qa1, kb1, a, 0, 0, 0);
      sc[nf] = a;
    }
    // bias gather (LDS) + mask + online softmax
    float mj[4];
#pragma unroll
    for (int nf = 0; nf < 4; ++nf) mj[nf] = mask[b * 512 + j0 + nf * 16 + lr];
    float lgv[4][4];
    bool ok[4][4];
    float tmax[4] = {NEGMAX, NEGMAX, NEGMAX, NEGMAX};
    int iloc = w * 16 + kg * 4;                 // local i of r=0
#pragma unroll
    for (int nf = 0; nf < 4; ++nf) {
      int jloc = nf * 16 + lr;
      int relc = i0 + iloc - (j0 + jloc) + 511;  // rel index of r=0
#pragma unroll
      for (int r = 0; r < 4; ++r) {
        int idx = crl16[relc + r];
        float bias = b2f(qpk_s[iloc + r][idx - ib8]) +
                     b2f(kpq_s[idx - idx_base][jloc]);
        bool o_ = (mi[r] * mj[nf]) > 0.f;
        float v = o_ ? (sc[nf][r] + bias) * INV_SCALE : NEGMAX;
        ok[nf][r] = o_;
        lgv[nf][r] = v;
        tmax[r] = fmaxf(tmax[r], v);
      }
    }
#pragma unroll
    for (int r = 0; r < 4; ++r) {
#pragma unroll
      for (int off = 8; off; off >>= 1) tmax[r] = fmaxf(tmax[r], __shfl_xor(tmax[r], off));
    }
    float tsum[4];
#pragma unroll
    for (int r = 0; r < 4; ++r) {
      float mn = fmaxf(m_run[r], tmax[r]);
      float scale = (mn <= -1e37f) ? 1.f : __expf(m_run[r] - mn);
      m_run[r] = mn;
      s_run[r] *= scale;
      o[0][r] *= scale; o[1][r] *= scale; o[2][r] *= scale; o[3][r] *= scale;
      float ls = 0.f;
#pragma unroll
      for (int nf = 0; nf < 4; ++nf) {
        float p = ok[nf][r] ? __expf(lgv[nf][r] - mn) : 0.f;
        lgv[nf][r] = p;
        ls += p;
      }
      tsum[r] = ls;
    }
#pragma unroll
    for (int r = 0; r < 4; ++r) {
#pragma unroll
      for (int off = 8; off; off >>= 1) tsum[r] += __shfl_xor(tsum[r], off);
      s_run[r] += tsum[r];
    }
    // P (C/D layout) -> LDS -> A-frag layout (per-wave buffer, no barrier)
#pragma unroll
    for (int nf = 0; nf < 4; ++nf)
#pragma unroll
      for (int r = 0; r < 4; ++r) ps[w][kg * 4 + r][nf * 16 + lr] = f2b(lgv[nf][r]);
    bf16x8 pa0 = *(const bf16x8*)(&ps[w][lr][kg * 8]);
    bf16x8 pa1 = *(const bf16x8*)(&ps[w][lr][kg * 8 + 32]);
    // PV accumulate
#pragma unroll
    for (int nf = 0; nf < 4; ++nf) {
      bf16x8 vb0 = *(const bf16x8*)(&vs[nf * 16 + lr][kg * 8]);
      bf16x8 vb1 = *(const bf16x8*)(&vs[nf * 16 + lr][kg * 8 + 32]);
      o[nf] = __builtin_amdgcn_mfma_f32_16x16x32_bf16(pa0, vb0, o[nf], 0, 0, 0);
      o[nf] = __builtin_amdgcn_mfma_f32_16x16x32_bf16(pa1, vb1, o[nf], 0, 0, 0);
    }
  }
#pragma unroll
  for (int r = 0; r < 4; ++r) {
    float inv = (s_run[r] > 0.f) ? 1.f / s_run[r] : 0.f;
    int i = i0 + w * 16 + kg * 4 + r;
#pragma unroll
    for (int nf = 0; nf < 4; ++nf)
      ctx[(size_t)(b * 512 + i) * 512 + h * 64 + nf * 16 + lr] = f2b(o[nf][r] * inv);
  }
}

// ---------------------------------------------------------------------------
// Host launch
// ---------------------------------------------------------------------------
extern "C" void kernel_launch(void* const* d_in, const int* in_sizes, int n_in,
                              void* d_out, int out_size, void* d_ws, size_t ws_size,
                              hipStream_t stream) {
  const float* x       = (const float*)d_in[0];
  const float* mask    = (const float*)d_in[1];
  const float* emb_s   = (const float*)d_in[2];
  const float* emb_b   = (const float*)d_in[3];
  const float* rel_emb = (const float*)d_in[4];
  const float* rel_s   = (const float*)d_in[5];
  const float* rel_b   = (const float*)d_in[6];
  const float* Wq = (const float*)d_in[7];
  const float* bq = (const float*)d_in[8];
  const float* Wk = (const float*)d_in[9];
  const float* bk = (const float*)d_in[10];
  const float* Wv = (const float*)d_in[11];
  const float* bv = (const float*)d_in[12];
  const float* Wo = (const float*)d_in[13];
  const float* bo = (const float*)d_in[14];
  const float* as_ = (const float*)d_in[15];
  const float* ab_ = (const float*)d_in[16];
  const float* Wi = (const float*)d_in[17];
  const float* bi = (const float*)d_in[18];
  const float* Wf = (const float*)d_in[19];
  const float* bf_ = (const float*)d_in[20];
  const float* fs_ = (const float*)d_in[21];
  const float* fb_ = (const float*)d_in[22];
  const float* Wc = (const float*)d_in[23];
  const float* bc = (const float*)d_in[24];
  float* out = (float*)d_out;

  char* p = (char*)d_ws;
  auto alloc = [&](size_t bytes) {
    char* r = p;
    p += (bytes + 255) & ~(size_t)255;
    return r;
  };
  float* hcat = (float*)alloc((size_t)4608 * 512 * 4);
  float* tmpA = (float*)alloc((size_t)4096 * 512 * 4);
  u16* hbf  = (u16*)alloc((size_t)4608 * 512 * 2);
  u16* qbf  = (u16*)alloc((size_t)4608 * 512 * 2);      // q | pq
  u16* kbf  = (u16*)alloc((size_t)4608 * 512 * 2);      // k | pk
  u16* vbf  = (u16*)alloc((size_t)4096 * 512 * 2);
  u16* vT   = (u16*)alloc((size_t)64 * 64 * 512 * 2);   // [bh][d][j]
  u16* ctxb = (u16*)alloc((size_t)4096 * 512 * 2);
  u16* mid  = (u16*)alloc((size_t)4096 * 768 * 2);
  u16* WtQ  = (u16*)alloc((size_t)3 * 512 * 512 * 2);
  u16* WtK  = (u16*)alloc((size_t)3 * 512 * 512 * 2);
  u16* WtV  = (u16*)alloc((size_t)3 * 512 * 512 * 2);
  u16* WtO  = (u16*)alloc((size_t)3 * 512 * 512 * 2);
  u16* WtI  = (u16*)alloc((size_t)3 * 768 * 512 * 2);
  u16* WtF  = (u16*)alloc((size_t)3 * 512 * 768 * 2);
  u16* WtC  = (u16*)alloc((size_t)100 * 512 * 2);
  u16* Qpk  = (u16*)alloc((size_t)64 * 512 * 512 * 2);  // [bh][i][bucket]
  u16* KpqT = (u16*)alloc((size_t)64 * 640 * 512 * 2);  // [bh][bucket][j], 128 guard rows
  int* crel = (int*)alloc((size_t)1024 * 4);

  relbucket_kernel<<<4, 256, 0, stream>>>(crel);
  wtrans_kernel<<<dim3(16, 16, 3), 256, 0, stream>>>(Wq, WtQ, 512, 512, 262144, 262144);
  wtrans_kernel<<<dim3(16, 16, 3), 256, 0, stream>>>(Wk, WtK, 512, 512, 262144, 262144);
  wtrans_kernel<<<dim3(16, 16, 3), 256, 0, stream>>>(Wv, WtV, 512, 512, 262144, 262144);
  wtrans_kernel<<<dim3(16, 16, 3), 256, 0, stream>>>(Wo, WtO, 512, 512, 262144, 262144);
  wtrans_kernel<<<dim3(24, 16, 3), 256, 0, stream>>>(Wi, WtI, 512, 768, 393216, 393216);
  wtrans_kernel<<<dim3(16, 24, 3), 256, 0, stream>>>(Wf, WtF, 768, 512, 393216, 393216);
  wtrans_kernel<<<dim3(4, 16, 1), 256, 0, stream>>>(Wc, WtC, 512, 100, 0, 0);
  ln_kernel<false, true><<<1024, 256, 0, stream>>>(x, nullptr, emb_s, emb_b, mask,
                                                   hcat, hbf, 4096);
  ln_kernel<false, false><<<128, 256, 0, stream>>>(rel_emb, nullptr, rel_s, rel_b, nullptr,
                                                   hcat + (size_t)4096 * 512,
                                                   hbf + (size_t)4096 * 512, 512);

  for (int l = 0; l < 3; ++l) {
    // q|pq, k|pk (shared weights incl. bias), v
    gemm_bf16<1, u16><<<dim3(8, 72, 1), 256, 0, stream>>>(
        hbf, WtQ + (size_t)l * 262144, bq + l * 512, qbf, 4608, 512, 512,
        512, 512, 512, 0, 0, 0, 0, 0, 0);
    gemm_bf16<1, u16><<<dim3(8, 72, 1), 256, 0, stream>>>(
        hbf, WtK + (size_t)l * 262144, bk + l * 512, kbf, 4608, 512, 512,
        512, 512, 512, 0, 0, 0, 0, 0, 0);
    gemm_bf16<1, u16><<<dim3(8, 64, 1), 256, 0, stream>>>(
        hbf, WtV + (size_t)l * 262144, bv + l * 512, vbf, 4096, 512, 512,
        512, 512, 512, 0, 0, 0, 0, 0, 0);
    vtrans_kernel<<<dim3(16, 2, 64), 256, 0, stream>>>(vbf, vT);
    // Qpk[b,h][i][r] = q @ pk^T ; KpqT[b,h][r][j] = pq @ k^T (swapped operands)
    gemm_bf16<0, u16><<<dim3(8, 8, 64), 256, 0, stream>>>(
        qbf, kbf + (size_t)4096 * 512, nullptr, Qpk, 512, 512, 64,
        512, 512, 512, 262144, 64, 0, 64, 2097152, 262144);
    gemm_bf16<0, u16><<<dim3(8, 8, 64), 256, 0, stream>>>(
        qbf + (size_t)4096 * 512, kbf, nullptr, KpqT, 512, 512, 64,
        512, 512, 512, 0, 64, 327680, 64, 2621440, 327680);
    // fused QK^T + bias + XSoftmax + PV
    attn_fused<<<dim3(8, 64), 256, 0, stream>>>(qbf, kbf, vT, Qpk, KpqT, mask, crel, ctxb);
    // O proj -> fp32, LN(+h)
    gemm_bf16<1, float><<<dim3(8, 64, 1), 256, 0, stream>>>(
        ctxb, WtO + (size_t)l * 262144, bo + l * 512, tmpA, 4096, 512, 512,
        512, 512, 512, 0, 0, 0, 0, 0, 0);
    ln_kernel<true, false><<<1024, 256, 0, stream>>>(tmpA, hcat, as_ + l * 512, ab_ + l * 512,
                                                     nullptr, hcat, hbf, 4096);
    // FFN
    gemm_bf16<2, u16><<<dim3(12, 64, 1), 256, 0, stream>>>(
        hbf, WtI + (size_t)l * 393216, bi + l * 768, mid, 4096, 768, 512,
        512, 512, 768, 0, 0, 0, 0, 0, 0);
    gemm_bf16<1, float><<<dim3(8, 64, 1), 256, 0, stream>>>(
        mid, WtF + (size_t)l * 393216, bf_ + l * 512, tmpA, 4096, 512, 768,
        768, 768, 512, 0, 0, 0, 0, 0, 0);
    ln_kernel<true, false><<<1024, 256, 0, stream>>>(tmpA, hcat, fs_ + l * 512, fb_ + l * 512,
                                                     nullptr, hcat, hbf, 4096);
  }
  gemm_bf16<1, float><<<dim3(2, 64, 1), 256, 0, stream>>>(
      hbf, WtC, bc, out, 4096, 100, 512, 512, 512, 100, 0, 0, 0, 0, 0, 0);
}

// Round 7
// 608.592 us; speedup vs baseline: 5.7509x; 1.0127x over previous
//
#include <hip/hip_runtime.h>
#include <hip/hip_bf16.h>
#include <math.h>

// B=8, S=512, HID=512, HEADS=8, DH=64, FF=768, NL=3, SPAN=256, MAXP=512, VOCAB=100
#define EPS_LN 1e-7f
#define INV_SCALE 0.072168783648703221f   // 1/sqrt(64*3)
#define NEGMAX -3.402823466e38f

typedef unsigned short u16;
typedef __attribute__((ext_vector_type(8))) short bf16x8;  // 8 bf16 = 4 VGPRs
typedef __attribute__((ext_vector_type(4))) float f32x4;

__device__ __forceinline__ u16 f2b(float f) {
  union { float f; unsigned int u; } v; v.f = f;
  unsigned int r = v.u + 0x7FFFu + ((v.u >> 16) & 1u);
  return (u16)(r >> 16);
}
__device__ __forceinline__ float b2f(u16 u) {
  union { unsigned int u; float f; } v; v.u = ((unsigned int)u) << 16;
  return v.f;
}
__device__ __forceinline__ float gelu_exact(float v) {
  return 0.5f * v * (1.f + erff(v * 0.70710678118654752440f));
}

// ---------------------------------------------------------------------------
// Relative-position bucket, collapsed to 1-D: idx depends only on rel = i-j.
// crel[rel+511] = clip(bucket(rel)+256, 0, 511), rel in [-511,511].
// Monotone nondecreasing in rel, |step| <= 1 -> any 127-wide rel window maps
// to a <=127-wide contiguous idx window (used for LDS staging in attn).
// ---------------------------------------------------------------------------
__global__ __launch_bounds__(256) void relbucket_kernel(int* __restrict__ crel) {
  int idx = blockIdx.x * 256 + threadIdx.x;
  if (idx >= 1023) return;
  int rel = idx - 511;
  int a = (rel < 128 && rel > -128) ? 127 : (rel < 0 ? -rel : rel);
  int bucket;
  if (a <= 128) {
    bucket = rel;
  } else {
    double lp = ceil(log((double)a / 128.0) / log(511.0 / 128.0) * 127.0) + 128.0;
    int l = (int)lp;
    bucket = (rel > 0) ? l : -l;
  }
  int c = bucket + 256;
  c = c < 0 ? 0 : (c > 511 ? 511 : c);
  crel[idx] = c;
}

// ---------------------------------------------------------------------------
// LayerNorm over 512 cols; writes fp32 master and optional bf16 mirror.
// ---------------------------------------------------------------------------
template <bool RESID, bool MASK>
__global__ __launch_bounds__(256) void ln_kernel(const float* __restrict__ x,
                                                 const float* __restrict__ res,
                                                 const float* __restrict__ gam,
                                                 const float* __restrict__ bet,
                                                 const float* __restrict__ mask,
                                                 float* __restrict__ out,
                                                 u16* __restrict__ outb, int nrows) {
  int w = threadIdx.x >> 6, ln = threadIdx.x & 63;
  int row = blockIdx.x * 4 + w;
  if (row >= nrows) return;
  const float* xr = x + (size_t)row * 512;
  float v[8];
#pragma unroll
  for (int c = 0; c < 2; ++c) {
    float4 a = *(const float4*)(xr + (ln << 3) + (c << 2));
    v[c * 4 + 0] = a.x; v[c * 4 + 1] = a.y; v[c * 4 + 2] = a.z; v[c * 4 + 3] = a.w;
    if (RESID) {
      float4 r4 = *(const float4*)(res + (size_t)row * 512 + (ln << 3) + (c << 2));
      v[c * 4 + 0] += r4.x; v[c * 4 + 1] += r4.y; v[c * 4 + 2] += r4.z; v[c * 4 + 3] += r4.w;
    }
  }
  float sum = 0.f;
#pragma unroll
  for (int c = 0; c < 8; ++c) sum += v[c];
#pragma unroll
  for (int off = 32; off; off >>= 1) sum += __shfl_xor(sum, off);
  float mu = sum * (1.f / 512.f);
  float vs = 0.f;
#pragma unroll
  for (int c = 0; c < 8; ++c) { float d = v[c] - mu; vs += d * d; }
#pragma unroll
  for (int off = 32; off; off >>= 1) vs += __shfl_xor(vs, off);
  float rstd = 1.f / sqrtf(vs * (1.f / 512.f) + EPS_LN);
  float mk = MASK ? mask[row] : 1.f;
  float* orow = out + (size_t)row * 512;
  u16* brow = outb ? outb + (size_t)row * 512 : nullptr;
#pragma unroll
  for (int c = 0; c < 2; ++c) {
    int col = (ln << 3) + (c << 2);
    float o[4];
#pragma unroll
    for (int q = 0; q < 4; ++q)
      o[q] = ((v[c * 4 + q] - mu) * rstd * gam[col + q] + bet[col + q]) * mk;
    *(float4*)(orow + col) = make_float4(o[0], o[1], o[2], o[3]);
    if (brow) {
      ushort4 ob = { f2b(o[0]), f2b(o[1]), f2b(o[2]), f2b(o[3]) };
      *(ushort4*)(brow + col) = ob;
    }
  }
}

// ---------------------------------------------------------------------------
// Weight transpose + bf16 cast: W f32 [K][N] row-major -> Wt bf16 [N][K].
// ---------------------------------------------------------------------------
__global__ __launch_bounds__(256) void wtrans_kernel(const float* __restrict__ W,
                                                     u16* __restrict__ Wt,
                                                     int K, int N, long wstride, long tstride) {
  __shared__ float tl[32][33];
  int z = blockIdx.z;
  W += (size_t)z * wstride;
  Wt += (size_t)z * tstride;
  int n0 = blockIdx.x * 32, k0 = blockIdx.y * 32;
  int c = threadIdx.x & 31, r8 = threadIdx.x >> 5;
#pragma unroll
  for (int p = 0; p < 4; ++p) {
    int r = r8 + p * 8;
    int k = k0 + r, n = n0 + c;
    tl[r][c] = (k < K && n < N) ? W[(size_t)k * N + n] : 0.f;
  }
  __syncthreads();
#pragma unroll
  for (int p = 0; p < 4; ++p) {
    int r = r8 + p * 8;
    int n = n0 + r, k = k0 + c;
    if (n < N && k < K) Wt[(size_t)n * K + k] = f2b(tl[c][r]);
  }
}

// ---------------------------------------------------------------------------
// V transpose: vbf [4096][512] bf16 -> vT [64(bh)][64(d)][512(j)] bf16.
// ---------------------------------------------------------------------------
__global__ __launch_bounds__(256) void vtrans_kernel(const u16* __restrict__ vbf,
                                                     u16* __restrict__ vT) {
  __shared__ u16 tl[32][33];
  int z = blockIdx.z;  // b*8+h
  int b = z >> 3, h = z & 7;
  int j0 = blockIdx.x * 32, d0 = blockIdx.y * 32;
  int c = threadIdx.x & 31, r8 = threadIdx.x >> 5;
#pragma unroll
  for (int p = 0; p < 4; ++p) {
    int r = r8 + p * 8;
    tl[r][c] = vbf[(size_t)(b * 512 + j0 + r) * 512 + h * 64 + d0 + c];
  }
  __syncthreads();
#pragma unroll
  for (int p = 0; p < 4; ++p) {
    int r = r8 + p * 8;
    vT[(size_t)z * 32768 + (size_t)(d0 + r) * 512 + j0 + c] = tl[c][r];
  }
}

// ---------------------------------------------------------------------------
// bf16 MFMA GEMM: C[M,N] = A[M,K] @ B[N,K]^T (+bias, +gelu).
// 64x64 tile, BK=64, 4 waves (2x2), mfma_f32_16x16x32_bf16.
// ---------------------------------------------------------------------------
template <int EPI, typename CT>
__global__ __launch_bounds__(256) void gemm_bf16(const u16* __restrict__ A,
                                                 const u16* __restrict__ B,
                                                 const float* __restrict__ bias,
                                                 CT* __restrict__ C,
                                                 int M, int N, int K,
                                                 int lda, int ldb, int ldc,
                                                 long sAb, long sAh, long sBb, long sBh,
                                                 long sCb, long sCh) {
  __shared__ u16 As[64][72];
  __shared__ u16 Bs[64][72];
  int t = threadIdx.x;
  int z = blockIdx.z, zb = z >> 3, zh = z & 7;
  A += (size_t)zb * sAb + (size_t)zh * sAh;
  B += (size_t)zb * sBb + (size_t)zh * sBh;
  C += (size_t)zb * sCb + (size_t)zh * sCh;
  int m0 = blockIdx.y * 64, n0 = blockIdx.x * 64;
  int w = t >> 6, l = t & 63;
  int wr = w >> 1, wc = w & 1, lr = l & 15, kg = l >> 4;
  f32x4 acc[2][2] = {};
  for (int k0 = 0; k0 < K; k0 += 64) {
#pragma unroll
    for (int p = 0; p < 2; ++p) {
      int c = t + (p << 8);
      int row = c >> 3, q = c & 7;
      uint4 av = *(const uint4*)(A + (size_t)(m0 + row) * lda + k0 + q * 8);
      *(uint4*)(&As[row][q * 8]) = av;
      uint4 bv = make_uint4(0u, 0u, 0u, 0u);
      if (n0 + row < N) bv = *(const uint4*)(B + (size_t)(n0 + row) * ldb + k0 + q * 8);
      *(uint4*)(&Bs[row][q * 8]) = bv;
    }
    __syncthreads();
#pragma unroll
    for (int s = 0; s < 2; ++s) {
      bf16x8 a0 = *(const bf16x8*)(&As[wr * 32 + lr][kg * 8 + s * 32]);
      bf16x8 a1 = *(const bf16x8*)(&As[wr * 32 + 16 + lr][kg * 8 + s * 32]);
      bf16x8 b0 = *(const bf16x8*)(&Bs[wc * 32 + lr][kg * 8 + s * 32]);
      bf16x8 b1 = *(const bf16x8*)(&Bs[wc * 32 + 16 + lr][kg * 8 + s * 32]);
      acc[0][0] = __builtin_amdgcn_mfma_f32_16x16x32_bf16(a0, b0, acc[0][0], 0, 0, 0);
      acc[0][1] = __builtin_amdgcn_mfma_f32_16x16x32_bf16(a0, b1, acc[0][1], 0, 0, 0);
      acc[1][0] = __builtin_amdgcn_mfma_f32_16x16x32_bf16(a1, b0, acc[1][0], 0, 0, 0);
      acc[1][1] = __builtin_amdgcn_mfma_f32_16x16x32_bf16(a1, b1, acc[1][1], 0, 0, 0);
    }
    __syncthreads();
  }
#pragma unroll
  for (int m = 0; m < 2; ++m)
#pragma unroll
    for (int n = 0; n < 2; ++n) {
      int col = n0 + wc * 32 + n * 16 + lr;
      if (col < N) {
        float bv = (EPI >= 1) ? bias[col] : 0.f;
#pragma unroll
        for (int r = 0; r < 4; ++r) {
          int row = m0 + wr * 32 + m * 16 + kg * 4 + r;
          float v = acc[m][n][r] + bv;
          if (EPI == 2) v = gelu_exact(v);
          if constexpr (sizeof(CT) == 2) {
            ((u16*)C)[(size_t)row * ldc + col] = f2b(v);
          } else {
            ((float*)C)[(size_t)row * ldc + col] = v;
          }
        }
      }
    }
}

// ---------------------------------------------------------------------------
// Fused disentangled attention, SPLIT-J (flash-decoding style).
// Block = (i-tile 0..7, z=b*8+h, js=0..3); each block does 2 of 8 j-tiles and
// writes UNNORMALIZED partials: po (bf16 o-accum) + pms (f32 m,s per row).
// logit(i,j) = (q.k + Qpk[i][f(i-j)] + KpqT[f(i-j)][j]) / SCALE, XSoftmax.
// Qpk gather goes straight to L2 (row-local, consecutive cols -> coalesces);
// KpqT slice (scattered rows) staged dense in LDS via the crel monotone
// window. P-transpose buffer ALIASES ks (barrier-protected) -> 38.9 KB LDS
// -> 4 blocks/CU; grid 2048 blocks -> occupancy cap 50% (was 25%).
// ---------------------------------------------------------------------------
__global__ __launch_bounds__(256) void attn_fused(const u16* __restrict__ qbf,
                                                  const u16* __restrict__ kbf,
                                                  const u16* __restrict__ vT,
                                                  const u16* __restrict__ Qpk,
                                                  const u16* __restrict__ KpqT,
                                                  const float* __restrict__ mask,
                                                  const int* __restrict__ crel,
                                                  u16* __restrict__ po,
                                                  float* __restrict__ pms) {
  __shared__ u16 ks[64][72];        //  9216 B (K tile; re-used as P tile)
  __shared__ u16 vs[64][72];        //  9216 B
  __shared__ u16 kpq_s[128][72];    // 18432 B
  __shared__ u16 crl16[1024];       //  2048 B  -> 38912 B total
  int t = threadIdx.x;
  int it = blockIdx.x;       // 0..7
  int z = blockIdx.y;        // b*8+h
  int js = blockIdx.z;       // 0..3
  int b = z >> 3, h = z & 7;
  int i0 = it * 64;
  int w = t >> 6, l = t & 63;
  int lr = l & 15, kg = l >> 4;

  for (int c = t; c < 1023; c += 256) crl16[c] = (u16)crel[c];

  // q fragments straight from global (one-time, 2x16B per lane)
  const u16* qrow = qbf + (size_t)(b * 512 + i0 + w * 16 + lr) * 512 + h * 64;
  bf16x8 qa0 = *(const bf16x8*)(qrow + kg * 8);
  bf16x8 qa1 = *(const bf16x8*)(qrow + kg * 8 + 32);

  float m_run[4], s_run[4];
  f32x4 o[4] = {};
  float mi[4];
#pragma unroll
  for (int r = 0; r < 4; ++r) {
    m_run[r] = NEGMAX;
    s_run[r] = 0.f;
    mi[r] = mask[b * 512 + i0 + w * 16 + kg * 4 + r];
  }
  const u16* qpk_base = Qpk + (size_t)z * 262144;   // [i][bucket], 512x512
  const u16* kpq_base = KpqT + (size_t)z * 327680;  // [bucket][j], 640x512 (guarded)
  __syncthreads();  // crl16 ready

  for (int jj = 0; jj < 2; ++jj) {
    int j0 = (js * 2 + jj) * 64;
    int idx_base = crl16[i0 - j0 - 63 + 511];  // min idx over tile (monotone)
    __syncthreads();  // previous tile fully consumed (ks-as-P, vs, kpq_s)
    for (int c = t; c < 512; c += 256) {
      int row = c >> 3, off = (c & 7) * 8;
      *(uint4*)(&ks[row][off]) =
          *(const uint4*)(kbf + (size_t)(b * 512 + j0 + row) * 512 + h * 64 + off);
      *(uint4*)(&vs[row][off]) =
          *(const uint4*)(vT + (size_t)z * 32768 + (size_t)row * 512 + j0 + off);
    }
    // kpq_s[128][64] <- KpqT[idx_base+row][j0 .. j0+63]
    for (int c = t; c < 1024; c += 256) {
      int row = c >> 3, off = (c & 7) * 8;
      *(uint4*)(&kpq_s[row][off]) =
          *(const uint4*)(kpq_base + (size_t)(idx_base + row) * 512 + j0 + off);
    }
    __syncthreads();
    // scores: 4 n-frags of 16 cols
    f32x4 sc[4];
#pragma unroll
    for (int nf = 0; nf < 4; ++nf) {
      bf16x8 kb0 = *(const bf16x8*)(&ks[nf * 16 + lr][kg * 8]);
      bf16x8 kb1 = *(const bf16x8*)(&ks[nf * 16 + lr][kg * 8 + 32]);
      f32x4 a = {};
      a = __builtin_amdgcn_mfma_f32_16x16x32_bf16(qa0, kb0, a, 0, 0, 0);
      a = __builtin_amdgcn_mfma_f32_16x16x32_bf16(qa1, kb1, a, 0, 0, 0);
      sc[nf] = a;
    }
    // bias gather (Qpk: global/L2; Kpq: LDS) + mask + online softmax
    float mj[4];
#pragma unroll
    for (int nf = 0; nf < 4; ++nf) mj[nf] = mask[b * 512 + j0 + nf * 16 + lr];
    float lgv[4][4];
    bool ok[4][4];
    float tmax[4] = {NEGMAX, NEGMAX, NEGMAX, NEGMAX};
    int iloc = w * 16 + kg * 4;                 // local i of r=0
#pragma unroll
    for (int nf = 0; nf < 4; ++nf) {
      int jloc = nf * 16 + lr;
      int relc = i0 + iloc - (j0 + jloc) + 511;  // rel index of r=0
#pragma unroll
      for (int r = 0; r < 4; ++r) {
        int idx = crl16[relc + r];
        float bias = b2f(qpk_base[(size_t)(i0 + iloc + r) * 512 + idx]) +
                     b2f(kpq_s[idx - idx_base][jloc]);
        bool o_ = (mi[r] * mj[nf]) > 0.f;
        float v = o_ ? (sc[nf][r] + bias) * INV_SCALE : NEGMAX;
        ok[nf][r] = o_;
        lgv[nf][r] = v;
        tmax[r] = fmaxf(tmax[r], v);
      }
    }
#pragma unroll
    for (int r = 0; r < 4; ++r) {
#pragma unroll
      for (int off = 8; off; off >>= 1) tmax[r] = fmaxf(tmax[r], __shfl_xor(tmax[r], off));
    }
    float tsum[4];
#pragma unroll
    for (int r = 0; r < 4; ++r) {
      float mn = fmaxf(m_run[r], tmax[r]);
      float scale = (mn <= -1e37f) ? 1.f : __expf(m_run[r] - mn);
      m_run[r] = mn;
      s_run[r] *= scale;
      o[0][r] *= scale; o[1][r] *= scale; o[2][r] *= scale; o[3][r] *= scale;
      float ls = 0.f;
#pragma unroll
      for (int nf = 0; nf < 4; ++nf) {
        float p = ok[nf][r] ? __expf(lgv[nf][r] - mn) : 0.f;
        lgv[nf][r] = p;
        ls += p;
      }
      tsum[r] = ls;
    }
#pragma unroll
    for (int r = 0; r < 4; ++r) {
#pragma unroll
      for (int off = 8; off; off >>= 1) tsum[r] += __shfl_xor(tsum[r], off);
      s_run[r] += tsum[r];
    }
    // all waves done reading ks -> reuse it as per-wave P buffer
    __syncthreads();
#pragma unroll
    for (int nf = 0; nf < 4; ++nf)
#pragma unroll
      for (int r = 0; r < 4; ++r) ks[w * 16 + kg * 4 + r][nf * 16 + lr] = f2b(lgv[nf][r]);
    bf16x8 pa0 = *(const bf16x8*)(&ks[w * 16 + lr][kg * 8]);
    bf16x8 pa1 = *(const bf16x8*)(&ks[w * 16 + lr][kg * 8 + 32]);
    // PV accumulate
#pragma unroll
    for (int nf = 0; nf < 4; ++nf) {
      bf16x8 vb0 = *(const bf16x8*)(&vs[nf * 16 + lr][kg * 8]);
      bf16x8 vb1 = *(const bf16x8*)(&vs[nf * 16 + lr][kg * 8 + 32]);
      o[nf] = __builtin_amdgcn_mfma_f32_16x16x32_bf16(pa0, vb0, o[nf], 0, 0, 0);
      o[nf] = __builtin_amdgcn_mfma_f32_16x16x32_bf16(pa1, vb1, o[nf], 0, 0, 0);
    }
  }
  // write unnormalized partials
#pragma unroll
  for (int r = 0; r < 4; ++r) {
    int i = i0 + w * 16 + kg * 4 + r;
    size_t pb = (((size_t)js * 64 + z) * 512 + i) * 64;
#pragma unroll
    for (int nf = 0; nf < 4; ++nf) po[pb + nf * 16 + lr] = f2b(o[nf][r]);
    if (lr == 0) {
      size_t mb = (((size_t)js * 64 + z) * 512 + i) * 2;
      pms[mb + 0] = m_run[r];
      pms[mb + 1] = s_run[r];
    }
  }
}

// ---------------------------------------------------------------------------
// Merge 4 j-split partials -> normalized ctx (bf16).
// One wave per (z,i) row; lane = d.
// ---------------------------------------------------------------------------
__global__ __launch_bounds__(256) void merge_kernel(const u16* __restrict__ po,
                                                    const float* __restrict__ pms,
                                                    u16* __restrict__ ctx) {
  int t = threadIdx.x;
  int w = t >> 6, d = t & 63;
  int row = blockIdx.x * 4 + w;   // 0..32767
  int z = row >> 9, i = row & 511;
  int b = z >> 3, h = z & 7;
  float mv[4], sv[4], m = NEGMAX;
#pragma unroll
  for (int js = 0; js < 4; ++js) {
    size_t mb = (((size_t)js * 64 + z) * 512 + i) * 2;
    mv[js] = pms[mb + 0];
    sv[js] = pms[mb + 1];
    m = fmaxf(m, mv[js]);
  }
  float o = 0.f, s = 0.f;
#pragma unroll
  for (int js = 0; js < 4; ++js) {
    float wgt = (mv[js] <= -1e37f) ? 0.f : __expf(mv[js] - m);
    o += wgt * b2f(po[(((size_t)js * 64 + z) * 512 + i) * 64 + d]);
    s += wgt * sv[js];
  }
  float r = (s > 0.f) ? o / s : 0.f;
  ctx[(size_t)(b * 512 + i) * 512 + h * 64 + d] = f2b(r);
}

// ---------------------------------------------------------------------------
// Host launch
// ---------------------------------------------------------------------------
extern "C" void kernel_launch(void* const* d_in, const int* in_sizes, int n_in,
                              void* d_out, int out_size, void* d_ws, size_t ws_size,
                              hipStream_t stream) {
  const float* x       = (const float*)d_in[0];
  const float* mask    = (const float*)d_in[1];
  const float* emb_s   = (const float*)d_in[2];
  const float* emb_b   = (const float*)d_in[3];
  const float* rel_emb = (const float*)d_in[4];
  const float* rel_s   = (const float*)d_in[5];
  const float* rel_b   = (const float*)d_in[6];
  const float* Wq = (const float*)d_in[7];
  const float* bq = (const float*)d_in[8];
  const float* Wk = (const float*)d_in[9];
  const float* bk = (const float*)d_in[10];
  const float* Wv = (const float*)d_in[11];
  const float* bv = (const float*)d_in[12];
  const float* Wo = (const float*)d_in[13];
  const float* bo = (const float*)d_in[14];
  const float* as_ = (const float*)d_in[15];
  const float* ab_ = (const float*)d_in[16];
  const float* Wi = (const float*)d_in[17];
  const float* bi = (const float*)d_in[18];
  const float* Wf = (const float*)d_in[19];
  const float* bf_ = (const float*)d_in[20];
  const float* fs_ = (const float*)d_in[21];
  const float* fb_ = (const float*)d_in[22];
  const float* Wc = (const float*)d_in[23];
  const float* bc = (const float*)d_in[24];
  float* out = (float*)d_out;

  char* p = (char*)d_ws;
  auto alloc = [&](size_t bytes) {
    char* r = p;
    p += (bytes + 255) & ~(size_t)255;
    return r;
  };
  // Union region: tmpA | mid | hbf are dead during attn+merge; the attention
  // partials (po: 16.78 MB bf16, pms: 1.05 MB f32 = 17.83 MB) overlay them.
  // hbf rows >= 4096 (rel_e, persistent) start at byte 14.68+4.19 MB of the
  // union -- beyond pms' end (17.83 MB), so they are never clobbered.
  float* hcat = (float*)alloc((size_t)4608 * 512 * 4);
  float* tmpA = (float*)alloc((size_t)4096 * 512 * 4);  // union base (8.39 MB)
  u16* mid  = (u16*)alloc((size_t)4096 * 768 * 2);      // union +8.39 (6.29 MB)
  u16* hbf  = (u16*)alloc((size_t)4608 * 512 * 2);      // union +14.68 (4.72 MB)
  u16* po   = (u16*)tmpA;                               // [4][64][512][64] bf16
  float* pms = (float*)((char*)tmpA + (size_t)4 * 64 * 512 * 64 * 2);  // [4][64][512][2]
  u16* qbf  = (u16*)alloc((size_t)4608 * 512 * 2);      // q | pq
  u16* kbf  = (u16*)alloc((size_t)4608 * 512 * 2);      // k | pk
  u16* vbf  = (u16*)alloc((size_t)4096 * 512 * 2);
  u16* vT   = (u16*)alloc((size_t)64 * 64 * 512 * 2);   // [bh][d][j]
  u16* ctxb = (u16*)alloc((size_t)4096 * 512 * 2);
  u16* WtQ  = (u16*)alloc((size_t)3 * 512 * 512 * 2);
  u16* WtK  = (u16*)alloc((size_t)3 * 512 * 512 * 2);
  u16* WtV  = (u16*)alloc((size_t)3 * 512 * 512 * 2);
  u16* WtO  = (u16*)alloc((size_t)3 * 512 * 512 * 2);
  u16* WtI  = (u16*)alloc((size_t)3 * 768 * 512 * 2);
  u16* WtF  = (u16*)alloc((size_t)3 * 512 * 768 * 2);
  u16* WtC  = (u16*)alloc((size_t)100 * 512 * 2);
  u16* Qpk  = (u16*)alloc((size_t)64 * 512 * 512 * 2);  // [bh][i][bucket]
  u16* KpqT = (u16*)alloc((size_t)64 * 640 * 512 * 2);  // [bh][bucket][j], 128 guard rows
  int* crel = (int*)alloc((size_t)1024 * 4);

  relbucket_kernel<<<4, 256, 0, stream>>>(crel);
  wtrans_kernel<<<dim3(16, 16, 3), 256, 0, stream>>>(Wq, WtQ, 512, 512, 262144, 262144);
  wtrans_kernel<<<dim3(16, 16, 3), 256, 0, stream>>>(Wk, WtK, 512, 512, 262144, 262144);
  wtrans_kernel<<<dim3(16, 16, 3), 256, 0, stream>>>(Wv, WtV, 512, 512, 262144, 262144);
  wtrans_kernel<<<dim3(16, 16, 3), 256, 0, stream>>>(Wo, WtO, 512, 512, 262144, 262144);
  wtrans_kernel<<<dim3(24, 16, 3), 256, 0, stream>>>(Wi, WtI, 512, 768, 393216, 393216);
  wtrans_kernel<<<dim3(16, 24, 3), 256, 0, stream>>>(Wf, WtF, 768, 512, 393216, 393216);
  wtrans_kernel<<<dim3(4, 16, 1), 256, 0, stream>>>(Wc, WtC, 512, 100, 0, 0);
  ln_kernel<false, true><<<1024, 256, 0, stream>>>(x, nullptr, emb_s, emb_b, mask,
                                                   hcat, hbf, 4096);
  ln_kernel<false, false><<<128, 256, 0, stream>>>(rel_emb, nullptr, rel_s, rel_b, nullptr,
                                                   hcat + (size_t)4096 * 512,
                                                   hbf + (size_t)4096 * 512, 512);

  for (int l = 0; l < 3; ++l) {
    // q|pq, k|pk (shared weights incl. bias), v
    gemm_bf16<1, u16><<<dim3(8, 72, 1), 256, 0, stream>>>(
        hbf, WtQ + (size_t)l * 262144, bq + l * 512, qbf, 4608, 512, 512,
        512, 512, 512, 0, 0, 0, 0, 0, 0);
    gemm_bf16<1, u16><<<dim3(8, 72, 1), 256, 0, stream>>>(
        hbf, WtK + (size_t)l * 262144, bk + l * 512, kbf, 4608, 512, 512,
        512, 512, 512, 0, 0, 0, 0, 0, 0);
    gemm_bf16<1, u16><<<dim3(8, 64, 1), 256, 0, stream>>>(
        hbf, WtV + (size_t)l * 262144, bv + l * 512, vbf, 4096, 512, 512,
        512, 512, 512, 0, 0, 0, 0, 0, 0);
    vtrans_kernel<<<dim3(16, 2, 64), 256, 0, stream>>>(vbf, vT);
    // Qpk[b,h][i][r] = q @ pk^T ; KpqT[b,h][r][j] = pq @ k^T (swapped operands)
    gemm_bf16<0, u16><<<dim3(8, 8, 64), 256, 0, stream>>>(
        qbf, kbf + (size_t)4096 * 512, nullptr, Qpk, 512, 512, 64,
        512, 512, 512, 262144, 64, 0, 64, 2097152, 262144);
    gemm_bf16<0, u16><<<dim3(8, 8, 64), 256, 0, stream>>>(
        qbf + (size_t)4096 * 512, kbf, nullptr, KpqT, 512, 512, 64,
        512, 512, 512, 0, 64, 327680, 64, 2621440, 327680);
    // fused QK^T + bias + XSoftmax + PV, 4-way j-split, then merge
    attn_fused<<<dim3(8, 64, 4), 256, 0, stream>>>(qbf, kbf, vT, Qpk, KpqT, mask, crel,
                                                   po, pms);
    merge_kernel<<<8192, 256, 0, stream>>>(po, pms, ctxb);
    // O proj -> fp32, LN(+h)
    gemm_bf16<1, float><<<dim3(8, 64, 1), 256, 0, stream>>>(
        ctxb, WtO + (size_t)l * 262144, bo + l * 512, tmpA, 4096, 512, 512,
        512, 512, 512, 0, 0, 0, 0, 0, 0);
    ln_kernel<true, false><<<1024, 256, 0, stream>>>(tmpA, hcat, as_ + l * 512, ab_ + l * 512,
                                                     nullptr, hcat, hbf, 4096);
    // FFN
    gemm_bf16<2, u16><<<dim3(12, 64, 1), 256, 0, stream>>>(
        hbf, WtI + (size_t)l * 393216, bi + l * 768, mid, 4096, 768, 512,
        512, 512, 768, 0, 0, 0, 0, 0, 0);
    gemm_bf16<1, float><<<dim3(8, 64, 1), 256, 0, stream>>>(
        mid, WtF + (size_t)l * 393216, bf_ + l * 512, tmpA, 4096, 512, 768,
        768, 768, 512, 0, 0, 0, 0, 0, 0);
    ln_kernel<true, false><<<1024, 256, 0, stream>>>(tmpA, hcat, fs_ + l * 512, fb_ + l * 512,
                                                     nullptr, hcat, hbf, 4096);
  }
  gemm_bf16<1, float><<<dim3(2, 64, 1), 256, 0, stream>>>(
      hbf, WtC, bc, out, 4096, 100, 512, 512, 512, 100, 0, 0, 0, 0, 0, 0);
}

// Round 8
// 520.386 us; speedup vs baseline: 6.7256x; 1.1695x over previous
//
#include <hip/hip_runtime.h>
#include <hip/hip_bf16.h>
#include <math.h>

// B=8, S=512, HID=512, HEADS=8, DH=64, FF=768, NL=3, SPAN=256, MAXP=512, VOCAB=100
#define EPS_LN 1e-7f
#define INV_SCALE 0.072168783648703221f   // 1/sqrt(64*3)
#define NEGMAX -3.402823466e38f

typedef unsigned short u16;
typedef __attribute__((ext_vector_type(8))) short bf16x8;  // 8 bf16 = 4 VGPRs
typedef __attribute__((ext_vector_type(4))) float f32x4;

__device__ __forceinline__ u16 f2b(float f) {
  union { float f; unsigned int u; } v; v.f = f;
  unsigned int r = v.u + 0x7FFFu + ((v.u >> 16) & 1u);
  return (u16)(r >> 16);
}
__device__ __forceinline__ float b2f(u16 u) {
  union { unsigned int u; float f; } v; v.u = ((unsigned int)u) << 16;
  return v.f;
}
__device__ __forceinline__ float gelu_exact(float v) {
  return 0.5f * v * (1.f + erff(v * 0.70710678118654752440f));
}

// ---------------------------------------------------------------------------
// Relative-position bucket table (1-D; crel monotone, |step|<=1).
// ---------------------------------------------------------------------------
__global__ __launch_bounds__(256) void relbucket_kernel(int* __restrict__ crel) {
  int idx = blockIdx.x * 256 + threadIdx.x;
  if (idx >= 1023) return;
  int rel = idx - 511;
  int a = (rel < 128 && rel > -128) ? 127 : (rel < 0 ? -rel : rel);
  int bucket;
  if (a <= 128) {
    bucket = rel;
  } else {
    double lp = ceil(log((double)a / 128.0) / log(511.0 / 128.0) * 127.0) + 128.0;
    int l = (int)lp;
    bucket = (rel > 0) ? l : -l;
  }
  int c = bucket + 256;
  c = c < 0 ? 0 : (c > 511 ? 511 : c);
  crel[idx] = c;
}

// ---------------------------------------------------------------------------
// Bias concat: [3][1536] = bq|bk|bv per layer.
// ---------------------------------------------------------------------------
__global__ __launch_bounds__(256) void biascat_kernel(const float* __restrict__ bq,
                                                      const float* __restrict__ bk,
                                                      const float* __restrict__ bv,
                                                      float* __restrict__ o) {
  int i = blockIdx.x * 256 + threadIdx.x;  // 3*1536
  if (i >= 4608) return;
  int l = i / 1536, c = i - l * 1536;
  float v = (c < 512) ? bq[l * 512 + c]
                      : (c < 1024) ? bk[l * 512 + c - 512] : bv[l * 512 + c - 1024];
  o[i] = v;
}

// ---------------------------------------------------------------------------
// LayerNorm over 512 cols; writes fp32 master and optional bf16 mirror.
// ---------------------------------------------------------------------------
template <bool RESID, bool MASK>
__global__ __launch_bounds__(256) void ln_kernel(const float* __restrict__ x,
                                                 const float* __restrict__ res,
                                                 const float* __restrict__ gam,
                                                 const float* __restrict__ bet,
                                                 const float* __restrict__ mask,
                                                 float* __restrict__ out,
                                                 u16* __restrict__ outb, int nrows) {
  int w = threadIdx.x >> 6, ln = threadIdx.x & 63;
  int row = blockIdx.x * 4 + w;
  if (row >= nrows) return;
  const float* xr = x + (size_t)row * 512;
  float v[8];
#pragma unroll
  for (int c = 0; c < 2; ++c) {
    float4 a = *(const float4*)(xr + (ln << 3) + (c << 2));
    v[c * 4 + 0] = a.x; v[c * 4 + 1] = a.y; v[c * 4 + 2] = a.z; v[c * 4 + 3] = a.w;
    if (RESID) {
      float4 r4 = *(const float4*)(res + (size_t)row * 512 + (ln << 3) + (c << 2));
      v[c * 4 + 0] += r4.x; v[c * 4 + 1] += r4.y; v[c * 4 + 2] += r4.z; v[c * 4 + 3] += r4.w;
    }
  }
  float sum = 0.f;
#pragma unroll
  for (int c = 0; c < 8; ++c) sum += v[c];
#pragma unroll
  for (int off = 32; off; off >>= 1) sum += __shfl_xor(sum, off);
  float mu = sum * (1.f / 512.f);
  float vs = 0.f;
#pragma unroll
  for (int c = 0; c < 8; ++c) { float d = v[c] - mu; vs += d * d; }
#pragma unroll
  for (int off = 32; off; off >>= 1) vs += __shfl_xor(vs, off);
  float rstd = 1.f / sqrtf(vs * (1.f / 512.f) + EPS_LN);
  float mk = MASK ? mask[row] : 1.f;
  float* orow = out + (size_t)row * 512;
  u16* brow = outb ? outb + (size_t)row * 512 : nullptr;
#pragma unroll
  for (int c = 0; c < 2; ++c) {
    int col = (ln << 3) + (c << 2);
    float o[4];
#pragma unroll
    for (int q = 0; q < 4; ++q)
      o[q] = ((v[c * 4 + q] - mu) * rstd * gam[col + q] + bet[col + q]) * mk;
    *(float4*)(orow + col) = make_float4(o[0], o[1], o[2], o[3]);
    if (brow) {
      ushort4 ob = { f2b(o[0]), f2b(o[1]), f2b(o[2]), f2b(o[3]) };
      *(ushort4*)(brow + col) = ob;
    }
  }
}

// ---------------------------------------------------------------------------
// Weight transpose + bf16 cast: W f32 [K][N] row-major -> Wt bf16 [N][K].
// ---------------------------------------------------------------------------
__global__ __launch_bounds__(256) void wtrans_kernel(const float* __restrict__ W,
                                                     u16* __restrict__ Wt,
                                                     int K, int N, long wstride, long tstride) {
  __shared__ float tl[32][33];
  int z = blockIdx.z;
  W += (size_t)z * wstride;
  Wt += (size_t)z * tstride;
  int n0 = blockIdx.x * 32, k0 = blockIdx.y * 32;
  int c = threadIdx.x & 31, r8 = threadIdx.x >> 5;
#pragma unroll
  for (int p = 0; p < 4; ++p) {
    int r = r8 + p * 8;
    int k = k0 + r, n = n0 + c;
    tl[r][c] = (k < K && n < N) ? W[(size_t)k * N + n] : 0.f;
  }
  __syncthreads();
#pragma unroll
  for (int p = 0; p < 4; ++p) {
    int r = r8 + p * 8;
    int n = n0 + r, k = k0 + c;
    if (n < N && k < K) Wt[(size_t)n * K + k] = f2b(tl[c][r]);
  }
}

// ---------------------------------------------------------------------------
// V transpose: qkv v-cols -> vT [64(bh)][64(d)][512(j)] bf16.
// ---------------------------------------------------------------------------
__global__ __launch_bounds__(256) void vtrans_kernel(const u16* __restrict__ qkv,
                                                     u16* __restrict__ vT) {
  __shared__ u16 tl[32][33];
  int z = blockIdx.z;  // b*8+h
  int b = z >> 3, h = z & 7;
  int j0 = blockIdx.x * 32, d0 = blockIdx.y * 32;
  int c = threadIdx.x & 31, r8 = threadIdx.x >> 5;
#pragma unroll
  for (int p = 0; p < 4; ++p) {
    int r = r8 + p * 8;
    tl[r][c] = qkv[(size_t)(b * 512 + j0 + r) * 1536 + 1024 + h * 64 + d0 + c];
  }
  __syncthreads();
#pragma unroll
  for (int p = 0; p < 4; ++p) {
    int r = r8 + p * 8;
    vT[(size_t)z * 32768 + (size_t)(d0 + r) * 512 + j0 + c] = tl[c][r];
  }
}

// ---------------------------------------------------------------------------
// 128x64-tile bf16 MFMA GEMM: C[M,N] = A[M,K] @ B[N,K]^T (+bias, +gelu).
// 4 waves (2x2), each 64x32 via 4x2 frags of mfma_f32_16x16x32_bf16.
// M%128==0, N%64==0, K%64==0 required.
// ---------------------------------------------------------------------------
template <int EPI, typename CT>
__global__ __launch_bounds__(256) void gemm128(const u16* __restrict__ A,
                                               const u16* __restrict__ B,
                                               const float* __restrict__ bias,
                                               CT* __restrict__ C,
                                               int M, int N, int K,
                                               int lda, int ldb, int ldc) {
  __shared__ u16 As[128][72];
  __shared__ u16 Bs[64][72];
  int t = threadIdx.x;
  int m0 = blockIdx.y * 128, n0 = blockIdx.x * 64;
  int w = t >> 6, l = t & 63;
  int wr = w >> 1, wc = w & 1, lr = l & 15, kg = l >> 4;
  f32x4 acc[4][2] = {};
  for (int k0 = 0; k0 < K; k0 += 64) {
#pragma unroll
    for (int p = 0; p < 4; ++p) {  // A: 128 rows x 8 chunks
      int c = t + (p << 8);
      int row = c >> 3, q = c & 7;
      *(uint4*)(&As[row][q * 8]) =
          *(const uint4*)(A + (size_t)(m0 + row) * lda + k0 + q * 8);
    }
#pragma unroll
    for (int p = 0; p < 2; ++p) {  // B: 64 rows x 8 chunks
      int c = t + (p << 8);
      int row = c >> 3, q = c & 7;
      *(uint4*)(&Bs[row][q * 8]) =
          *(const uint4*)(B + (size_t)(n0 + row) * ldb + k0 + q * 8);
    }
    __syncthreads();
#pragma unroll
    for (int s = 0; s < 2; ++s) {
      bf16x8 a[4], bb[2];
#pragma unroll
      for (int m = 0; m < 4; ++m)
        a[m] = *(const bf16x8*)(&As[wr * 64 + m * 16 + lr][kg * 8 + s * 32]);
#pragma unroll
      for (int n = 0; n < 2; ++n)
        bb[n] = *(const bf16x8*)(&Bs[wc * 32 + n * 16 + lr][kg * 8 + s * 32]);
#pragma unroll
      for (int m = 0; m < 4; ++m)
#pragma unroll
        for (int n = 0; n < 2; ++n)
          acc[m][n] = __builtin_amdgcn_mfma_f32_16x16x32_bf16(a[m], bb[n], acc[m][n], 0, 0, 0);
    }
    __syncthreads();
  }
#pragma unroll
  for (int m = 0; m < 4; ++m)
#pragma unroll
    for (int n = 0; n < 2; ++n) {
      int col = n0 + wc * 32 + n * 16 + lr;
      float bv = (EPI >= 1) ? bias[col] : 0.f;
#pragma unroll
      for (int r = 0; r < 4; ++r) {
        int row = m0 + wr * 64 + m * 16 + kg * 4 + r;
        float v = acc[m][n][r] + bv;
        if (EPI == 2) v = gelu_exact(v);
        if constexpr (sizeof(CT) == 2) {
          ((u16*)C)[(size_t)row * ldc + col] = f2b(v);
        } else {
          ((float*)C)[(size_t)row * ldc + col] = v;
        }
      }
    }
}

// ---------------------------------------------------------------------------
// 64x64-tile bf16 MFMA GEMM (kept for K=64 batched pos-GEMMs + classifier).
// ---------------------------------------------------------------------------
template <int EPI, typename CT>
__global__ __launch_bounds__(256) void gemm_bf16(const u16* __restrict__ A,
                                                 const u16* __restrict__ B,
                                                 const float* __restrict__ bias,
                                                 CT* __restrict__ C,
                                                 int M, int N, int K,
                                                 int lda, int ldb, int ldc,
                                                 long sAb, long sAh, long sBb, long sBh,
                                                 long sCb, long sCh) {
  __shared__ u16 As[64][72];
  __shared__ u16 Bs[64][72];
  int t = threadIdx.x;
  int z = blockIdx.z, zb = z >> 3, zh = z & 7;
  A += (size_t)zb * sAb + (size_t)zh * sAh;
  B += (size_t)zb * sBb + (size_t)zh * sBh;
  C += (size_t)zb * sCb + (size_t)zh * sCh;
  int m0 = blockIdx.y * 64, n0 = blockIdx.x * 64;
  int w = t >> 6, l = t & 63;
  int wr = w >> 1, wc = w & 1, lr = l & 15, kg = l >> 4;
  f32x4 acc[2][2] = {};
  for (int k0 = 0; k0 < K; k0 += 64) {
#pragma unroll
    for (int p = 0; p < 2; ++p) {
      int c = t + (p << 8);
      int row = c >> 3, q = c & 7;
      uint4 av = *(const uint4*)(A + (size_t)(m0 + row) * lda + k0 + q * 8);
      *(uint4*)(&As[row][q * 8]) = av;
      uint4 bv = make_uint4(0u, 0u, 0u, 0u);
      if (n0 + row < N) bv = *(const uint4*)(B + (size_t)(n0 + row) * ldb + k0 + q * 8);
      *(uint4*)(&Bs[row][q * 8]) = bv;
    }
    __syncthreads();
#pragma unroll
    for (int s = 0; s < 2; ++s) {
      bf16x8 a0 = *(const bf16x8*)(&As[wr * 32 + lr][kg * 8 + s * 32]);
      bf16x8 a1 = *(const bf16x8*)(&As[wr * 32 + 16 + lr][kg * 8 + s * 32]);
      bf16x8 b0 = *(const bf16x8*)(&Bs[wc * 32 + lr][kg * 8 + s * 32]);
      bf16x8 b1 = *(const bf16x8*)(&Bs[wc * 32 + 16 + lr][kg * 8 + s * 32]);
      acc[0][0] = __builtin_amdgcn_mfma_f32_16x16x32_bf16(a0, b0, acc[0][0], 0, 0, 0);
      acc[0][1] = __builtin_amdgcn_mfma_f32_16x16x32_bf16(a0, b1, acc[0][1], 0, 0, 0);
      acc[1][0] = __builtin_amdgcn_mfma_f32_16x16x32_bf16(a1, b0, acc[1][0], 0, 0, 0);
      acc[1][1] = __builtin_amdgcn_mfma_f32_16x16x32_bf16(a1, b1, acc[1][1], 0, 0, 0);
    }
    __syncthreads();
  }
#pragma unroll
  for (int m = 0; m < 2; ++m)
#pragma unroll
    for (int n = 0; n < 2; ++n) {
      int col = n0 + wc * 32 + n * 16 + lr;
      if (col < N) {
        float bv = (EPI >= 1) ? bias[col] : 0.f;
#pragma unroll
        for (int r = 0; r < 4; ++r) {
          int row = m0 + wr * 32 + m * 16 + kg * 4 + r;
          float v = acc[m][n][r] + bv;
          if (EPI == 2) v = gelu_exact(v);
          if constexpr (sizeof(CT) == 2) {
            ((u16*)C)[(size_t)row * ldc + col] = f2b(v);
          } else {
            ((float*)C)[(size_t)row * ldc + col] = v;
          }
        }
      }
    }
}

// ---------------------------------------------------------------------------
// Fused disentangled attention, SPLIT-J (flash-decoding style).
// qkv: [4608][1536] = q|k|v (rows 4096.. = pq|pk|--).
// ---------------------------------------------------------------------------
__global__ __launch_bounds__(256) void attn_fused(const u16* __restrict__ qkv,
                                                  const u16* __restrict__ vT,
                                                  const u16* __restrict__ Qpk,
                                                  const u16* __restrict__ KpqT,
                                                  const float* __restrict__ mask,
                                                  const int* __restrict__ crel,
                                                  u16* __restrict__ po,
                                                  float* __restrict__ pms) {
  __shared__ u16 ks[64][72];        //  9216 B (K tile; re-used as P tile)
  __shared__ u16 vs[64][72];        //  9216 B
  __shared__ u16 kpq_s[128][72];    // 18432 B
  __shared__ u16 crl16[1024];       //  2048 B  -> 38912 B total
  int t = threadIdx.x;
  int it = blockIdx.x;       // 0..7
  int z = blockIdx.y;        // b*8+h
  int js = blockIdx.z;       // 0..3
  int b = z >> 3, h = z & 7;
  int i0 = it * 64;
  int w = t >> 6, l = t & 63;
  int lr = l & 15, kg = l >> 4;

  for (int c = t; c < 1023; c += 256) crl16[c] = (u16)crel[c];

  // q fragments straight from global (one-time, 2x16B per lane)
  const u16* qrow = qkv + (size_t)(b * 512 + i0 + w * 16 + lr) * 1536 + h * 64;
  bf16x8 qa0 = *(const bf16x8*)(qrow + kg * 8);
  bf16x8 qa1 = *(const bf16x8*)(qrow + kg * 8 + 32);

  float m_run[4], s_run[4];
  f32x4 o[4] = {};
  float mi[4];
#pragma unroll
  for (int r = 0; r < 4; ++r) {
    m_run[r] = NEGMAX;
    s_run[r] = 0.f;
    mi[r] = mask[b * 512 + i0 + w * 16 + kg * 4 + r];
  }
  const u16* qpk_base = Qpk + (size_t)z * 262144;   // [i][bucket], 512x512
  const u16* kpq_base = KpqT + (size_t)z * 327680;  // [bucket][j], 640x512 (guarded)
  __syncthreads();  // crl16 ready

  for (int jj = 0; jj < 2; ++jj) {
    int j0 = (js * 2 + jj) * 64;
    int idx_base = crl16[i0 - j0 - 63 + 511];  // min idx over tile (monotone)
    __syncthreads();  // previous tile fully consumed (ks-as-P, vs, kpq_s)
    for (int c = t; c < 512; c += 256) {
      int row = c >> 3, off = (c & 7) * 8;
      *(uint4*)(&ks[row][off]) =
          *(const uint4*)(qkv + (size_t)(b * 512 + j0 + row) * 1536 + 512 + h * 64 + off);
      *(uint4*)(&vs[row][off]) =
          *(const uint4*)(vT + (size_t)z * 32768 + (size_t)row * 512 + j0 + off);
    }
    // kpq_s[128][64] <- KpqT[idx_base+row][j0 .. j0+63]
    for (int c = t; c < 1024; c += 256) {
      int row = c >> 3, off = (c & 7) * 8;
      *(uint4*)(&kpq_s[row][off]) =
          *(const uint4*)(kpq_base + (size_t)(idx_base + row) * 512 + j0 + off);
    }
    __syncthreads();
    // scores: 4 n-frags of 16 cols
    f32x4 sc[4];
#pragma unroll
    for (int nf = 0; nf < 4; ++nf) {
      bf16x8 kb0 = *(const bf16x8*)(&ks[nf * 16 + lr][kg * 8]);
      bf16x8 kb1 = *(const bf16x8*)(&ks[nf * 16 + lr][kg * 8 + 32]);
      f32x4 a = {};
      a = __builtin_amdgcn_mfma_f32_16x16x32_bf16(qa0, kb0, a, 0, 0, 0);
      a = __builtin_amdgcn_mfma_f32_16x16x32_bf16(qa1, kb1, a, 0, 0, 0);
      sc[nf] = a;
    }
    // bias gather (Qpk: global/L2; Kpq: LDS) + mask + online softmax
    float mj[4];
#pragma unroll
    for (int nf = 0; nf < 4; ++nf) mj[nf] = mask[b * 512 + j0 + nf * 16 + lr];
    float lgv[4][4];
    bool ok[4][4];
    float tmax[4] = {NEGMAX, NEGMAX, NEGMAX, NEGMAX};
    int iloc = w * 16 + kg * 4;                 // local i of r=0
#pragma unroll
    for (int nf = 0; nf < 4; ++nf) {
      int jloc = nf * 16 + lr;
      int relc = i0 + iloc - (j0 + jloc) + 511;  // rel index of r=0
#pragma unroll
      for (int r = 0; r < 4; ++r) {
        int idx = crl16[relc + r];
        float bias = b2f(qpk_base[(size_t)(i0 + iloc + r) * 512 + idx]) +
                     b2f(kpq_s[idx - idx_base][jloc]);
        bool o_ = (mi[r] * mj[nf]) > 0.f;
        float v = o_ ? (sc[nf][r] + bias) * INV_SCALE : NEGMAX;
        ok[nf][r] = o_;
        lgv[nf][r] = v;
        tmax[r] = fmaxf(tmax[r], v);
      }
    }
#pragma unroll
    for (int r = 0; r < 4; ++r) {
#pragma unroll
      for (int off = 8; off; off >>= 1) tmax[r] = fmaxf(tmax[r], __shfl_xor(tmax[r], off));
    }
    float tsum[4];
#pragma unroll
    for (int r = 0; r < 4; ++r) {
      float mn = fmaxf(m_run[r], tmax[r]);
      float scale = (mn <= -1e37f) ? 1.f : __expf(m_run[r] - mn);
      m_run[r] = mn;
      s_run[r] *= scale;
      o[0][r] *= scale; o[1][r] *= scale; o[2][r] *= scale; o[3][r] *= scale;
      float ls = 0.f;
#pragma unroll
      for (int nf = 0; nf < 4; ++nf) {
        float p = ok[nf][r] ? __expf(lgv[nf][r] - mn) : 0.f;
        lgv[nf][r] = p;
        ls += p;
      }
      tsum[r] = ls;
    }
#pragma unroll
    for (int r = 0; r < 4; ++r) {
#pragma unroll
      for (int off = 8; off; off >>= 1) tsum[r] += __shfl_xor(tsum[r], off);
      s_run[r] += tsum[r];
    }
    // all waves done reading ks -> reuse it as per-wave P buffer
    __syncthreads();
#pragma unroll
    for (int nf = 0; nf < 4; ++nf)
#pragma unroll
      for (int r = 0; r < 4; ++r) ks[w * 16 + kg * 4 + r][nf * 16 + lr] = f2b(lgv[nf][r]);
    bf16x8 pa0 = *(const bf16x8*)(&ks[w * 16 + lr][kg * 8]);
    bf16x8 pa1 = *(const bf16x8*)(&ks[w * 16 + lr][kg * 8 + 32]);
    // PV accumulate
#pragma unroll
    for (int nf = 0; nf < 4; ++nf) {
      bf16x8 vb0 = *(const bf16x8*)(&vs[nf * 16 + lr][kg * 8]);
      bf16x8 vb1 = *(const bf16x8*)(&vs[nf * 16 + lr][kg * 8 + 32]);
      o[nf] = __builtin_amdgcn_mfma_f32_16x16x32_bf16(pa0, vb0, o[nf], 0, 0, 0);
      o[nf] = __builtin_amdgcn_mfma_f32_16x16x32_bf16(pa1, vb1, o[nf], 0, 0, 0);
    }
  }
  // write unnormalized partials
#pragma unroll
  for (int r = 0; r < 4; ++r) {
    int i = i0 + w * 16 + kg * 4 + r;
    size_t pb = (((size_t)js * 64 + z) * 512 + i) * 64;
#pragma unroll
    for (int nf = 0; nf < 4; ++nf) po[pb + nf * 16 + lr] = f2b(o[nf][r]);
    if (lr == 0) {
      size_t mb = (((size_t)js * 64 + z) * 512 + i) * 2;
      pms[mb + 0] = m_run[r];
      pms[mb + 1] = s_run[r];
    }
  }
}

// ---------------------------------------------------------------------------
// Merge 4 j-split partials -> normalized ctx (bf16).
// ---------------------------------------------------------------------------
__global__ __launch_bounds__(256) void merge_kernel(const u16* __restrict__ po,
                                                    const float* __restrict__ pms,
                                                    u16* __restrict__ ctx) {
  int t = threadIdx.x;
  int w = t >> 6, d = t & 63;
  int row = blockIdx.x * 4 + w;   // 0..32767
  int z = row >> 9, i = row & 511;
  int b = z >> 3, h = z & 7;
  float mv[4], sv[4], m = NEGMAX;
#pragma unroll
  for (int js = 0; js < 4; ++js) {
    size_t mb = (((size_t)js * 64 + z) * 512 + i) * 2;
    mv[js] = pms[mb + 0];
    sv[js] = pms[mb + 1];
    m = fmaxf(m, mv[js]);
  }
  float o = 0.f, s = 0.f;
#pragma unroll
  for (int js = 0; js < 4; ++js) {
    float wgt = (mv[js] <= -1e37f) ? 0.f : __expf(mv[js] - m);
    o += wgt * b2f(po[(((size_t)js * 64 + z) * 512 + i) * 64 + d]);
    s += wgt * sv[js];
  }
  float r = (s > 0.f) ? o / s : 0.f;
  ctx[(size_t)(b * 512 + i) * 512 + h * 64 + d] = f2b(r);
}

// ---------------------------------------------------------------------------
// Host launch
// ---------------------------------------------------------------------------
extern "C" void kernel_launch(void* const* d_in, const int* in_sizes, int n_in,
                              void* d_out, int out_size, void* d_ws, size_t ws_size,
                              hipStream_t stream) {
  const float* x       = (const float*)d_in[0];
  const float* mask    = (const float*)d_in[1];
  const float* emb_s   = (const float*)d_in[2];
  const float* emb_b   = (const float*)d_in[3];
  const float* rel_emb = (const float*)d_in[4];
  const float* rel_s   = (const float*)d_in[5];
  const float* rel_b   = (const float*)d_in[6];
  const float* Wq = (const float*)d_in[7];
  const float* bq = (const float*)d_in[8];
  const float* Wk = (const float*)d_in[9];
  const float* bk = (const float*)d_in[10];
  const float* Wv = (const float*)d_in[11];
  const float* bv = (const float*)d_in[12];
  const float* Wo = (const float*)d_in[13];
  const float* bo = (const float*)d_in[14];
  const float* as_ = (const float*)d_in[15];
  const float* ab_ = (const float*)d_in[16];
  const float* Wi = (const float*)d_in[17];
  const float* bi = (const float*)d_in[18];
  const float* Wf = (const float*)d_in[19];
  const float* bf_ = (const float*)d_in[20];
  const float* fs_ = (const float*)d_in[21];
  const float* fb_ = (const float*)d_in[22];
  const float* Wc = (const float*)d_in[23];
  const float* bc = (const float*)d_in[24];
  float* out = (float*)d_out;

  char* p = (char*)d_ws;
  auto alloc = [&](size_t bytes) {
    char* r = p;
    p += (bytes + 255) & ~(size_t)255;
    return r;
  };
  // Union region: tmpA | mid | hbf are dead during attn+merge; the attention
  // partials (po: 16.78 MB bf16, pms: 1.05 MB f32) overlay them. hbf rows >=
  // 4096 (rel_e, persistent) start beyond pms' end, never clobbered; LN
  // rewrites hbf rows 0..4095 before the next consumer reads them.
  float* hcat = (float*)alloc((size_t)4608 * 512 * 4);
  float* tmpA = (float*)alloc((size_t)4096 * 512 * 4);  // union base
  u16* mid  = (u16*)alloc((size_t)4096 * 768 * 2);
  u16* hbf  = (u16*)alloc((size_t)4608 * 512 * 2);
  u16* po   = (u16*)tmpA;                               // [4][64][512][64] bf16
  float* pms = (float*)((char*)tmpA + (size_t)4 * 64 * 512 * 64 * 2);  // [4][64][512][2]
  u16* qkv  = (u16*)alloc((size_t)4608 * 1536 * 2);     // q|k|v (+pq|pk rows)
  u16* vT   = (u16*)alloc((size_t)64 * 64 * 512 * 2);   // [bh][d][j]
  u16* ctxb = (u16*)alloc((size_t)4096 * 512 * 2);
  u16* WtQKV = (u16*)alloc((size_t)3 * 1536 * 512 * 2);
  u16* WtO  = (u16*)alloc((size_t)3 * 512 * 512 * 2);
  u16* WtI  = (u16*)alloc((size_t)3 * 768 * 512 * 2);
  u16* WtF  = (u16*)alloc((size_t)3 * 512 * 768 * 2);
  u16* WtC  = (u16*)alloc((size_t)100 * 512 * 2);
  float* bqkv = (float*)alloc((size_t)3 * 1536 * 4);
  u16* Qpk  = (u16*)alloc((size_t)64 * 512 * 512 * 2);  // [bh][i][bucket]
  u16* KpqT = (u16*)alloc((size_t)64 * 640 * 512 * 2);  // [bh][bucket][j], guard rows
  int* crel = (int*)alloc((size_t)1024 * 4);

  relbucket_kernel<<<4, 256, 0, stream>>>(crel);
  biascat_kernel<<<18, 256, 0, stream>>>(bq, bk, bv, bqkv);
  // WtQKV[l][n][k]: n 0..511 = Wq, 512..1023 = Wk, 1024..1535 = Wv
  wtrans_kernel<<<dim3(16, 16, 3), 256, 0, stream>>>(Wq, WtQKV, 512, 512, 262144, 786432);
  wtrans_kernel<<<dim3(16, 16, 3), 256, 0, stream>>>(Wk, WtQKV + 262144, 512, 512, 262144, 786432);
  wtrans_kernel<<<dim3(16, 16, 3), 256, 0, stream>>>(Wv, WtQKV + 524288, 512, 512, 262144, 786432);
  wtrans_kernel<<<dim3(16, 16, 3), 256, 0, stream>>>(Wo, WtO, 512, 512, 262144, 262144);
  wtrans_kernel<<<dim3(24, 16, 3), 256, 0, stream>>>(Wi, WtI, 512, 768, 393216, 393216);
  wtrans_kernel<<<dim3(16, 24, 3), 256, 0, stream>>>(Wf, WtF, 768, 512, 393216, 393216);
  wtrans_kernel<<<dim3(4, 16, 1), 256, 0, stream>>>(Wc, WtC, 512, 100, 0, 0);
  ln_kernel<false, true><<<1024, 256, 0, stream>>>(x, nullptr, emb_s, emb_b, mask,
                                                   hcat, hbf, 4096);
  ln_kernel<false, false><<<128, 256, 0, stream>>>(rel_emb, nullptr, rel_s, rel_b, nullptr,
                                                   hcat + (size_t)4096 * 512,
                                                   hbf + (size_t)4096 * 512, 512);

  for (int l = 0; l < 3; ++l) {
    // fused q|k|v (+pq|pk) projection: [4608][1536]
    gemm128<1, u16><<<dim3(24, 36), 256, 0, stream>>>(
        hbf, WtQKV + (size_t)l * 786432, bqkv + l * 1536, qkv,
        4608, 1536, 512, 512, 512, 1536);
    vtrans_kernel<<<dim3(16, 2, 64), 256, 0, stream>>>(qkv, vT);
    // Qpk[b,h][i][r] = q @ pk^T ; KpqT[b,h][r][j] = pq @ k^T (swapped operands)
    gemm_bf16<0, u16><<<dim3(8, 8, 64), 256, 0, stream>>>(
        qkv, qkv + (size_t)4096 * 1536 + 512, nullptr, Qpk, 512, 512, 64,
        1536, 1536, 512, 786432, 64, 0, 64, 2097152, 262144);
    gemm_bf16<0, u16><<<dim3(8, 8, 64), 256, 0, stream>>>(
        qkv + (size_t)4096 * 1536, qkv + 512, nullptr, KpqT, 512, 512, 64,
        1536, 1536, 512, 0, 64, 786432, 64, 2621440, 327680);
    // fused QK^T + bias + XSoftmax + PV, 4-way j-split, then merge
    attn_fused<<<dim3(8, 64, 4), 256, 0, stream>>>(qkv, vT, Qpk, KpqT, mask, crel,
                                                   po, pms);
    merge_kernel<<<8192, 256, 0, stream>>>(po, pms, ctxb);
    // O proj -> fp32, LN(+h)
    gemm128<1, float><<<dim3(8, 32), 256, 0, stream>>>(
        ctxb, WtO + (size_t)l * 262144, bo + l * 512, tmpA, 4096, 512, 512, 512, 512, 512);
    ln_kernel<true, false><<<1024, 256, 0, stream>>>(tmpA, hcat, as_ + l * 512, ab_ + l * 512,
                                                     nullptr, hcat, hbf, 4096);
    // FFN
    gemm128<2, u16><<<dim3(12, 32), 256, 0, stream>>>(
        hbf, WtI + (size_t)l * 393216, bi + l * 768, mid, 4096, 768, 512, 512, 512, 768);
    gemm128<1, float><<<dim3(8, 32), 256, 0, stream>>>(
        mid, WtF + (size_t)l * 393216, bf_ + l * 512, tmpA, 4096, 512, 768, 768, 768, 512);
    ln_kernel<true, false><<<1024, 256, 0, stream>>>(tmpA, hcat, fs_ + l * 512, fb_ + l * 512,
                                                     nullptr, hcat, hbf, 4096);
  }
  gemm_bf16<1, float><<<dim3(2, 64, 1), 256, 0, stream>>>(
      hbf, WtC, bc, out, 4096, 100, 512, 512, 512, 100, 0, 0, 0, 0, 0, 0);
}

// Round 9
// 482.850 us; speedup vs baseline: 7.2485x; 1.0777x over previous
//
#include <hip/hip_runtime.h>
#include <hip/hip_bf16.h>
#include <math.h>

// B=8, S=512, HID=512, HEADS=8, DH=64, FF=768, NL=3, SPAN=256, MAXP=512, VOCAB=100
#define EPS_LN 1e-7f
#define INV_SCALE 0.072168783648703221f   // 1/sqrt(64*3)
#define NEGMAX -3.402823466e38f

typedef unsigned short u16;
typedef __attribute__((ext_vector_type(8))) short bf16x8;  // 8 bf16 = 4 VGPRs
typedef __attribute__((ext_vector_type(4))) float f32x4;

__device__ __forceinline__ u16 f2b(float f) {
  union { float f; unsigned int u; } v; v.f = f;
  unsigned int r = v.u + 0x7FFFu + ((v.u >> 16) & 1u);
  return (u16)(r >> 16);
}
__device__ __forceinline__ float b2f(u16 u) {
  union { unsigned int u; float f; } v; v.u = ((unsigned int)u) << 16;
  return v.f;
}
__device__ __forceinline__ float gelu_exact(float v) {
  return 0.5f * v * (1.f + erff(v * 0.70710678118654752440f));
}

// ---------------------------------------------------------------------------
// Relative-position bucket table (1-D; crel monotone nondecreasing, step<=1).
// ---------------------------------------------------------------------------
__global__ __launch_bounds__(256) void relbucket_kernel(int* __restrict__ crel) {
  int idx = blockIdx.x * 256 + threadIdx.x;
  if (idx >= 1023) return;
  int rel = idx - 511;
  int a = (rel < 128 && rel > -128) ? 127 : (rel < 0 ? -rel : rel);
  int bucket;
  if (a <= 128) {
    bucket = rel;
  } else {
    double lp = ceil(log((double)a / 128.0) / log(511.0 / 128.0) * 127.0) + 128.0;
    int l = (int)lp;
    bucket = (rel > 0) ? l : -l;
  }
  int c = bucket + 256;
  c = c < 0 ? 0 : (c > 511 ? 511 : c);
  crel[idx] = c;
}

// ---------------------------------------------------------------------------
// Bias concat: [3][1536] = bq|bk|bv per layer.
// ---------------------------------------------------------------------------
__global__ __launch_bounds__(256) void biascat_kernel(const float* __restrict__ bq,
                                                      const float* __restrict__ bk,
                                                      const float* __restrict__ bv,
                                                      float* __restrict__ o) {
  int i = blockIdx.x * 256 + threadIdx.x;  // 3*1536
  if (i >= 4608) return;
  int l = i / 1536, c = i - l * 1536;
  float v = (c < 512) ? bq[l * 512 + c]
                      : (c < 1024) ? bk[l * 512 + c - 512] : bv[l * 512 + c - 1024];
  o[i] = v;
}

// ---------------------------------------------------------------------------
// LayerNorm over 512 cols; writes fp32 master and optional bf16 mirror.
// ---------------------------------------------------------------------------
template <bool RESID, bool MASK>
__global__ __launch_bounds__(256) void ln_kernel(const float* __restrict__ x,
                                                 const float* __restrict__ res,
                                                 const float* __restrict__ gam,
                                                 const float* __restrict__ bet,
                                                 const float* __restrict__ mask,
                                                 float* __restrict__ out,
                                                 u16* __restrict__ outb, int nrows) {
  int w = threadIdx.x >> 6, ln = threadIdx.x & 63;
  int row = blockIdx.x * 4 + w;
  if (row >= nrows) return;
  const float* xr = x + (size_t)row * 512;
  float v[8];
#pragma unroll
  for (int c = 0; c < 2; ++c) {
    float4 a = *(const float4*)(xr + (ln << 3) + (c << 2));
    v[c * 4 + 0] = a.x; v[c * 4 + 1] = a.y; v[c * 4 + 2] = a.z; v[c * 4 + 3] = a.w;
    if (RESID) {
      float4 r4 = *(const float4*)(res + (size_t)row * 512 + (ln << 3) + (c << 2));
      v[c * 4 + 0] += r4.x; v[c * 4 + 1] += r4.y; v[c * 4 + 2] += r4.z; v[c * 4 + 3] += r4.w;
    }
  }
  float sum = 0.f;
#pragma unroll
  for (int c = 0; c < 8; ++c) sum += v[c];
#pragma unroll
  for (int off = 32; off; off >>= 1) sum += __shfl_xor(sum, off);
  float mu = sum * (1.f / 512.f);
  float vs = 0.f;
#pragma unroll
  for (int c = 0; c < 8; ++c) { float d = v[c] - mu; vs += d * d; }
#pragma unroll
  for (int off = 32; off; off >>= 1) vs += __shfl_xor(vs, off);
  float rstd = 1.f / sqrtf(vs * (1.f / 512.f) + EPS_LN);
  float mk = MASK ? mask[row] : 1.f;
  float* orow = out + (size_t)row * 512;
  u16* brow = outb ? outb + (size_t)row * 512 : nullptr;
#pragma unroll
  for (int c = 0; c < 2; ++c) {
    int col = (ln << 3) + (c << 2);
    float o[4];
#pragma unroll
    for (int q = 0; q < 4; ++q)
      o[q] = ((v[c * 4 + q] - mu) * rstd * gam[col + q] + bet[col + q]) * mk;
    *(float4*)(orow + col) = make_float4(o[0], o[1], o[2], o[3]);
    if (brow) {
      ushort4 ob = { f2b(o[0]), f2b(o[1]), f2b(o[2]), f2b(o[3]) };
      *(ushort4*)(brow + col) = ob;
    }
  }
}

// ---------------------------------------------------------------------------
// Weight transpose + bf16 cast: W f32 [K][N] row-major -> Wt bf16 [N][K].
// ---------------------------------------------------------------------------
__global__ __launch_bounds__(256) void wtrans_kernel(const float* __restrict__ W,
                                                     u16* __restrict__ Wt,
                                                     int K, int N, long wstride, long tstride) {
  __shared__ float tl[32][33];
  int z = blockIdx.z;
  W += (size_t)z * wstride;
  Wt += (size_t)z * tstride;
  int n0 = blockIdx.x * 32, k0 = blockIdx.y * 32;
  int c = threadIdx.x & 31, r8 = threadIdx.x >> 5;
#pragma unroll
  for (int p = 0; p < 4; ++p) {
    int r = r8 + p * 8;
    int k = k0 + r, n = n0 + c;
    tl[r][c] = (k < K && n < N) ? W[(size_t)k * N + n] : 0.f;
  }
  __syncthreads();
#pragma unroll
  for (int p = 0; p < 4; ++p) {
    int r = r8 + p * 8;
    int n = n0 + r, k = k0 + c;
    if (n < N && k < K) Wt[(size_t)n * K + k] = f2b(tl[c][r]);
  }
}

// ---------------------------------------------------------------------------
// V transpose: qkv v-cols -> vT [64(bh)][64(d)][512(j)] bf16.
// ---------------------------------------------------------------------------
__global__ __launch_bounds__(256) void vtrans_kernel(const u16* __restrict__ qkv,
                                                     u16* __restrict__ vT) {
  __shared__ u16 tl[32][33];
  int z = blockIdx.z;  // b*8+h
  int b = z >> 3, h = z & 7;
  int j0 = blockIdx.x * 32, d0 = blockIdx.y * 32;
  int c = threadIdx.x & 31, r8 = threadIdx.x >> 5;
#pragma unroll
  for (int p = 0; p < 4; ++p) {
    int r = r8 + p * 8;
    tl[r][c] = qkv[(size_t)(b * 512 + j0 + r) * 1536 + 1024 + h * 64 + d0 + c];
  }
  __syncthreads();
#pragma unroll
  for (int p = 0; p < 4; ++p) {
    int r = r8 + p * 8;
    vT[(size_t)z * 32768 + (size_t)(d0 + r) * 512 + j0 + c] = tl[c][r];
  }
}

// ---------------------------------------------------------------------------
// 128x64-tile bf16 MFMA GEMM: C[M,N] = A[M,K] @ B[N,K]^T (+bias, +gelu).
// ---------------------------------------------------------------------------
template <int EPI, typename CT>
__global__ __launch_bounds__(256) void gemm128(const u16* __restrict__ A,
                                               const u16* __restrict__ B,
                                               const float* __restrict__ bias,
                                               CT* __restrict__ C,
                                               int M, int N, int K,
                                               int lda, int ldb, int ldc) {
  __shared__ u16 As[128][72];
  __shared__ u16 Bs[64][72];
  int t = threadIdx.x;
  int m0 = blockIdx.y * 128, n0 = blockIdx.x * 64;
  int w = t >> 6, l = t & 63;
  int wr = w >> 1, wc = w & 1, lr = l & 15, kg = l >> 4;
  f32x4 acc[4][2] = {};
  for (int k0 = 0; k0 < K; k0 += 64) {
#pragma unroll
    for (int p = 0; p < 4; ++p) {
      int c = t + (p << 8);
      int row = c >> 3, q = c & 7;
      *(uint4*)(&As[row][q * 8]) =
          *(const uint4*)(A + (size_t)(m0 + row) * lda + k0 + q * 8);
    }
#pragma unroll
    for (int p = 0; p < 2; ++p) {
      int c = t + (p << 8);
      int row = c >> 3, q = c & 7;
      *(uint4*)(&Bs[row][q * 8]) =
          *(const uint4*)(B + (size_t)(n0 + row) * ldb + k0 + q * 8);
    }
    __syncthreads();
#pragma unroll
    for (int s = 0; s < 2; ++s) {
      bf16x8 a[4], bb[2];
#pragma unroll
      for (int m = 0; m < 4; ++m)
        a[m] = *(const bf16x8*)(&As[wr * 64 + m * 16 + lr][kg * 8 + s * 32]);
#pragma unroll
      for (int n = 0; n < 2; ++n)
        bb[n] = *(const bf16x8*)(&Bs[wc * 32 + n * 16 + lr][kg * 8 + s * 32]);
#pragma unroll
      for (int m = 0; m < 4; ++m)
#pragma unroll
        for (int n = 0; n < 2; ++n)
          acc[m][n] = __builtin_amdgcn_mfma_f32_16x16x32_bf16(a[m], bb[n], acc[m][n], 0, 0, 0);
    }
    __syncthreads();
  }
#pragma unroll
  for (int m = 0; m < 4; ++m)
#pragma unroll
    for (int n = 0; n < 2; ++n) {
      int col = n0 + wc * 32 + n * 16 + lr;
      float bv = (EPI >= 1) ? bias[col] : 0.f;
#pragma unroll
      for (int r = 0; r < 4; ++r) {
        int row = m0 + wr * 64 + m * 16 + kg * 4 + r;
        float v = acc[m][n][r] + bv;
        if (EPI == 2) v = gelu_exact(v);
        if constexpr (sizeof(CT) == 2) {
          ((u16*)C)[(size_t)row * ldc + col] = f2b(v);
        } else {
          ((float*)C)[(size_t)row * ldc + col] = v;
        }
      }
    }
}

// ---------------------------------------------------------------------------
// 64x64-tile bf16 MFMA GEMM (classifier only).
// ---------------------------------------------------------------------------
template <int EPI, typename CT>
__global__ __launch_bounds__(256) void gemm_bf16(const u16* __restrict__ A,
                                                 const u16* __restrict__ B,
                                                 const float* __restrict__ bias,
                                                 CT* __restrict__ C,
                                                 int M, int N, int K,
                                                 int lda, int ldb, int ldc) {
  __shared__ u16 As[64][72];
  __shared__ u16 Bs[64][72];
  int t = threadIdx.x;
  int m0 = blockIdx.y * 64, n0 = blockIdx.x * 64;
  int w = t >> 6, l = t & 63;
  int wr = w >> 1, wc = w & 1, lr = l & 15, kg = l >> 4;
  f32x4 acc[2][2] = {};
  for (int k0 = 0; k0 < K; k0 += 64) {
#pragma unroll
    for (int p = 0; p < 2; ++p) {
      int c = t + (p << 8);
      int row = c >> 3, q = c & 7;
      uint4 av = *(const uint4*)(A + (size_t)(m0 + row) * lda + k0 + q * 8);
      *(uint4*)(&As[row][q * 8]) = av;
      uint4 bv = make_uint4(0u, 0u, 0u, 0u);
      if (n0 + row < N) bv = *(const uint4*)(B + (size_t)(n0 + row) * ldb + k0 + q * 8);
      *(uint4*)(&Bs[row][q * 8]) = bv;
    }
    __syncthreads();
#pragma unroll
    for (int s = 0; s < 2; ++s) {
      bf16x8 a0 = *(const bf16x8*)(&As[wr * 32 + lr][kg * 8 + s * 32]);
      bf16x8 a1 = *(const bf16x8*)(&As[wr * 32 + 16 + lr][kg * 8 + s * 32]);
      bf16x8 b0 = *(const bf16x8*)(&Bs[wc * 32 + lr][kg * 8 + s * 32]);
      bf16x8 b1 = *(const bf16x8*)(&Bs[wc * 32 + 16 + lr][kg * 8 + s * 32]);
      acc[0][0] = __builtin_amdgcn_mfma_f32_16x16x32_bf16(a0, b0, acc[0][0], 0, 0, 0);
      acc[0][1] = __builtin_amdgcn_mfma_f32_16x16x32_bf16(a0, b1, acc[0][1], 0, 0, 0);
      acc[1][0] = __builtin_amdgcn_mfma_f32_16x16x32_bf16(a1, b0, acc[1][0], 0, 0, 0);
      acc[1][1] = __builtin_amdgcn_mfma_f32_16x16x32_bf16(a1, b1, acc[1][1], 0, 0, 0);
    }
    __syncthreads();
  }
#pragma unroll
  for (int m = 0; m < 2; ++m)
#pragma unroll
    for (int n = 0; n < 2; ++n) {
      int col = n0 + wc * 32 + n * 16 + lr;
      if (col < N) {
        float bv = (EPI >= 1) ? bias[col] : 0.f;
#pragma unroll
        for (int r = 0; r < 4; ++r) {
          int row = m0 + wr * 32 + m * 16 + kg * 4 + r;
          float v = acc[m][n][r] + bv;
          if (EPI == 2) v = gelu_exact(v);
          if constexpr (sizeof(CT) == 2) {
            ((u16*)C)[(size_t)row * ldc + col] = f2b(v);
          } else {
            ((float*)C)[(size_t)row * ldc + col] = v;
          }
        }
      }
    }
}

// ---------------------------------------------------------------------------
// Fused disentangled attention, 8-way split-j, bias ON THE FLY via MFMA.
// Block = (i-tile 0..7, z=b*8+h, js=0..7): ONE 64x64 (i,j) tile.
// bias1[i][w] = Q-tile @ pk_window^T (64x128); bias2[w][j] = pq_window @ K^T.
// Windows (<=127 buckets, crel monotone) staged dense in LDS from qkv rel
// rows (L2-resident), then OVERWRITTEN in place by the bias tiles.
// No online softmax (single tile): partials (o, m, s) written for merge.
// LDS 47 KB -> 3 blocks/CU. V-fragments direct from global vT.
// ---------------------------------------------------------------------------
__global__ __launch_bounds__(256) void attn_fused(const u16* __restrict__ qkv,
                                                  const u16* __restrict__ vT,
                                                  const float* __restrict__ mask,
                                                  const int* __restrict__ crel,
                                                  u16* __restrict__ po,
                                                  float* __restrict__ pms) {
  __shared__ u16 ks[64][72];      //  9216 B (K tile; later per-wave P buffer)
  __shared__ u16 U1[128][72];     // 18432 B (pk window -> b1s[64][136] view)
  __shared__ u16 U2[128][72];     // 18432 B (pq window -> b2s[128][72])
  __shared__ u16 crl16[1024];     //  2048 B   -> 48128 B total
  int t = threadIdx.x;
  int it = blockIdx.x;       // 0..7
  int z = blockIdx.y;        // b*8+h
  int js = blockIdx.z;       // 0..7
  int b = z >> 3, h = z & 7;
  int i0 = it * 64, j0 = js * 64;
  int w = t >> 6, l = t & 63;
  int lr = l & 15, kg = l >> 4;

  for (int c = t; c < 1023; c += 256) crl16[c] = (u16)crel[c];
  __syncthreads();
  int ib = crl16[i0 - j0 - 63 + 511];  // min bucket over tile (monotone)

  // stage K tile + pk/pq windows (clamped rows; clamped values never gathered)
  for (int c = t; c < 512; c += 256) {
    int row = c >> 3, off = (c & 7) * 8;
    *(uint4*)(&ks[row][off]) =
        *(const uint4*)(qkv + (size_t)(b * 512 + j0 + row) * 1536 + 512 + h * 64 + off);
  }
  for (int c = t; c < 1024; c += 256) {
    int row = c >> 3, off = (c & 7) * 8;
    int rw = ib + row;
    rw = rw > 511 ? 511 : rw;
    const u16* relrow = qkv + (size_t)(4096 + rw) * 1536 + h * 64;
    *(uint4*)(&U1[row][off]) = *(const uint4*)(relrow + 512 + off);  // pk
    *(uint4*)(&U2[row][off]) = *(const uint4*)(relrow + off);        // pq
  }

  // q fragments straight from global
  const u16* qrow = qkv + (size_t)(b * 512 + i0 + w * 16 + lr) * 1536 + h * 64;
  bf16x8 qa0 = *(const bf16x8*)(qrow + kg * 8);
  bf16x8 qa1 = *(const bf16x8*)(qrow + kg * 8 + 32);
  __syncthreads();

  // QK^T scores (4 col-frags)
  f32x4 sc[4];
#pragma unroll
  for (int nf = 0; nf < 4; ++nf) {
    bf16x8 kb0 = *(const bf16x8*)(&ks[nf * 16 + lr][kg * 8]);
    bf16x8 kb1 = *(const bf16x8*)(&ks[nf * 16 + lr][kg * 8 + 32]);
    f32x4 a = {};
    a = __builtin_amdgcn_mfma_f32_16x16x32_bf16(qa0, kb0, a, 0, 0, 0);
    a = __builtin_amdgcn_mfma_f32_16x16x32_bf16(qa1, kb1, a, 0, 0, 0);
    sc[nf] = a;
  }
  // bias1 = Q @ pk_win^T : wave w owns i-rows w*16..+16, all 128 w-cols
  f32x4 b1a[8];
#pragma unroll
  for (int f = 0; f < 8; ++f) {
    bf16x8 p0 = *(const bf16x8*)(&U1[f * 16 + lr][kg * 8]);
    bf16x8 p1 = *(const bf16x8*)(&U1[f * 16 + lr][kg * 8 + 32]);
    f32x4 a = {};
    a = __builtin_amdgcn_mfma_f32_16x16x32_bf16(qa0, p0, a, 0, 0, 0);
    a = __builtin_amdgcn_mfma_f32_16x16x32_bf16(qa1, p1, a, 0, 0, 0);
    b1a[f] = a;
  }
  // bias2 = pq_win @ K^T : wave w owns bucket-rows w*32..+32 (2 groups of 16)
  f32x4 b2a[2][4];
#pragma unroll
  for (int g = 0; g < 2; ++g) {
    bf16x8 a0 = *(const bf16x8*)(&U2[w * 32 + g * 16 + lr][kg * 8]);
    bf16x8 a1 = *(const bf16x8*)(&U2[w * 32 + g * 16 + lr][kg * 8 + 32]);
#pragma unroll
    for (int f = 0; f < 4; ++f) {
      bf16x8 kb0 = *(const bf16x8*)(&ks[f * 16 + lr][kg * 8]);
      bf16x8 kb1 = *(const bf16x8*)(&ks[f * 16 + lr][kg * 8 + 32]);
      f32x4 a = {};
      a = __builtin_amdgcn_mfma_f32_16x16x32_bf16(a0, kb0, a, 0, 0, 0);
      a = __builtin_amdgcn_mfma_f32_16x16x32_bf16(a1, kb1, a, 0, 0, 0);
      b2a[g][f] = a;
    }
  }
  __syncthreads();  // all reads of U1/U2 done -> overwrite with bias tiles
  u16* b1 = &U1[0][0];  // b1s[64][136]
#pragma unroll
  for (int f = 0; f < 8; ++f)
#pragma unroll
    for (int r = 0; r < 4; ++r)
      b1[(w * 16 + kg * 4 + r) * 136 + f * 16 + lr] = f2b(b1a[f][r]);
#pragma unroll
  for (int g = 0; g < 2; ++g)
#pragma unroll
    for (int f = 0; f < 4; ++f)
#pragma unroll
      for (int r = 0; r < 4; ++r)
        U2[w * 32 + g * 16 + kg * 4 + r][f * 16 + lr] = f2b(b2a[g][f][r]);
  __syncthreads();  // b2s is read cross-wave

  // V fragments direct from global (issue early, consumed after softmax)
  bf16x8 vb[4][2];
#pragma unroll
  for (int nf = 0; nf < 4; ++nf) {
    const u16* vrow = vT + (size_t)z * 32768 + (size_t)(nf * 16 + lr) * 512 + j0;
    vb[nf][0] = *(const bf16x8*)(vrow + kg * 8);
    vb[nf][1] = *(const bf16x8*)(vrow + kg * 8 + 32);
  }

  // gather bias (both LDS) + mask + softmax (single tile: no rescale)
  float mi[4], mj[4];
#pragma unroll
  for (int r = 0; r < 4; ++r) mi[r] = mask[b * 512 + i0 + w * 16 + kg * 4 + r];
#pragma unroll
  for (int nf = 0; nf < 4; ++nf) mj[nf] = mask[b * 512 + j0 + nf * 16 + lr];
  float lgv[4][4];
  bool ok[4][4];
  float tmax[4] = {NEGMAX, NEGMAX, NEGMAX, NEGMAX};
  int iloc = w * 16 + kg * 4;
#pragma unroll
  for (int nf = 0; nf < 4; ++nf) {
    int jloc = nf * 16 + lr;
    int relc = i0 + iloc - (j0 + jloc) + 511;
#pragma unroll
    for (int r = 0; r < 4; ++r) {
      int idx = crl16[relc + r] - ib;
      float bias = b2f(b1[(iloc + r) * 136 + idx]) + b2f(U2[idx][jloc]);
      bool o_ = (mi[r] * mj[nf]) > 0.f;
      float v = o_ ? (sc[nf][r] + bias) * INV_SCALE : NEGMAX;
      ok[nf][r] = o_;
      lgv[nf][r] = v;
      tmax[r] = fmaxf(tmax[r], v);
    }
  }
#pragma unroll
  for (int r = 0; r < 4; ++r) {
#pragma unroll
    for (int off = 8; off; off >>= 1) tmax[r] = fmaxf(tmax[r], __shfl_xor(tmax[r], off));
  }
  float tsum[4];
#pragma unroll
  for (int r = 0; r < 4; ++r) {
    float mn = tmax[r];
    float ls = 0.f;
#pragma unroll
    for (int nf = 0; nf < 4; ++nf) {
      float p = ok[nf][r] ? __expf(lgv[nf][r] - mn) : 0.f;
      lgv[nf][r] = p;
      ls += p;
    }
    tsum[r] = ls;
  }
#pragma unroll
  for (int r = 0; r < 4; ++r) {
#pragma unroll
    for (int off = 8; off; off >>= 1) tsum[r] += __shfl_xor(tsum[r], off);
  }
  // P (C/D layout) -> per-wave rows of ks (wave-local, no barrier needed)
#pragma unroll
  for (int nf = 0; nf < 4; ++nf)
#pragma unroll
    for (int r = 0; r < 4; ++r) ks[w * 16 + kg * 4 + r][nf * 16 + lr] = f2b(lgv[nf][r]);
  bf16x8 pa0 = *(const bf16x8*)(&ks[w * 16 + lr][kg * 8]);
  bf16x8 pa1 = *(const bf16x8*)(&ks[w * 16 + lr][kg * 8 + 32]);
  // PV
  f32x4 o[4] = {};
#pragma unroll
  for (int nf = 0; nf < 4; ++nf) {
    o[nf] = __builtin_amdgcn_mfma_f32_16x16x32_bf16(pa0, vb[nf][0], o[nf], 0, 0, 0);
    o[nf] = __builtin_amdgcn_mfma_f32_16x16x32_bf16(pa1, vb[nf][1], o[nf], 0, 0, 0);
  }
  // write unnormalized partials
#pragma unroll
  for (int r = 0; r < 4; ++r) {
    int i = i0 + w * 16 + kg * 4 + r;
    size_t pb = (((size_t)js * 64 + z) * 512 + i) * 64;
#pragma unroll
    for (int nf = 0; nf < 4; ++nf) po[pb + nf * 16 + lr] = f2b(o[nf][r]);
    if (lr == 0) {
      size_t mb = (((size_t)js * 64 + z) * 512 + i) * 2;
      pms[mb + 0] = tmax[r];
      pms[mb + 1] = tsum[r];
    }
  }
}

// ---------------------------------------------------------------------------
// Merge 8 j-split partials -> normalized ctx (bf16).
// ---------------------------------------------------------------------------
__global__ __launch_bounds__(256) void merge_kernel(const u16* __restrict__ po,
                                                    const float* __restrict__ pms,
                                                    u16* __restrict__ ctx) {
  int t = threadIdx.x;
  int w = t >> 6, d = t & 63;
  int row = blockIdx.x * 4 + w;   // 0..32767
  int z = row >> 9, i = row & 511;
  int b = z >> 3, h = z & 7;
  float mv[8], sv[8], m = NEGMAX;
#pragma unroll
  for (int js = 0; js < 8; ++js) {
    size_t mb = (((size_t)js * 64 + z) * 512 + i) * 2;
    mv[js] = pms[mb + 0];
    sv[js] = pms[mb + 1];
    m = fmaxf(m, mv[js]);
  }
  float o = 0.f, s = 0.f;
#pragma unroll
  for (int js = 0; js < 8; ++js) {
    float wgt = (mv[js] <= -1e37f) ? 0.f : __expf(mv[js] - m);
    o += wgt * b2f(po[(((size_t)js * 64 + z) * 512 + i) * 64 + d]);
    s += wgt * sv[js];
  }
  float r = (s > 0.f) ? o / s : 0.f;
  ctx[(size_t)(b * 512 + i) * 512 + h * 64 + d] = f2b(r);
}

// ---------------------------------------------------------------------------
// Host launch
// ---------------------------------------------------------------------------
extern "C" void kernel_launch(void* const* d_in, const int* in_sizes, int n_in,
                              void* d_out, int out_size, void* d_ws, size_t ws_size,
                              hipStream_t stream) {
  const float* x       = (const float*)d_in[0];
  const float* mask    = (const float*)d_in[1];
  const float* emb_s   = (const float*)d_in[2];
  const float* emb_b   = (const float*)d_in[3];
  const float* rel_emb = (const float*)d_in[4];
  const float* rel_s   = (const float*)d_in[5];
  const float* rel_b   = (const float*)d_in[6];
  const float* Wq = (const float*)d_in[7];
  const float* bq = (const float*)d_in[8];
  const float* Wk = (const float*)d_in[9];
  const float* bk = (const float*)d_in[10];
  const float* Wv = (const float*)d_in[11];
  const float* bv = (const float*)d_in[12];
  const float* Wo = (const float*)d_in[13];
  const float* bo = (const float*)d_in[14];
  const float* as_ = (const float*)d_in[15];
  const float* ab_ = (const float*)d_in[16];
  const float* Wi = (const float*)d_in[17];
  const float* bi = (const float*)d_in[18];
  const float* Wf = (const float*)d_in[19];
  const float* bf_ = (const float*)d_in[20];
  const float* fs_ = (const float*)d_in[21];
  const float* fb_ = (const float*)d_in[22];
  const float* Wc = (const float*)d_in[23];
  const float* bc = (const float*)d_in[24];
  float* out = (float*)d_out;

  char* p = (char*)d_ws;
  auto alloc = [&](size_t bytes) {
    char* r = p;
    p += (bytes + 255) & ~(size_t)255;
    return r;
  };
  float* hcat = (float*)alloc((size_t)4608 * 512 * 4);
  float* tmpA = (float*)alloc((size_t)4096 * 512 * 4);
  u16* mid  = (u16*)alloc((size_t)4096 * 768 * 2);
  u16* hbf  = (u16*)alloc((size_t)4608 * 512 * 2);
  u16* qkv  = (u16*)alloc((size_t)4608 * 1536 * 2);     // q|k|v (+pq|pk rows)
  u16* vT   = (u16*)alloc((size_t)64 * 64 * 512 * 2);   // [bh][d][j]
  u16* ctxb = (u16*)alloc((size_t)4096 * 512 * 2);
  u16* po   = (u16*)alloc((size_t)8 * 64 * 512 * 64 * 2);   // [js][bh][i][d]
  float* pms = (float*)alloc((size_t)8 * 64 * 512 * 2 * 4); // [js][bh][i][2]
  u16* WtQKV = (u16*)alloc((size_t)3 * 1536 * 512 * 2);
  u16* WtO  = (u16*)alloc((size_t)3 * 512 * 512 * 2);
  u16* WtI  = (u16*)alloc((size_t)3 * 768 * 512 * 2);
  u16* WtF  = (u16*)alloc((size_t)3 * 512 * 768 * 2);
  u16* WtC  = (u16*)alloc((size_t)100 * 512 * 2);
  float* bqkv = (float*)alloc((size_t)3 * 1536 * 4);
  int* crel = (int*)alloc((size_t)1024 * 4);

  relbucket_kernel<<<4, 256, 0, stream>>>(crel);
  biascat_kernel<<<18, 256, 0, stream>>>(bq, bk, bv, bqkv);
  wtrans_kernel<<<dim3(16, 16, 3), 256, 0, stream>>>(Wq, WtQKV, 512, 512, 262144, 786432);
  wtrans_kernel<<<dim3(16, 16, 3), 256, 0, stream>>>(Wk, WtQKV + 262144, 512, 512, 262144, 786432);
  wtrans_kernel<<<dim3(16, 16, 3), 256, 0, stream>>>(Wv, WtQKV + 524288, 512, 512, 262144, 786432);
  wtrans_kernel<<<dim3(16, 16, 3), 256, 0, stream>>>(Wo, WtO, 512, 512, 262144, 262144);
  wtrans_kernel<<<dim3(24, 16, 3), 256, 0, stream>>>(Wi, WtI, 512, 768, 393216, 393216);
  wtrans_kernel<<<dim3(16, 24, 3), 256, 0, stream>>>(Wf, WtF, 768, 512, 393216, 393216);
  wtrans_kernel<<<dim3(4, 16, 1), 256, 0, stream>>>(Wc, WtC, 512, 100, 0, 0);
  ln_kernel<false, true><<<1024, 256, 0, stream>>>(x, nullptr, emb_s, emb_b, mask,
                                                   hcat, hbf, 4096);
  ln_kernel<false, false><<<128, 256, 0, stream>>>(rel_emb, nullptr, rel_s, rel_b, nullptr,
                                                   hcat + (size_t)4096 * 512,
                                                   hbf + (size_t)4096 * 512, 512);

  for (int l = 0; l < 3; ++l) {
    // fused q|k|v (+pq|pk) projection: [4608][1536]
    gemm128<1, u16><<<dim3(24, 36), 256, 0, stream>>>(
        hbf, WtQKV + (size_t)l * 786432, bqkv + l * 1536, qkv,
        4608, 1536, 512, 512, 512, 1536);
    vtrans_kernel<<<dim3(16, 2, 64), 256, 0, stream>>>(qkv, vT);
    // fused QK^T + on-the-fly MFMA bias + XSoftmax + PV, 8-way split-j
    attn_fused<<<dim3(8, 64, 8), 256, 0, stream>>>(qkv, vT, mask, crel, po, pms);
    merge_kernel<<<8192, 256, 0, stream>>>(po, pms, ctxb);
    // O proj -> fp32, LN(+h)
    gemm128<1, float><<<dim3(8, 32), 256, 0, stream>>>(
        ctxb, WtO + (size_t)l * 262144, bo + l * 512, tmpA, 4096, 512, 512, 512, 512, 512);
    ln_kernel<true, false><<<1024, 256, 0, stream>>>(tmpA, hcat, as_ + l * 512, ab_ + l * 512,
                                                     nullptr, hcat, hbf, 4096);
    // FFN
    gemm128<2, u16><<<dim3(12, 32), 256, 0, stream>>>(
        hbf, WtI + (size_t)l * 393216, bi + l * 768, mid, 4096, 768, 512, 512, 512, 768);
    gemm128<1, float><<<dim3(8, 32), 256, 0, stream>>>(
        mid, WtF + (size_t)l * 393216, bf_ + l * 512, tmpA, 4096, 512, 768, 768, 768, 512);
    ln_kernel<true, false><<<1024, 256, 0, stream>>>(tmpA, hcat, fs_ + l * 512, fb_ + l * 512,
                                                     nullptr, hcat, hbf, 4096);
  }
  gemm_bf16<1, float><<<dim3(2, 64), 256, 0, stream>>>(
      hbf, WtC, bc, out, 4096, 100, 512, 512, 512, 100);
}

// Round 10
// 473.934 us; speedup vs baseline: 7.3848x; 1.0188x over previous
//
#include <hip/hip_runtime.h>
#include <hip/hip_bf16.h>
#include <math.h>

// B=8, S=512, HID=512, HEADS=8, DH=64, FF=768, NL=3, SPAN=256, MAXP=512, VOCAB=100
#define EPS_LN 1e-7f
#define INV_SCALE 0.072168783648703221f   // 1/sqrt(64*3)
#define NEGMAX -3.402823466e38f

typedef unsigned short u16;
typedef __attribute__((ext_vector_type(8))) short bf16x8;  // 8 bf16 = 4 VGPRs
typedef __attribute__((ext_vector_type(4))) float f32x4;

__device__ __forceinline__ u16 f2b(float f) {
  union { float f; unsigned int u; } v; v.f = f;
  unsigned int r = v.u + 0x7FFFu + ((v.u >> 16) & 1u);
  return (u16)(r >> 16);
}
__device__ __forceinline__ float b2f(u16 u) {
  union { unsigned int u; float f; } v; v.u = ((unsigned int)u) << 16;
  return v.f;
}
__device__ __forceinline__ float gelu_exact(float v) {
  return 0.5f * v * (1.f + erff(v * 0.70710678118654752440f));
}
// DeBERTa log-bucket for a single rel value (must match relbucket_kernel bit-exactly)
__device__ __forceinline__ int bucket_clip(int rel) {
  int a = (rel < 128 && rel > -128) ? 127 : (rel < 0 ? -rel : rel);
  int bucket;
  if (a <= 128) {
    bucket = rel;
  } else {
    double lp = ceil(log((double)a / 128.0) / log(511.0 / 128.0) * 127.0) + 128.0;
    int l = (int)lp;
    bucket = (rel > 0) ? l : -l;
  }
  int c = bucket + 256;
  return c < 0 ? 0 : (c > 511 ? 511 : c);
}

// ---------------------------------------------------------------------------
// Relative-position bucket table (1-D; crel monotone nondecreasing, step<=1).
// ---------------------------------------------------------------------------
__global__ __launch_bounds__(256) void relbucket_kernel(int* __restrict__ crel) {
  int idx = blockIdx.x * 256 + threadIdx.x;
  if (idx >= 1023) return;
  crel[idx] = bucket_clip(idx - 511);
}

// ---------------------------------------------------------------------------
// Bias concat: [3][1536] = bq|bk|bv per layer.
// ---------------------------------------------------------------------------
__global__ __launch_bounds__(256) void biascat_kernel(const float* __restrict__ bq,
                                                      const float* __restrict__ bk,
                                                      const float* __restrict__ bv,
                                                      float* __restrict__ o) {
  int i = blockIdx.x * 256 + threadIdx.x;  // 3*1536
  if (i >= 4608) return;
  int l = i / 1536, c = i - l * 1536;
  float v = (c < 512) ? bq[l * 512 + c]
                      : (c < 1024) ? bk[l * 512 + c - 512] : bv[l * 512 + c - 1024];
  o[i] = v;
}

// ---------------------------------------------------------------------------
// LayerNorm over 512 cols; writes fp32 master and optional bf16 mirror.
// ---------------------------------------------------------------------------
template <bool RESID, bool MASK>
__global__ __launch_bounds__(256) void ln_kernel(const float* __restrict__ x,
                                                 const float* __restrict__ res,
                                                 const float* __restrict__ gam,
                                                 const float* __restrict__ bet,
                                                 const float* __restrict__ mask,
                                                 float* __restrict__ out,
                                                 u16* __restrict__ outb, int nrows) {
  int w = threadIdx.x >> 6, ln = threadIdx.x & 63;
  int row = blockIdx.x * 4 + w;
  if (row >= nrows) return;
  const float* xr = x + (size_t)row * 512;
  float v[8];
#pragma unroll
  for (int c = 0; c < 2; ++c) {
    float4 a = *(const float4*)(xr + (ln << 3) + (c << 2));
    v[c * 4 + 0] = a.x; v[c * 4 + 1] = a.y; v[c * 4 + 2] = a.z; v[c * 4 + 3] = a.w;
    if (RESID) {
      float4 r4 = *(const float4*)(res + (size_t)row * 512 + (ln << 3) + (c << 2));
      v[c * 4 + 0] += r4.x; v[c * 4 + 1] += r4.y; v[c * 4 + 2] += r4.z; v[c * 4 + 3] += r4.w;
    }
  }
  float sum = 0.f;
#pragma unroll
  for (int c = 0; c < 8; ++c) sum += v[c];
#pragma unroll
  for (int off = 32; off; off >>= 1) sum += __shfl_xor(sum, off);
  float mu = sum * (1.f / 512.f);
  float vs = 0.f;
#pragma unroll
  for (int c = 0; c < 8; ++c) { float d = v[c] - mu; vs += d * d; }
#pragma unroll
  for (int off = 32; off; off >>= 1) vs += __shfl_xor(vs, off);
  float rstd = 1.f / sqrtf(vs * (1.f / 512.f) + EPS_LN);
  float mk = MASK ? mask[row] : 1.f;
  float* orow = out + (size_t)row * 512;
  u16* brow = outb ? outb + (size_t)row * 512 : nullptr;
#pragma unroll
  for (int c = 0; c < 2; ++c) {
    int col = (ln << 3) + (c << 2);
    float o[4];
#pragma unroll
    for (int q = 0; q < 4; ++q)
      o[q] = ((v[c * 4 + q] - mu) * rstd * gam[col + q] + bet[col + q]) * mk;
    *(float4*)(orow + col) = make_float4(o[0], o[1], o[2], o[3]);
    if (brow) {
      ushort4 ob = { f2b(o[0]), f2b(o[1]), f2b(o[2]), f2b(o[3]) };
      *(ushort4*)(brow + col) = ob;
    }
  }
}

// ---------------------------------------------------------------------------
// Weight transpose + bf16 cast: W f32 [K][N] row-major -> Wt bf16 [N][K].
// ---------------------------------------------------------------------------
__global__ __launch_bounds__(256) void wtrans_kernel(const float* __restrict__ W,
                                                     u16* __restrict__ Wt,
                                                     int K, int N, long wstride, long tstride) {
  __shared__ float tl[32][33];
  int z = blockIdx.z;
  W += (size_t)z * wstride;
  Wt += (size_t)z * tstride;
  int n0 = blockIdx.x * 32, k0 = blockIdx.y * 32;
  int c = threadIdx.x & 31, r8 = threadIdx.x >> 5;
#pragma unroll
  for (int p = 0; p < 4; ++p) {
    int r = r8 + p * 8;
    int k = k0 + r, n = n0 + c;
    tl[r][c] = (k < K && n < N) ? W[(size_t)k * N + n] : 0.f;
  }
  __syncthreads();
#pragma unroll
  for (int p = 0; p < 4; ++p) {
    int r = r8 + p * 8;
    int n = n0 + r, k = k0 + c;
    if (n < N && k < K) Wt[(size_t)n * K + k] = f2b(tl[c][r]);
  }
}

// ---------------------------------------------------------------------------
// V transpose: qkv v-cols -> vT [64(bh)][64(d)][512(j)] bf16.
// ---------------------------------------------------------------------------
__global__ __launch_bounds__(256) void vtrans_kernel(const u16* __restrict__ qkv,
                                                     u16* __restrict__ vT) {
  __shared__ u16 tl[32][33];
  int z = blockIdx.z;  // b*8+h
  int b = z >> 3, h = z & 7;
  int j0 = blockIdx.x * 32, d0 = blockIdx.y * 32;
  int c = threadIdx.x & 31, r8 = threadIdx.x >> 5;
#pragma unroll
  for (int p = 0; p < 4; ++p) {
    int r = r8 + p * 8;
    tl[r][c] = qkv[(size_t)(b * 512 + j0 + r) * 1536 + 1024 + h * 64 + d0 + c];
  }
  __syncthreads();
#pragma unroll
  for (int p = 0; p < 4; ++p) {
    int r = r8 + p * 8;
    vT[(size_t)z * 32768 + (size_t)(d0 + r) * 512 + j0 + c] = tl[c][r];
  }
}

// ---------------------------------------------------------------------------
// 128x64-tile bf16 MFMA GEMM: C[M,N] = A[M,K] @ B[N,K]^T (+bias, +gelu).
// ---------------------------------------------------------------------------
template <int EPI, typename CT>
__global__ __launch_bounds__(256) void gemm128(const u16* __restrict__ A,
                                               const u16* __restrict__ B,
                                               const float* __restrict__ bias,
                                               CT* __restrict__ C,
                                               int M, int N, int K,
                                               int lda, int ldb, int ldc) {
  __shared__ u16 As[128][72];
  __shared__ u16 Bs[64][72];
  int t = threadIdx.x;
  int m0 = blockIdx.y * 128, n0 = blockIdx.x * 64;
  int w = t >> 6, l = t & 63;
  int wr = w >> 1, wc = w & 1, lr = l & 15, kg = l >> 4;
  f32x4 acc[4][2] = {};
  for (int k0 = 0; k0 < K; k0 += 64) {
#pragma unroll
    for (int p = 0; p < 4; ++p) {
      int c = t + (p << 8);
      int row = c >> 3, q = c & 7;
      *(uint4*)(&As[row][q * 8]) =
          *(const uint4*)(A + (size_t)(m0 + row) * lda + k0 + q * 8);
    }
#pragma unroll
    for (int p = 0; p < 2; ++p) {
      int c = t + (p << 8);
      int row = c >> 3, q = c & 7;
      *(uint4*)(&Bs[row][q * 8]) =
          *(const uint4*)(B + (size_t)(n0 + row) * ldb + k0 + q * 8);
    }
    __syncthreads();
#pragma unroll
    for (int s = 0; s < 2; ++s) {
      bf16x8 a[4], bb[2];
#pragma unroll
      for (int m = 0; m < 4; ++m)
        a[m] = *(const bf16x8*)(&As[wr * 64 + m * 16 + lr][kg * 8 + s * 32]);
#pragma unroll
      for (int n = 0; n < 2; ++n)
        bb[n] = *(const bf16x8*)(&Bs[wc * 32 + n * 16 + lr][kg * 8 + s * 32]);
#pragma unroll
      for (int m = 0; m < 4; ++m)
#pragma unroll
        for (int n = 0; n < 2; ++n)
          acc[m][n] = __builtin_amdgcn_mfma_f32_16x16x32_bf16(a[m], bb[n], acc[m][n], 0, 0, 0);
    }
    __syncthreads();
  }
#pragma unroll
  for (int m = 0; m < 4; ++m)
#pragma unroll
    for (int n = 0; n < 2; ++n) {
      int col = n0 + wc * 32 + n * 16 + lr;
      float bv = (EPI >= 1) ? bias[col] : 0.f;
#pragma unroll
      for (int r = 0; r < 4; ++r) {
        int row = m0 + wr * 64 + m * 16 + kg * 4 + r;
        float v = acc[m][n][r] + bv;
        if (EPI == 2) v = gelu_exact(v);
        if constexpr (sizeof(CT) == 2) {
          ((u16*)C)[(size_t)row * ldc + col] = f2b(v);
        } else {
          ((float*)C)[(size_t)row * ldc + col] = v;
        }
      }
    }
}

// ---------------------------------------------------------------------------
// 64x64-tile bf16 MFMA GEMM (classifier only).
// ---------------------------------------------------------------------------
template <int EPI, typename CT>
__global__ __launch_bounds__(256) void gemm_bf16(const u16* __restrict__ A,
                                                 const u16* __restrict__ B,
                                                 const float* __restrict__ bias,
                                                 CT* __restrict__ C,
                                                 int M, int N, int K,
                                                 int lda, int ldb, int ldc) {
  __shared__ u16 As[64][72];
  __shared__ u16 Bs[64][72];
  int t = threadIdx.x;
  int m0 = blockIdx.y * 64, n0 = blockIdx.x * 64;
  int w = t >> 6, l = t & 63;
  int wr = w >> 1, wc = w & 1, lr = l & 15, kg = l >> 4;
  f32x4 acc[2][2] = {};
  for (int k0 = 0; k0 < K; k0 += 64) {
#pragma unroll
    for (int p = 0; p < 2; ++p) {
      int c = t + (p << 8);
      int row = c >> 3, q = c & 7;
      uint4 av = *(const uint4*)(A + (size_t)(m0 + row) * lda + k0 + q * 8);
      *(uint4*)(&As[row][q * 8]) = av;
      uint4 bv = make_uint4(0u, 0u, 0u, 0u);
      if (n0 + row < N) bv = *(const uint4*)(B + (size_t)(n0 + row) * ldb + k0 + q * 8);
      *(uint4*)(&Bs[row][q * 8]) = bv;
    }
    __syncthreads();
#pragma unroll
    for (int s = 0; s < 2; ++s) {
      bf16x8 a0 = *(const bf16x8*)(&As[wr * 32 + lr][kg * 8 + s * 32]);
      bf16x8 a1 = *(const bf16x8*)(&As[wr * 32 + 16 + lr][kg * 8 + s * 32]);
      bf16x8 b0 = *(const bf16x8*)(&Bs[wc * 32 + lr][kg * 8 + s * 32]);
      bf16x8 b1 = *(const bf16x8*)(&Bs[wc * 32 + 16 + lr][kg * 8 + s * 32]);
      acc[0][0] = __builtin_amdgcn_mfma_f32_16x16x32_bf16(a0, b0, acc[0][0], 0, 0, 0);
      acc[0][1] = __builtin_amdgcn_mfma_f32_16x16x32_bf16(a0, b1, acc[0][1], 0, 0, 0);
      acc[1][0] = __builtin_amdgcn_mfma_f32_16x16x32_bf16(a1, b0, acc[1][0], 0, 0, 0);
      acc[1][1] = __builtin_amdgcn_mfma_f32_16x16x32_bf16(a1, b1, acc[1][1], 0, 0, 0);
    }
    __syncthreads();
  }
#pragma unroll
  for (int m = 0; m < 2; ++m)
#pragma unroll
    for (int n = 0; n < 2; ++n) {
      int col = n0 + wc * 32 + n * 16 + lr;
      if (col < N) {
        float bv = (EPI >= 1) ? bias[col] : 0.f;
#pragma unroll
        for (int r = 0; r < 4; ++r) {
          int row = m0 + wr * 32 + m * 16 + kg * 4 + r;
          float v = acc[m][n][r] + bv;
          if (EPI == 2) v = gelu_exact(v);
          if constexpr (sizeof(CT) == 2) {
            ((u16*)C)[(size_t)row * ldc + col] = f2b(v);
          } else {
            ((float*)C)[(size_t)row * ldc + col] = v;
          }
        }
      }
    }
}

// ---------------------------------------------------------------------------
// Fused disentangled attention, 8-way split-j, bias on-the-fly via MFMA.
// 1-D grid 4096, XCD-CHUNKED decode: hw round-robins linear id over 8 XCDs
// (wg&7 = xcd), so z = xcd*8 + (wg>>3)>>6 gives each XCD 8 contiguous (b,h)
// slices -> ~2.6 MB working set per XCD, L2-resident (was: every XCD
// re-fetching all 64 slices; FETCH 38.6 MB vs ~20 MB unique).
// ib (window base bucket) computed analytically -> no crl16 barrier before
// staging; crl16 only needed at gather time (covered by later barriers).
// ---------------------------------------------------------------------------
__global__ __launch_bounds__(256) void attn_fused(const u16* __restrict__ qkv,
                                                  const u16* __restrict__ vT,
                                                  const float* __restrict__ mask,
                                                  const int* __restrict__ crel,
                                                  u16* __restrict__ po,
                                                  float* __restrict__ pms) {
  __shared__ u16 ks[64][72];      //  9216 B (K tile; later per-wave P buffer)
  __shared__ u16 U1[128][72];     // 18432 B (pk window -> b1s[64][136] view)
  __shared__ u16 U2[128][72];     // 18432 B (pq window -> b2s[128][72])
  __shared__ u16 crl16[1024];     //  2048 B   -> 48128 B total
  int t = threadIdx.x;
  int wg = blockIdx.x;            // 0..4095
  int xcd = wg & 7, q = wg >> 3;  // q: 0..511
  int z = xcd * 8 + (q >> 6);     // b*8+h, chunked per XCD
  int rem = q & 63;
  int it = rem >> 3, js = rem & 7;
  int b = z >> 3, h = z & 7;
  int i0 = it * 64, j0 = js * 64;
  int w = t >> 6, l = t & 63;
  int lr = l & 15, kg = l >> 4;

  int ib = bucket_clip(i0 - j0 - 63);  // min bucket over tile (crel monotone)

  for (int c = t; c < 1023; c += 256) crl16[c] = (u16)crel[c];
  // stage K tile + pk/pq windows (clamped rows; clamped values never gathered)
  for (int c = t; c < 512; c += 256) {
    int row = c >> 3, off = (c & 7) * 8;
    *(uint4*)(&ks[row][off]) =
        *(const uint4*)(qkv + (size_t)(b * 512 + j0 + row) * 1536 + 512 + h * 64 + off);
  }
  for (int c = t; c < 1024; c += 256) {
    int row = c >> 3, off = (c & 7) * 8;
    int rw = ib + row;
    rw = rw > 511 ? 511 : rw;
    const u16* relrow = qkv + (size_t)(4096 + rw) * 1536 + h * 64;
    *(uint4*)(&U1[row][off]) = *(const uint4*)(relrow + 512 + off);  // pk
    *(uint4*)(&U2[row][off]) = *(const uint4*)(relrow + off);        // pq
  }

  // q fragments straight from global
  const u16* qrow = qkv + (size_t)(b * 512 + i0 + w * 16 + lr) * 1536 + h * 64;
  bf16x8 qa0 = *(const bf16x8*)(qrow + kg * 8);
  bf16x8 qa1 = *(const bf16x8*)(qrow + kg * 8 + 32);
  __syncthreads();

  // QK^T scores (4 col-frags)
  f32x4 sc[4];
#pragma unroll
  for (int nf = 0; nf < 4; ++nf) {
    bf16x8 kb0 = *(const bf16x8*)(&ks[nf * 16 + lr][kg * 8]);
    bf16x8 kb1 = *(const bf16x8*)(&ks[nf * 16 + lr][kg * 8 + 32]);
    f32x4 a = {};
    a = __builtin_amdgcn_mfma_f32_16x16x32_bf16(qa0, kb0, a, 0, 0, 0);
    a = __builtin_amdgcn_mfma_f32_16x16x32_bf16(qa1, kb1, a, 0, 0, 0);
    sc[nf] = a;
  }
  // bias1 = Q @ pk_win^T : wave w owns i-rows w*16..+16, all 128 w-cols
  f32x4 b1a[8];
#pragma unroll
  for (int f = 0; f < 8; ++f) {
    bf16x8 p0 = *(const bf16x8*)(&U1[f * 16 + lr][kg * 8]);
    bf16x8 p1 = *(const bf16x8*)(&U1[f * 16 + lr][kg * 8 + 32]);
    f32x4 a = {};
    a = __builtin_amdgcn_mfma_f32_16x16x32_bf16(qa0, p0, a, 0, 0, 0);
    a = __builtin_amdgcn_mfma_f32_16x16x32_bf16(qa1, p1, a, 0, 0, 0);
    b1a[f] = a;
  }
  // bias2 = pq_win @ K^T : wave w owns bucket-rows w*32..+32 (2 groups of 16)
  f32x4 b2a[2][4];
#pragma unroll
  for (int g = 0; g < 2; ++g) {
    bf16x8 a0 = *(const bf16x8*)(&U2[w * 32 + g * 16 + lr][kg * 8]);
    bf16x8 a1 = *(const bf16x8*)(&U2[w * 32 + g * 16 + lr][kg * 8 + 32]);
#pragma unroll
    for (int f = 0; f < 4; ++f) {
      bf16x8 kb0 = *(const bf16x8*)(&ks[f * 16 + lr][kg * 8]);
      bf16x8 kb1 = *(const bf16x8*)(&ks[f * 16 + lr][kg * 8 + 32]);
      f32x4 a = {};
      a = __builtin_amdgcn_mfma_f32_16x16x32_bf16(a0, kb0, a, 0, 0, 0);
      a = __builtin_amdgcn_mfma_f32_16x16x32_bf16(a1, kb1, a, 0, 0, 0);
      b2a[g][f] = a;
    }
  }
  __syncthreads();  // all reads of U1/U2 done -> overwrite with bias tiles
  u16* b1 = &U1[0][0];  // b1s[64][136]
#pragma unroll
  for (int f = 0; f < 8; ++f)
#pragma unroll
    for (int r = 0; r < 4; ++r)
      b1[(w * 16 + kg * 4 + r) * 136 + f * 16 + lr] = f2b(b1a[f][r]);
#pragma unroll
  for (int g = 0; g < 2; ++g)
#pragma unroll
    for (int f = 0; f < 4; ++f)
#pragma unroll
      for (int r = 0; r < 4; ++r)
        U2[w * 32 + g * 16 + kg * 4 + r][f * 16 + lr] = f2b(b2a[g][f][r]);
  __syncthreads();  // b2s is read cross-wave

  // V fragments direct from global (issue early, consumed after softmax)
  bf16x8 vb[4][2];
#pragma unroll
  for (int nf = 0; nf < 4; ++nf) {
    const u16* vrow = vT + (size_t)z * 32768 + (size_t)(nf * 16 + lr) * 512 + j0;
    vb[nf][0] = *(const bf16x8*)(vrow + kg * 8);
    vb[nf][1] = *(const bf16x8*)(vrow + kg * 8 + 32);
  }

  // gather bias (both LDS) + mask + softmax (single tile: no rescale)
  float mi[4], mj[4];
#pragma unroll
  for (int r = 0; r < 4; ++r) mi[r] = mask[b * 512 + i0 + w * 16 + kg * 4 + r];
#pragma unroll
  for (int nf = 0; nf < 4; ++nf) mj[nf] = mask[b * 512 + j0 + nf * 16 + lr];
  float lgv[4][4];
  bool ok[4][4];
  float tmax[4] = {NEGMAX, NEGMAX, NEGMAX, NEGMAX};
  int iloc = w * 16 + kg * 4;
#pragma unroll
  for (int nf = 0; nf < 4; ++nf) {
    int jloc = nf * 16 + lr;
    int relc = i0 + iloc - (j0 + jloc) + 511;
#pragma unroll
    for (int r = 0; r < 4; ++r) {
      int idx = crl16[relc + r] - ib;
      float bias = b2f(b1[(iloc + r) * 136 + idx]) + b2f(U2[idx][jloc]);
      bool o_ = (mi[r] * mj[nf]) > 0.f;
      float v = o_ ? (sc[nf][r] + bias) * INV_SCALE : NEGMAX;
      ok[nf][r] = o_;
      lgv[nf][r] = v;
      tmax[r] = fmaxf(tmax[r], v);
    }
  }
#pragma unroll
  for (int r = 0; r < 4; ++r) {
#pragma unroll
    for (int off = 8; off; off >>= 1) tmax[r] = fmaxf(tmax[r], __shfl_xor(tmax[r], off));
  }
  float tsum[4];
#pragma unroll
  for (int r = 0; r < 4; ++r) {
    float mn = tmax[r];
    float ls = 0.f;
#pragma unroll
    for (int nf = 0; nf < 4; ++nf) {
      float p = ok[nf][r] ? __expf(lgv[nf][r] - mn) : 0.f;
      lgv[nf][r] = p;
      ls += p;
    }
    tsum[r] = ls;
  }
#pragma unroll
  for (int r = 0; r < 4; ++r) {
#pragma unroll
    for (int off = 8; off; off >>= 1) tsum[r] += __shfl_xor(tsum[r], off);
  }
  // P (C/D layout) -> per-wave rows of ks (wave-local, no barrier needed)
#pragma unroll
  for (int nf = 0; nf < 4; ++nf)
#pragma unroll
    for (int r = 0; r < 4; ++r) ks[w * 16 + kg * 4 + r][nf * 16 + lr] = f2b(lgv[nf][r]);
  bf16x8 pa0 = *(const bf16x8*)(&ks[w * 16 + lr][kg * 8]);
  bf16x8 pa1 = *(const bf16x8*)(&ks[w * 16 + lr][kg * 8 + 32]);
  // PV
  f32x4 o[4] = {};
#pragma unroll
  for (int nf = 0; nf < 4; ++nf) {
    o[nf] = __builtin_amdgcn_mfma_f32_16x16x32_bf16(pa0, vb[nf][0], o[nf], 0, 0, 0);
    o[nf] = __builtin_amdgcn_mfma_f32_16x16x32_bf16(pa1, vb[nf][1], o[nf], 0, 0, 0);
  }
  // write unnormalized partials
#pragma unroll
  for (int r = 0; r < 4; ++r) {
    int i = i0 + w * 16 + kg * 4 + r;
    size_t pb = (((size_t)js * 64 + z) * 512 + i) * 64;
#pragma unroll
    for (int nf = 0; nf < 4; ++nf) po[pb + nf * 16 + lr] = f2b(o[nf][r]);
    if (lr == 0) {
      size_t mb = (((size_t)js * 64 + z) * 512 + i) * 2;
      pms[mb + 0] = tmax[r];
      pms[mb + 1] = tsum[r];
    }
  }
}

// ---------------------------------------------------------------------------
// Merge 8 j-split partials -> normalized ctx (bf16).
// ---------------------------------------------------------------------------
__global__ __launch_bounds__(256) void merge_kernel(const u16* __restrict__ po,
                                                    const float* __restrict__ pms,
                                                    u16* __restrict__ ctx) {
  int t = threadIdx.x;
  int w = t >> 6, d = t & 63;
  int row = blockIdx.x * 4 + w;   // 0..32767
  int z = row >> 9, i = row & 511;
  int b = z >> 3, h = z & 7;
  float mv[8], sv[8], m = NEGMAX;
#pragma unroll
  for (int js = 0; js < 8; ++js) {
    size_t mb = (((size_t)js * 64 + z) * 512 + i) * 2;
    mv[js] = pms[mb + 0];
    sv[js] = pms[mb + 1];
    m = fmaxf(m, mv[js]);
  }
  float o = 0.f, s = 0.f;
#pragma unroll
  for (int js = 0; js < 8; ++js) {
    float wgt = (mv[js] <= -1e37f) ? 0.f : __expf(mv[js] - m);
    o += wgt * b2f(po[(((size_t)js * 64 + z) * 512 + i) * 64 + d]);
    s += wgt * sv[js];
  }
  float r = (s > 0.f) ? o / s : 0.f;
  ctx[(size_t)(b * 512 + i) * 512 + h * 64 + d] = f2b(r);
}

// ---------------------------------------------------------------------------
// Host launch
// ---------------------------------------------------------------------------
extern "C" void kernel_launch(void* const* d_in, const int* in_sizes, int n_in,
                              void* d_out, int out_size, void* d_ws, size_t ws_size,
                              hipStream_t stream) {
  const float* x       = (const float*)d_in[0];
  const float* mask    = (const float*)d_in[1];
  const float* emb_s   = (const float*)d_in[2];
  const float* emb_b   = (const float*)d_in[3];
  const float* rel_emb = (const float*)d_in[4];
  const float* rel_s   = (const float*)d_in[5];
  const float* rel_b   = (const float*)d_in[6];
  const float* Wq = (const float*)d_in[7];
  const float* bq = (const float*)d_in[8];
  const float* Wk = (const float*)d_in[9];
  const float* bk = (const float*)d_in[10];
  const float* Wv = (const float*)d_in[11];
  const float* bv = (const float*)d_in[12];
  const float* Wo = (const float*)d_in[13];
  const float* bo = (const float*)d_in[14];
  const float* as_ = (const float*)d_in[15];
  const float* ab_ = (const float*)d_in[16];
  const float* Wi = (const float*)d_in[17];
  const float* bi = (const float*)d_in[18];
  const float* Wf = (const float*)d_in[19];
  const float* bf_ = (const float*)d_in[20];
  const float* fs_ = (const float*)d_in[21];
  const float* fb_ = (const float*)d_in[22];
  const float* Wc = (const float*)d_in[23];
  const float* bc = (const float*)d_in[24];
  float* out = (float*)d_out;

  char* p = (char*)d_ws;
  auto alloc = [&](size_t bytes) {
    char* r = p;
    p += (bytes + 255) & ~(size_t)255;
    return r;
  };
  float* hcat = (float*)alloc((size_t)4608 * 512 * 4);
  float* tmpA = (float*)alloc((size_t)4096 * 512 * 4);
  u16* mid  = (u16*)alloc((size_t)4096 * 768 * 2);
  u16* hbf  = (u16*)alloc((size_t)4608 * 512 * 2);
  u16* qkv  = (u16*)alloc((size_t)4608 * 1536 * 2);     // q|k|v (+pq|pk rows)
  u16* vT   = (u16*)alloc((size_t)64 * 64 * 512 * 2);   // [bh][d][j]
  u16* ctxb = (u16*)alloc((size_t)4096 * 512 * 2);
  u16* po   = (u16*)alloc((size_t)8 * 64 * 512 * 64 * 2);   // [js][bh][i][d]
  float* pms = (float*)alloc((size_t)8 * 64 * 512 * 2 * 4); // [js][bh][i][2]
  u16* WtQKV = (u16*)alloc((size_t)3 * 1536 * 512 * 2);
  u16* WtO  = (u16*)alloc((size_t)3 * 512 * 512 * 2);
  u16* WtI  = (u16*)alloc((size_t)3 * 768 * 512 * 2);
  u16* WtF  = (u16*)alloc((size_t)3 * 512 * 768 * 2);
  u16* WtC  = (u16*)alloc((size_t)100 * 512 * 2);
  float* bqkv = (float*)alloc((size_t)3 * 1536 * 4);
  int* crel = (int*)alloc((size_t)1024 * 4);

  relbucket_kernel<<<4, 256, 0, stream>>>(crel);
  biascat_kernel<<<18, 256, 0, stream>>>(bq, bk, bv, bqkv);
  wtrans_kernel<<<dim3(16, 16, 3), 256, 0, stream>>>(Wq, WtQKV, 512, 512, 262144, 786432);
  wtrans_kernel<<<dim3(16, 16, 3), 256, 0, stream>>>(Wk, WtQKV + 262144, 512, 512, 262144, 786432);
  wtrans_kernel<<<dim3(16, 16, 3), 256, 0, stream>>>(Wv, WtQKV + 524288, 512, 512, 262144, 786432);
  wtrans_kernel<<<dim3(16, 16, 3), 256, 0, stream>>>(Wo, WtO, 512, 512, 262144, 262144);
  wtrans_kernel<<<dim3(24, 16, 3), 256, 0, stream>>>(Wi, WtI, 512, 768, 393216, 393216);
  wtrans_kernel<<<dim3(16, 24, 3), 256, 0, stream>>>(Wf, WtF, 768, 512, 393216, 393216);
  wtrans_kernel<<<dim3(4, 16, 1), 256, 0, stream>>>(Wc, WtC, 512, 100, 0, 0);
  ln_kernel<false, true><<<1024, 256, 0, stream>>>(x, nullptr, emb_s, emb_b, mask,
                                                   hcat, hbf, 4096);
  ln_kernel<false, false><<<128, 256, 0, stream>>>(rel_emb, nullptr, rel_s, rel_b, nullptr,
                                                   hcat + (size_t)4096 * 512,
                                                   hbf + (size_t)4096 * 512, 512);

  for (int l = 0; l < 3; ++l) {
    // fused q|k|v (+pq|pk) projection: [4608][1536]
    gemm128<1, u16><<<dim3(24, 36), 256, 0, stream>>>(
        hbf, WtQKV + (size_t)l * 786432, bqkv + l * 1536, qkv,
        4608, 1536, 512, 512, 512, 1536);
    vtrans_kernel<<<dim3(16, 2, 64), 256, 0, stream>>>(qkv, vT);
    // fused QK^T + on-the-fly MFMA bias + XSoftmax + PV, 8-way split-j
    attn_fused<<<4096, 256, 0, stream>>>(qkv, vT, mask, crel, po, pms);
    merge_kernel<<<8192, 256, 0, stream>>>(po, pms, ctxb);
    // O proj -> fp32, LN(+h)
    gemm128<1, float><<<dim3(8, 32), 256, 0, stream>>>(
        ctxb, WtO + (size_t)l * 262144, bo + l * 512, tmpA, 4096, 512, 512, 512, 512, 512);
    ln_kernel<true, false><<<1024, 256, 0, stream>>>(tmpA, hcat, as_ + l * 512, ab_ + l * 512,
                                                     nullptr, hcat, hbf, 4096);
    // FFN
    gemm128<2, u16><<<dim3(12, 32), 256, 0, stream>>>(
        hbf, WtI + (size_t)l * 393216, bi + l * 768, mid, 4096, 768, 512, 512, 512, 768);
    gemm128<1, float><<<dim3(8, 32), 256, 0, stream>>>(
        mid, WtF + (size_t)l * 393216, bf_ + l * 512, tmpA, 4096, 512, 768, 768, 768, 512);
    ln_kernel<true, false><<<1024, 256, 0, stream>>>(tmpA, hcat, fs_ + l * 512, fb_ + l * 512,
                                                     nullptr, hcat, hbf, 4096);
  }
  gemm_bf16<1, float><<<dim3(2, 64), 256, 0, stream>>>(
      hbf, WtC, bc, out, 4096, 100, 512, 512, 512, 100);
}